// Round 12
// baseline (660.462 us; speedup 1.0000x reference)
//
#include <hip/hip_runtime.h>
#include <cstddef>

namespace {

constexpr int Gn  = 64;
constexpr int Pn  = 512;
constexpr int EPGn= 4096;
constexpr int Nn  = Gn * Pn;    // 32768 nodes
constexpr int En  = Gn * EPGn;  // 262144 edges
constexpr int H   = 128;

constexpr int BM = 64, BK = 32, BN = 128;
constexpr int LDA = BK + 4;
constexpr int RS  = 256;        // bf16-plane row stride (hi 128 | lo 128)
constexpr int SLAB = 4096;      // elements per 32k-slab in frag layout

typedef __bf16 bf16_t;
typedef bf16_t bf16x8 __attribute__((ext_vector_type(8)));
typedef bf16_t bf16x4 __attribute__((ext_vector_type(4)));
typedef float  f32x4  __attribute__((ext_vector_type(4)));

__device__ __forceinline__ float4 ld4(const float* p) { return *reinterpret_cast<const float4*>(p); }
__device__ __forceinline__ void st4(float* p, const float4 v) { *reinterpret_cast<float4*>(p) = v; }
__device__ __forceinline__ f32x4 mfma16(bf16x8 a, bf16x8 b, f32x4 c) {
    return __builtin_amdgcn_mfma_f32_16x16x32_bf16(a, b, c, 0, 0, 0);
}

// bijective XCD swizzle: grid must be divisible by 8; cpx = grid/8
__device__ __forceinline__ int xcd_swz(int bid, int cpx)
{
    return (bid & 7) * cpx + (bid >> 3);
}

// async global->LDS, 16B per lane; LDS dest = wave-uniform base + lane*16
__device__ __forceinline__ void gload_lds16(const bf16_t* g, bf16_t* l)
{
    typedef __attribute__((address_space(1))) const unsigned int* gp_t;
    typedef __attribute__((address_space(3))) unsigned int* lp_t;
    __builtin_amdgcn_global_load_lds((gp_t)(const void*)g, (lp_t)(void*)l, 16, 0, 0);
}

// ---------------------------------------------------------------------------
// Weight prep: fp32 W[K][128] -> bf16 hi/lo in MFMA B-fragment-major layout.
// ---------------------------------------------------------------------------
__global__ void prep_wfrag(const float* __restrict__ W, bf16_t* __restrict__ Bh,
                           bf16_t* __restrict__ Bl)
{
    const int i = blockIdx.x * 256 + threadIdx.x;   // i < K*128
    const int k = i >> 7, n = i & 127;
    const float v = W[i];
    const bf16_t h = (bf16_t)v;
    const bf16_t l = (bf16_t)(v - (float)h);
    const int idx = ((((k >> 5) * 8) + (n >> 4)) * 64 + ((k >> 3) & 3) * 16 + (n & 15)) * 8 + (k & 7);
    Bh[idx] = h; Bl[idx] = l;
}

// per-graph hoisted u-segment partial product: out[g][c] = sum_k u[g][k]*W[k][c]
__global__ void useg_k(const float* __restrict__ u, const float* __restrict__ W,
                       float* __restrict__ outp)
{
    __shared__ float su[H];
    const int g = blockIdx.x, c = threadIdx.x;
    su[c] = u[g * H + c];
    __syncthreads();
    float s = 0.f;
#pragma unroll 8
    for (int k = 0; k < H; ++k) s = fmaf(su[k], W[k * H + c], s);
    outp[g * H + c] = s;
}

__device__ __forceinline__ void split8(const float4 a, const float4 b, bf16x8& h, bf16x8& l)
{
    const float v[8] = {a.x, a.y, a.z, a.w, b.x, b.y, b.z, b.w};
#pragma unroll
    for (int j = 0; j < 8; ++j) {
        const bf16_t hh = (bf16_t)v[j];
        h[j] = hh;
        l[j] = (bf16_t)(v[j] - (float)hh);
    }
}

// load one wave's 32-col weight slice for one 32-k slab (2 n-tiles, hi+lo)
__device__ __forceinline__ void loadB(const bf16_t* __restrict__ Wh, const bf16_t* __restrict__ Wl,
                                      int kc32, int wn, int lane, bf16x8* Bh, bf16x8* Bl)
{
#pragma unroll
    for (int nt = 0; nt < 2; ++nt) {
        const size_t idx = (size_t)(((kc32 * 8) + wn * 2 + nt) * 64 + lane) * 8;
        Bh[nt] = *reinterpret_cast<const bf16x8*>(Wh + idx);
        Bl[nt] = *reinterpret_cast<const bf16x8*>(Wl + idx);
    }
}

// ---------------------------------------------------------------------------
// xpart_k: per-node partial products for the edge MLP.
// Pa[n] = x[n] @ eW1[0:128] ; Pb[n] = x[n] @ eW1[128:256]  (fp32 out)
// ---------------------------------------------------------------------------
__global__ __launch_bounds__(256, 4)
void xpart_k(const bf16_t* __restrict__ xp,
             const bf16_t* __restrict__ Wh, const bf16_t* __restrict__ Wl,
             float* __restrict__ Pa, float* __restrict__ Pb)
{
    __shared__ __align__(16) char smem[32 * 1024];
    const int t = threadIdx.x, lane = t & 63, wv = t >> 6;
    const int wn = wv;
    const int l15 = lane & 15, l4 = lane >> 4;
    const int row0 = blockIdx.x * 64;

    f32x4 accA[4][2], accB[4][2];
#pragma unroll
    for (int mt = 0; mt < 4; ++mt)
#pragma unroll
        for (int nt = 0; nt < 2; ++nt) { accA[mt][nt] = (f32x4)0.f; accB[mt][nt] = (f32x4)0.f; }

    auto stage = [&](int kc, int bufi) {
        const bf16_t* rp = xp + (size_t)(row0 + lane) * RS + kc * 64 + wv * 8;
        bf16_t* base = (bf16_t*)(smem + bufi * 16384);
        gload_lds16(rp,       base + wv * 512);
        gload_lds16(rp + 32,  base + (wv + 4) * 512);
        gload_lds16(rp + 128, base + 4096 + wv * 512);
        gload_lds16(rp + 160, base + 4096 + (wv + 4) * 512);
    };

    stage(0, 0);
    stage(1, 1);
    __syncthreads();

#pragma unroll
    for (int kc = 0; kc < 2; ++kc) {
        const bf16_t* aH = (const bf16_t*)(smem + (size_t)kc * 16384);
        const bf16_t* aL = aH + 4096;
#pragma unroll
        for (int ks = 0; ks < 2; ++ks) {
            const int slab = kc * 2 + ks;
            bf16x8 BhA[2], BlA[2], BhB[2], BlB[2];
            loadB(Wh, Wl, slab,     wn, lane, BhA, BlA);
            loadB(Wh, Wl, slab + 4, wn, lane, BhB, BlB);
#pragma unroll
            for (int mt = 0; mt < 4; ++mt) {
                const int ro = mt * 16 + l15;
                const bf16x8 Ah = *reinterpret_cast<const bf16x8*>(aH + ((ks * 4 + l4) * 64 + ro) * 8);
                const bf16x8 Al = *reinterpret_cast<const bf16x8*>(aL + ((ks * 4 + l4) * 64 + ro) * 8);
#pragma unroll
                for (int nt = 0; nt < 2; ++nt) {
                    accA[mt][nt] = mfma16(Al, BhA[nt], accA[mt][nt]);
                    accA[mt][nt] = mfma16(Ah, BlA[nt], accA[mt][nt]);
                    accA[mt][nt] = mfma16(Ah, BhA[nt], accA[mt][nt]);
                    accB[mt][nt] = mfma16(Al, BhB[nt], accB[mt][nt]);
                    accB[mt][nt] = mfma16(Ah, BlB[nt], accB[mt][nt]);
                    accB[mt][nt] = mfma16(Ah, BhB[nt], accB[mt][nt]);
                }
            }
        }
    }

#pragma unroll
    for (int mt = 0; mt < 4; ++mt)
#pragma unroll
        for (int r2 = 0; r2 < 4; ++r2) {
            const int row = mt * 16 + l4 * 4 + r2;
#pragma unroll
            for (int nt = 0; nt < 2; ++nt) {
                const int col = wn * 32 + nt * 16 + l15;
                Pa[(size_t)(row0 + row) * H + col] = accA[mt][nt][r2];
                Pb[(size_t)(row0 + row) * H + col] = accB[mt][nt][r2];
            }
        }
}

// ---------------------------------------------------------------------------
// MFMA fused 2-layer MLP + LN, bf16x3 precision.
// 4-way N-split waves; weight registers prefetched one slab ahead (static idx).
// PRE=true: fp32 Pa[iA]+Pb[iB] loaded EARLY into pre[] regs (T14), applied at
// the transition (phase-1 MFMAs don't wait on the gather).
// ---------------------------------------------------------------------------
template<int NSEG, bool PLANES, bool PRE>
__global__ __launch_bounds__(256, 4)
void mfma_mlp_ln(const void* __restrict__ p0v, const int* __restrict__ i0,
                 const void* __restrict__ p1v, const int* __restrict__ i1,
                 const void* __restrict__ p2v, const int* __restrict__ i2,
                 const int* __restrict__ iA, const int* __restrict__ iB,
                 const float* __restrict__ Pa, const float* __restrict__ Pb,
                 const bf16_t* __restrict__ W1h, const bf16_t* __restrict__ W1l,
                 const bf16_t* __restrict__ W2h, const bf16_t* __restrict__ W2l,
                 const float* __restrict__ b1, const float* __restrict__ b2,
                 const float* __restrict__ gam, const float* __restrict__ bet,
                 const float* __restrict__ useg,
                 bf16_t* __restrict__ outP, float* __restrict__ out32,
                 float* __restrict__ pool, int gshift, float pscale, int cpx)
{
    // Overlay: phase1 A-tiles (2 bufs x [hi 8KB | lo 8KB]) alias phase2 hidden.
    __shared__ __align__(16) char smem[32 * 1024];
    __shared__ float redS[4][64], redQ[4][64];

    const int t = threadIdx.x;
    const int lane = t & 63;
    const int wv = t >> 6;          // wave id == staging k-subgroup == wn
    const int wn = wv;              // 4-way N split
    const int l15 = lane & 15, l4 = lane >> 4;
    const int bid = (cpx > 0) ? xcd_swz(blockIdx.x, cpx) : blockIdx.x;
    const int row0 = bid * 64;

    // staging row indices per segment (PRE: seg0 is direct)
    const int s0 = (PRE || !i0) ? row0 + lane : i0[row0 + lane];
    const int s1 = (NSEG > 1) ? (i1 ? i1[row0 + lane] : row0 + lane) : 0;
    const int s2 = (NSEG > 2) ? (i2 ? i2[row0 + lane] : row0 + lane) : 0;

    f32x4 acc[4][2];
#pragma unroll
    for (int mt = 0; mt < 4; ++mt)
#pragma unroll
        for (int nt = 0; nt < 2; ++nt) acc[mt][nt] = (f32x4)0.f;

    constexpr int NC = NSEG * 2;    // 64-wide K chunks
    constexpr int NS1 = NC * 2;     // 32-wide K slabs in phase 1

    auto stage_async = [&](int kc, int bufi) {
        const int seg = kc >> 1, kh = kc & 1;
        const bf16_t* p; int srow;
        if (seg == 0)      { p = (const bf16_t*)p0v; srow = s0; }
        else if (seg == 1) { p = (const bf16_t*)p1v; srow = s1; }
        else               { p = (const bf16_t*)p2v; srow = s2; }
        const bf16_t* rp = p + (size_t)srow * RS + kh * 64 + wv * 8;
        bf16_t* base = (bf16_t*)(smem + bufi * 16384);
        gload_lds16(rp,        base + wv * 512);              // hi, kg=wv
        gload_lds16(rp + 32,   base + (wv + 4) * 512);        // hi, kg=wv+4
        gload_lds16(rp + 128,  base + 4096 + wv * 512);       // lo, kg=wv
        gload_lds16(rp + 160,  base + 4096 + (wv + 4) * 512); // lo, kg=wv+4
    };

    auto stage_f32 = [&](int kc, int bufi) {
        const int seg = kc >> 1, kh = kc & 1;
        const float* p; int srow;
        if (seg == 0)      { p = (const float*)p0v; srow = s0; }
        else if (seg == 1) { p = (const float*)p1v; srow = s1; }
        else               { p = (const float*)p2v; srow = s2; }
        const float* sp = p + (size_t)srow * H + kh * 64 + wv * 8;
        bf16_t* base = (bf16_t*)(smem + bufi * 16384);
        bf16x8 h, l;
        split8(ld4(sp), ld4(sp + 4), h, l);
        *reinterpret_cast<bf16x8*>(base + ((wv)     * 64 + lane) * 8) = h;
        *reinterpret_cast<bf16x8*>(base + 4096 + ((wv)     * 64 + lane) * 8) = l;
        split8(ld4(sp + 32), ld4(sp + 36), h, l);
        *reinterpret_cast<bf16x8*>(base + ((wv + 4) * 64 + lane) * 8) = h;
        *reinterpret_cast<bf16x8*>(base + 4096 + ((wv + 4) * 64 + lane) * 8) = l;
    };

    // named static double buffers for weight prefetch (rule #20 safe)
    bf16x8 BhA[2], BlA[2], BhB[2], BlB[2];
    loadB(W1h, W1l, 0, wn, lane, BhA, BlA);
    if constexpr (PLANES) stage_async(0, 0); else stage_f32(0, 0);

    // PRE (T14): issue gathered per-node partial loads EARLY into pre[] regs;
    // first use is at the transition, so phase-1 MFMAs don't wait on them.
    f32x4 pre[4][2];
    if constexpr (PRE) {
        const int ia = iA[row0 + lane];
        const int ib = iB[row0 + lane];
#pragma unroll
        for (int mt = 0; mt < 4; ++mt)
#pragma unroll
            for (int r2 = 0; r2 < 4; ++r2) {
                const int r = mt * 16 + l4 * 4 + r2;
                const int sa = __shfl(ia, r);
                const int sb = __shfl(ib, r);
#pragma unroll
                for (int nt = 0; nt < 2; ++nt) {
                    const int col = wn * 32 + nt * 16 + l15;
                    pre[mt][nt][r2] = Pa[(size_t)sa * H + col] + Pb[(size_t)sb * H + col];
                }
            }
    }
    __syncthreads();

    // ---- phase 1: hidden = A @ W1 (weight regs ping-pong, static idx) ----
#pragma unroll 1
    for (int kc = 0; kc < NC; ++kc) {
        if (kc + 1 < NC) {
            if constexpr (PLANES) stage_async(kc + 1, (kc & 1) ^ 1);
            else                  stage_f32(kc + 1, (kc & 1) ^ 1);
        }
        const bf16_t* aH = (const bf16_t*)(smem + (size_t)(kc & 1) * 16384);
        const bf16_t* aL = aH + 4096;

        // ---- ks = 0: compute from A-buffer, prefetch into B-buffer ----
        {
            const int slab = kc * 2;
            if (slab + 1 < NS1)
                loadB(W1h, W1l, slab + 1, wn, lane, BhB, BlB);
#pragma unroll
            for (int mt = 0; mt < 4; ++mt) {
                const int ro = mt * 16 + l15;
                const bf16x8 Ah = *reinterpret_cast<const bf16x8*>(aH + ((l4) * 64 + ro) * 8);
                const bf16x8 Al = *reinterpret_cast<const bf16x8*>(aL + ((l4) * 64 + ro) * 8);
#pragma unroll
                for (int nt = 0; nt < 2; ++nt) {
                    acc[mt][nt] = mfma16(Al, BhA[nt], acc[mt][nt]);
                    acc[mt][nt] = mfma16(Ah, BlA[nt], acc[mt][nt]);
                    acc[mt][nt] = mfma16(Ah, BhA[nt], acc[mt][nt]);
                }
            }
        }
        // ---- ks = 1: compute from B-buffer, prefetch into A-buffer ----
        {
            const int slab = kc * 2 + 1;
            if (slab + 1 < NS1)
                loadB(W1h, W1l, slab + 1, wn, lane, BhA, BlA);
#pragma unroll
            for (int mt = 0; mt < 4; ++mt) {
                const int ro = mt * 16 + l15;
                const bf16x8 Ah = *reinterpret_cast<const bf16x8*>(aH + ((4 + l4) * 64 + ro) * 8);
                const bf16x8 Al = *reinterpret_cast<const bf16x8*>(aL + ((4 + l4) * 64 + ro) * 8);
#pragma unroll
                for (int nt = 0; nt < 2; ++nt) {
                    acc[mt][nt] = mfma16(Al, BhB[nt], acc[mt][nt]);
                    acc[mt][nt] = mfma16(Ah, BlB[nt], acc[mt][nt]);
                    acc[mt][nt] = mfma16(Ah, BhB[nt], acc[mt][nt]);
                }
            }
        }
        __syncthreads();   // drains vmcnt (async stage) + orders LDS reuse
    }

    // ---- transition: hidden = relu(acc + pre + b1 + useg) -> LDS frag ----
    {
        const int g = row0 >> gshift;
        bf16_t* sHh = (bf16_t*)smem;
        bf16_t* sHl = sHh + 8192;
#pragma unroll
        for (int mt = 0; mt < 4; ++mt)
#pragma unroll
            for (int nt = 0; nt < 2; ++nt) {
                const int col = wn * 32 + nt * 16 + l15;
                float bb = b1[col];
                if (useg) bb += useg[(size_t)g * H + col];
#pragma unroll
                for (int r2 = 0; r2 < 4; ++r2) {
                    const int rloc = mt * 16 + l4 * 4 + r2;
                    float v = acc[mt][nt][r2] + bb;
                    if constexpr (PRE) v += pre[mt][nt][r2];
                    v = v > 0.f ? v : 0.f;
                    const bf16_t h = (bf16_t)v;
                    const int sidx = (col >> 3) * 512 + rloc * 8 + (col & 7);
                    sHh[sidx] = h;
                    sHl[sidx] = (bf16_t)(v - (float)h);
                    acc[mt][nt][r2] = 0.f;
                }
            }
    }
    __syncthreads();

    // ---- phase 2: out = hidden @ W2 (fully unrolled, static idx) ----
    {
        const bf16_t* sHh = (const bf16_t*)smem;
        const bf16_t* sHl = sHh + 8192;
        loadB(W2h, W2l, 0, wn, lane, BhA, BlA);
#pragma unroll
        for (int kc2 = 0; kc2 < 4; ++kc2) {
            if (kc2 + 1 < 4) {
                if ((kc2 & 1) == 0) loadB(W2h, W2l, kc2 + 1, wn, lane, BhB, BlB);
                else                loadB(W2h, W2l, kc2 + 1, wn, lane, BhA, BlA);
            }
#pragma unroll
            for (int mt = 0; mt < 4; ++mt) {
                const int ro = mt * 16 + l15;
                const bf16x8 Ah = *reinterpret_cast<const bf16x8*>(sHh + ((kc2 * 4 + l4) * 64 + ro) * 8);
                const bf16x8 Al = *reinterpret_cast<const bf16x8*>(sHl + ((kc2 * 4 + l4) * 64 + ro) * 8);
#pragma unroll
                for (int nt = 0; nt < 2; ++nt) {
                    if ((kc2 & 1) == 0) {
                        acc[mt][nt] = mfma16(Al, BhA[nt], acc[mt][nt]);
                        acc[mt][nt] = mfma16(Ah, BlA[nt], acc[mt][nt]);
                        acc[mt][nt] = mfma16(Ah, BhA[nt], acc[mt][nt]);
                    } else {
                        acc[mt][nt] = mfma16(Al, BhB[nt], acc[mt][nt]);
                        acc[mt][nt] = mfma16(Ah, BlB[nt], acc[mt][nt]);
                        acc[mt][nt] = mfma16(Ah, BhB[nt], acc[mt][nt]);
                    }
                }
            }
        }
    }

    // ---- epilogue: bias2 + LayerNorm + affine (+ fused pool) ----
    float bb2[2], ggv[2], btv[2];
#pragma unroll
    for (int nt = 0; nt < 2; ++nt) {
        const int col = wn * 32 + nt * 16 + l15;
        bb2[nt] = b2[col]; ggv[nt] = gam[col]; btv[nt] = bet[col];
    }
#pragma unroll
    for (int mt = 0; mt < 4; ++mt)
#pragma unroll
        for (int r2 = 0; r2 < 4; ++r2) {
            float s = 0.f, q = 0.f;
#pragma unroll
            for (int nt = 0; nt < 2; ++nt) {
                const float v = acc[mt][nt][r2] + bb2[nt];
                s += v; q += v * v;
            }
            s += __shfl_xor(s, 1, 16); s += __shfl_xor(s, 2, 16);
            s += __shfl_xor(s, 4, 16); s += __shfl_xor(s, 8, 16);
            q += __shfl_xor(q, 1, 16); q += __shfl_xor(q, 2, 16);
            q += __shfl_xor(q, 4, 16); q += __shfl_xor(q, 8, 16);
            if (l15 == 0) {
                const int row = mt * 16 + l4 * 4 + r2;
                redS[wn][row] = s; redQ[wn][row] = q;
            }
        }
    __syncthreads();

    float cs[2] = {0.f, 0.f};
#pragma unroll
    for (int mt = 0; mt < 4; ++mt)
#pragma unroll
        for (int r2 = 0; r2 < 4; ++r2) {
            const int row = mt * 16 + l4 * 4 + r2;
            const float S = redS[0][row] + redS[1][row] + redS[2][row] + redS[3][row];
            const float Q = redQ[0][row] + redQ[1][row] + redQ[2][row] + redQ[3][row];
            const float mean = S * (1.f / 128.f);
            const float var  = Q * (1.f / 128.f) - mean * mean;
            const float rstd = rsqrtf(var + 1e-5f);
            bf16_t* opP = outP + (size_t)(row0 + row) * RS;
#pragma unroll
            for (int nt = 0; nt < 2; ++nt) {
                const int col = wn * 32 + nt * 16 + l15;
                const float v = acc[mt][nt][r2] + bb2[nt];
                const float o = (v - mean) * rstd * ggv[nt] + btv[nt];
                const bf16_t oh = (bf16_t)o;
                opP[col]       = oh;
                opP[col + 128] = (bf16_t)(o - (float)oh);
                if (out32) out32[(size_t)(row0 + row) * H + col] = o;
                cs[nt] += o;
            }
        }

    if (pool != nullptr) {
        const int g = row0 >> gshift;
#pragma unroll
        for (int nt = 0; nt < 2; ++nt) {
            float s = cs[nt];
            s += __shfl_xor(s, 16);
            s += __shfl_xor(s, 32);
            if (l4 == 0)
                atomicAdd(&pool[(size_t)g * H + wn * 32 + nt * 16 + l15], s * pscale);
        }
    }
}

// ---------------------------------------------------------------------------
// Input projection (fp32 in, bf16-plane out); optional input-row gather
// ---------------------------------------------------------------------------
template<int K>
__global__ __launch_bounds__(256, 2)
void proj_relu(const float* __restrict__ in, const float* __restrict__ W,
               const float* __restrict__ b, bf16_t* __restrict__ outP,
               const int* __restrict__ ridx)
{
    constexpr int LDAP = K + 4;
    __shared__ float sA[BM * LDAP];
    __shared__ float sWp[K * BN];

    const int tid = threadIdx.x;
    const int rg = tid >> 4, cg = tid & 15;
    const int m0 = rg * 4, n0 = cg * 8;
    const int row0 = blockIdx.x * BM;

    if constexpr (K == 64) {
        const int lr = tid >> 2, lc = (tid & 3) * 16;
        const int srow = ridx ? ridx[row0 + lr] : row0 + lr;
        const float* srcp = in + (size_t)srow * K + lc;
#pragma unroll
        for (int q = 0; q < 16; q += 4) st4(&sA[lr * LDAP + lc + q], ld4(srcp + q));
        const int wrk = tid >> 2, wck = (tid & 3) * 32;
        const float* wsp = W + (size_t)wrk * BN + wck;
#pragma unroll
        for (int q = 0; q < 32; q += 4) st4(&sWp[wrk * BN + wck + q], ld4(wsp + q));
    } else {
        const int lr = tid >> 2, lc = (tid & 3) * 8;
        const int srow = ridx ? ridx[row0 + lr] : row0 + lr;
        const float* srcp = in + (size_t)srow * K + lc;
        st4(&sA[lr * LDAP + lc],     ld4(srcp));
        st4(&sA[lr * LDAP + lc + 4], ld4(srcp + 4));
        const int wrk = tid >> 3, wck = (tid & 7) * 16;
        const float* wsp = W + (size_t)wrk * BN + wck;
#pragma unroll
        for (int q = 0; q < 16; q += 4) st4(&sWp[wrk * BN + wck + q], ld4(wsp + q));
    }
    __syncthreads();

    float acc[4][8];
#pragma unroll
    for (int i = 0; i < 4; ++i)
#pragma unroll
        for (int j = 0; j < 8; ++j) acc[i][j] = 0.f;

#pragma unroll 8
    for (int k = 0; k < K; ++k) {
        float a[4];
#pragma unroll
        for (int i = 0; i < 4; ++i) a[i] = sA[(m0 + i) * LDAP + k];
        const float4 wA = ld4(&sWp[k * BN + n0]);
        const float4 wB = ld4(&sWp[k * BN + n0 + 4]);
        const float w[8] = {wA.x, wA.y, wA.z, wA.w, wB.x, wB.y, wB.z, wB.w};
#pragma unroll
        for (int i = 0; i < 4; ++i)
#pragma unroll
            for (int j = 0; j < 8; ++j)
                acc[i][j] = fmaf(a[i], w[j], acc[i][j]);
    }

    const float4 bA = ld4(&b[n0]), bB = ld4(&b[n0 + 4]);
    const float bb[8] = {bA.x, bA.y, bA.z, bA.w, bB.x, bB.y, bB.z, bB.w};
#pragma unroll
    for (int i = 0; i < 4; ++i) {
        bf16x8 hv, lv;
#pragma unroll
        for (int j = 0; j < 8; ++j) {
            float v = acc[i][j] + bb[j];
            v = v > 0.f ? v : 0.f;
            const bf16_t h = (bf16_t)v;
            hv[j] = h;
            lv[j] = (bf16_t)(v - (float)h);
        }
        bf16_t* op = outP + (size_t)(row0 + m0 + i) * RS + n0;
        *reinterpret_cast<bf16x8*>(op)       = hv;
        *reinterpret_cast<bf16x8*>(op + 128) = lv;
    }
}

// ---------------------------------------------------------------------------
// Head: out[row] = relu(in[row,:] @ W1 + b1) . w2 + b2[0]; bf16-plane input
// ---------------------------------------------------------------------------
__global__ __launch_bounds__(256, 2)
void head_mlp(const bf16_t* __restrict__ inP, const float* __restrict__ W1,
              const float* __restrict__ b1, const float* __restrict__ w2,
              const float* __restrict__ b2, float* __restrict__ outp)
{
    __shared__ float sA[BM * LDA];
    __shared__ float sW[BK * BN];

    const int tid = threadIdx.x;
    const int rg = tid >> 4, cg = tid & 15;
    const int m0 = rg * 4, n0 = cg * 8;
    const int row0 = blockIdx.x * BM;
    const int lr = tid >> 2, lc = (tid & 3) * 8;
    const int wr = tid >> 3, wc = (tid & 7) * 16;

    float acc[4][8];
#pragma unroll
    for (int i = 0; i < 4; ++i)
#pragma unroll
        for (int j = 0; j < 8; ++j) acc[i][j] = 0.f;

#pragma unroll 1
    for (int kc = 0; kc < 4; ++kc) {
        const int koff = kc * 32;
        const bf16_t* rp = inP + (size_t)(row0 + lr) * RS + koff + lc;
        const bf16x8 h = *reinterpret_cast<const bf16x8*>(rp);
        const bf16x8 l = *reinterpret_cast<const bf16x8*>(rp + 128);
        float a[8];
#pragma unroll
        for (int j = 0; j < 8; ++j) a[j] = (float)h[j] + (float)l[j];
        st4(&sA[lr * LDA + lc],     make_float4(a[0], a[1], a[2], a[3]));
        st4(&sA[lr * LDA + lc + 4], make_float4(a[4], a[5], a[6], a[7]));
        const float* wsrc = W1 + (size_t)koff * BN + wr * BN + wc;
        st4(&sW[wr * BN + wc],      ld4(wsrc));
        st4(&sW[wr * BN + wc + 4],  ld4(wsrc + 4));
        st4(&sW[wr * BN + wc + 8],  ld4(wsrc + 8));
        st4(&sW[wr * BN + wc + 12], ld4(wsrc + 12));
        __syncthreads();
#pragma unroll
        for (int kk = 0; kk < BK; ++kk) {
            float a2[4];
#pragma unroll
            for (int i = 0; i < 4; ++i) a2[i] = sA[(m0 + i) * LDA + kk];
            const float4 wA = ld4(&sW[kk * BN + n0]);
            const float4 wB = ld4(&sW[kk * BN + n0 + 4]);
            const float w[8] = {wA.x, wA.y, wA.z, wA.w, wB.x, wB.y, wB.z, wB.w};
#pragma unroll
            for (int i = 0; i < 4; ++i)
#pragma unroll
                for (int j = 0; j < 8; ++j)
                    acc[i][j] = fmaf(a2[i], w[j], acc[i][j]);
        }
        __syncthreads();
    }

    const float4 bA = ld4(&b1[n0]),  bB = ld4(&b1[n0 + 4]);
    const float4 vA = ld4(&w2[n0]),  vB = ld4(&w2[n0 + 4]);
    const float bb[8] = {bA.x, bA.y, bA.z, bA.w, bB.x, bB.y, bB.z, bB.w};
    const float vv[8] = {vA.x, vA.y, vA.z, vA.w, vB.x, vB.y, vB.z, vB.w};
#pragma unroll
    for (int i = 0; i < 4; ++i) {
        float p = 0.f;
#pragma unroll
        for (int j = 0; j < 8; ++j) {
            float h = acc[i][j] + bb[j];
            h = h > 0.f ? h : 0.f;
            p = fmaf(h, vv[j], p);
        }
        p += __shfl_xor(p, 1, 16); p += __shfl_xor(p, 2, 16);
        p += __shfl_xor(p, 4, 16); p += __shfl_xor(p, 8, 16);
        if (cg == 0) outp[row0 + m0 + i] = p + b2[0];
    }
}

// ---------------------------------------------------------------------------
// CSR build (once per launch; edge_index is fixed)
// ---------------------------------------------------------------------------
__global__ void count_int_k(const int* __restrict__ dst, int* __restrict__ cnt)
{
    const int i = blockIdx.x * 256 + threadIdx.x;
    atomicAdd(&cnt[dst[i]], 1);
}

__global__ void scan_graph_k(const int* __restrict__ cnt, int* __restrict__ off)
{
    __shared__ int s[256];
    const int g = blockIdx.x;
    const int t = threadIdx.x;
    const int a = cnt[g * Pn + 2 * t];
    const int b = cnt[g * Pn + 2 * t + 1];
    s[t] = a + b;
    __syncthreads();
    for (int d = 1; d < 256; d <<= 1) {
        const int v = (t >= d) ? s[t - d] : 0;
        __syncthreads();
        s[t] += v;
        __syncthreads();
    }
    const int excl = s[t] - (a + b);
    off[g * Pn + 2 * t]     = g * EPGn + excl;
    off[g * Pn + 2 * t + 1] = g * EPGn + excl + a;
}

__global__ void place_k(const int* __restrict__ dst, const int* __restrict__ off,
                        int* __restrict__ cur, int* __restrict__ perm)
{
    const int i = blockIdx.x * 256 + threadIdx.x;
    const int d = dst[i];
    const int p = off[d] + atomicAdd(&cur[d], 1);
    perm[p] = i;
}

__global__ void sort_bucket_k(int* __restrict__ perm, const int* __restrict__ off,
                              const int* __restrict__ cnt)
{
    const int n = blockIdx.x * 256 + threadIdx.x;
    if (n >= Nn) return;
    const int o = off[n], c = cnt[n];
    for (int i = 1; i < c; ++i) {
        const int key = perm[o + i];
        int j = i - 1;
        while (j >= 0 && perm[o + j] > key) { perm[o + j + 1] = perm[o + j]; --j; }
        perm[o + j + 1] = key;
    }
}

// psrc/pdst[slot] = src/dst[perm[slot]]
__global__ void make_pidx_k(const int* __restrict__ perm, const int* __restrict__ src,
                            const int* __restrict__ dst, int* __restrict__ psrc,
                            int* __restrict__ pdst)
{
    const int s = blockIdx.x * 256 + threadIdx.x;
    const int e = perm[s];
    psrc[s] = src[e];
    pdst[s] = dst[e];
}

// agg[n] = mean of incoming edge messages; he stored in CSR-slot order, so
// node n's rows are CONTIGUOUS at slots off[n]..off[n]+cnt[n] (streaming).
__global__ __launch_bounds__(256)
void gather_agg_k(const bf16_t* __restrict__ hep, const int* __restrict__ off,
                  const int* __restrict__ cnt, bf16_t* __restrict__ aggp, int cpx)
{
    const int tid = threadIdx.x;
    const int bid = xcd_swz(blockIdx.x, cpx);
    const int n = bid * 8 + (tid >> 5);
    const int q = tid & 31;
    const int o = off[n], c = cnt[n];
    float a0 = 0.f, a1 = 0.f, a2 = 0.f, a3 = 0.f;
    const bf16_t* rp = hep + (size_t)o * RS + q * 4;
    for (int k = 0; k < c; ++k, rp += RS) {
        const bf16x4 h = *reinterpret_cast<const bf16x4*>(rp);
        const bf16x4 l = *reinterpret_cast<const bf16x4*>(rp + 128);
        a0 += (float)h[0] + (float)l[0];
        a1 += (float)h[1] + (float)l[1];
        a2 += (float)h[2] + (float)l[2];
        a3 += (float)h[3] + (float)l[3];
    }
    const float inv = 1.f / fmaxf((float)c, 1.f);
    const float v[4] = {a0 * inv, a1 * inv, a2 * inv, a3 * inv};
    bf16x4 hv, lv;
#pragma unroll
    for (int j = 0; j < 4; ++j) {
        const bf16_t h = (bf16_t)v[j];
        hv[j] = h;
        lv[j] = (bf16_t)(v[j] - (float)h);
    }
    bf16_t* op = aggp + (size_t)n * RS + q * 4;
    *reinterpret_cast<bf16x4*>(op)       = hv;
    *reinterpret_cast<bf16x4*>(op + 128) = lv;
}

// ---------------------------------------------------------------------------
// small utility kernels
// ---------------------------------------------------------------------------
__global__ void init_u_k(float* __restrict__ u, bf16_t* __restrict__ up,
                         const float* __restrict__ u0)
{
    const int idx = blockIdx.x * 256 + threadIdx.x;   // < 64*128
    const int g = idx >> 7, col = idx & 127;
    const float v = u0[col];
    u[idx] = v;
    const bf16_t h = (bf16_t)v;
    up[(size_t)g * RS + col]       = h;
    up[(size_t)g * RS + 128 + col] = (bf16_t)(v - (float)h);
}

__global__ void softmax_head_k(const float* __restrict__ logits, float* __restrict__ outp)
{
    const int g = blockIdx.x;
    const int tid = threadIdx.x;
    const float* lg = logits + (size_t)g * Pn;
    const float v0 = lg[tid], v1 = lg[tid + 256];
    float bv; int bi;
    if (v1 > v0) { bv = v1; bi = tid + 256; } else { bv = v0; bi = tid; }

    __shared__ float sv[256];
    __shared__ int   si[256];
    sv[tid] = bv; si[tid] = bi;
    __syncthreads();
    for (int s = 128; s > 0; s >>= 1) {
        if (tid < s) {
            const float ov = sv[tid + s]; const int oi = si[tid + s];
            if (ov > sv[tid] || (ov == sv[tid] && oi < si[tid])) { sv[tid] = ov; si[tid] = oi; }
        }
        __syncthreads();
    }
    const float mx = sv[0];
    const int ai = si[0];
    __syncthreads();

    const float d0 = v0 - mx, d1 = v1 - mx;
    const float e0 = __expf(d0), e1 = __expf(d1);
    __shared__ float ss[256];
    __shared__ float st[256];
    ss[tid] = e0 + e1;
    st[tid] = e0 * d0 + e1 * d1;
    __syncthreads();
    for (int s = 128; s > 0; s >>= 1) {
        if (tid < s) { ss[tid] += ss[tid + s]; st[tid] += st[tid + s]; }
        __syncthreads();
    }
    if (tid == 0) {
        const float S = ss[0];
        const float logS = logf(S);
        outp[g]            = (float)ai;
        outp[Gn + g]       = -logS;
        outp[2 * Gn + g]   = logS - st[0] / S;
    }
}

} // namespace

extern "C" void kernel_launch(void* const* d_in, const int* in_sizes, int n_in,
                              void* d_out, int out_size, void* d_ws, size_t ws_size,
                              hipStream_t stream)
{
    (void)in_sizes; (void)n_in; (void)out_size; (void)ws_size;

    const float* x     = (const float*)d_in[0];
    const float* ea    = (const float*)d_in[1];
    const int*   ei    = (const int*)d_in[2];
    const float* Wn  = (const float*)d_in[6];
    const float* bn_ = (const float*)d_in[7];
    const float* We  = (const float*)d_in[8];
    const float* be_ = (const float*)d_in[9];
    const float* u0  = (const float*)d_in[10];
    const float* eW1 = (const float*)d_in[11];
    const float* eb1 = (const float*)d_in[12];
    const float* eW2 = (const float*)d_in[13];
    const float* eb2 = (const float*)d_in[14];
    const float* eg  = (const float*)d_in[15];
    const float* ebn = (const float*)d_in[16];
    const float* nW1 = (const float*)d_in[17];
    const float* nb1 = (const float*)d_in[18];
    const float* nW2 = (const float*)d_in[19];
    const float* nb2 = (const float*)d_in[20];
    const float* ng  = (const float*)d_in[21];
    const float* nbn = (const float*)d_in[22];
    const float* gW1 = (const float*)d_in[23];
    const float* gb1 = (const float*)d_in[24];
    const float* gW2 = (const float*)d_in[25];
    const float* gb2 = (const float*)d_in[26];
    const float* gg  = (const float*)d_in[27];
    const float* gbn = (const float*)d_in[28];
    const float* aW1 = (const float*)d_in[29];
    const float* ab1 = (const float*)d_in[30];
    const float* aW2 = (const float*)d_in[31];
    const float* ab2 = (const float*)d_in[32];
    const float* cW1 = (const float*)d_in[33];
    const float* cb1 = (const float*)d_in[34];
    const float* cW2 = (const float*)d_in[35];
    const float* cb2 = (const float*)d_in[36];

    const int* srcI = ei;
    const int* dstI = ei + En;

    // workspace layout
    float* ws     = (float*)d_ws;
    float* u      = ws;                              // 64*128 fp32
    float* nmean  = u + Gn * H;                      // 64*128
    float* emean  = nmean + Gn * H;                  // 64*128
    float* usegE  = emean + Gn * H;                  // 64*128
    float* usegN  = usegE + Gn * H;                  // 64*128
    float* Pa     = usegN + Gn * H;                  // N*128 fp32
    float* Pb     = Pa + (size_t)Nn * H;             // N*128 fp32
    float* logits = Pb + (size_t)Nn * H;             // N
    int*   cnt    = (int*)(logits + Nn);             // N
    int*   off    = cnt + Nn;                        // N
    int*   cur    = off + Nn;                        // N
    int*   perm   = cur + Nn;                        // E
    int*   psrc   = perm + En;                       // E
    int*   pdst   = psrc + En;                       // E
    bf16_t* bfb  = (bf16_t*)(pdst + En);
    bf16_t* hxp  = bfb;                              // N*256
    bf16_t* hep  = hxp + (size_t)Nn * RS;            // E*256  (CSR-slot order)
    bf16_t* aggp = hep + (size_t)En * RS;            // N*256
    bf16_t* up   = aggp + (size_t)Nn * RS;           // 64*256
    bf16_t* frag = up + Gn * RS;
    bf16_t* eW1h = frag;              bf16_t* eW1l = eW1h + 384 * 128;   frag += 2 * 384 * 128;
    bf16_t* eW2h = frag;              bf16_t* eW2l = eW2h + 128 * 128;   frag += 2 * 128 * 128;
    bf16_t* nW1h = frag;              bf16_t* nW1l = nW1h + 256 * 128;   frag += 2 * 256 * 128;
    bf16_t* nW2h = frag;              bf16_t* nW2l = nW2h + 128 * 128;   frag += 2 * 128 * 128;
    bf16_t* gW1h = frag;              bf16_t* gW1l = gW1h + 384 * 128;   frag += 2 * 384 * 128;
    bf16_t* gW2h = frag;              bf16_t* gW2l = gW2h + 128 * 128;

    float* outp = (float*)d_out;

    // weight prep (eW1 rows 0-383: x-src/x-dst/e slabs; u-seg hoisted)
    prep_wfrag<<<(384 * 128) / 256, 256, 0, stream>>>(eW1, eW1h, eW1l);
    prep_wfrag<<<(128 * 128) / 256, 256, 0, stream>>>(eW2, eW2h, eW2l);
    prep_wfrag<<<(256 * 128) / 256, 256, 0, stream>>>(nW1, nW1h, nW1l);
    prep_wfrag<<<(128 * 128) / 256, 256, 0, stream>>>(nW2, nW2h, nW2l);
    prep_wfrag<<<(384 * 128) / 256, 256, 0, stream>>>(gW1, gW1h, gW1l);
    prep_wfrag<<<(128 * 128) / 256, 256, 0, stream>>>(gW2, gW2h, gW2l);

    // CSR build (dst fixed across layers); edges processed in slot order
    hipMemsetAsync(cnt, 0, Nn * sizeof(int), stream);
    hipMemsetAsync(cur, 0, Nn * sizeof(int), stream);
    count_int_k<<<En / 256, 256, 0, stream>>>(dstI, cnt);
    scan_graph_k<<<Gn, 256, 0, stream>>>(cnt, off);
    place_k<<<En / 256, 256, 0, stream>>>(dstI, off, cur, perm);
    sort_bucket_k<<<(Nn + 255) / 256, 256, 0, stream>>>(perm, off, cnt);
    make_pidx_k<<<En / 256, 256, 0, stream>>>(perm, srcI, dstI, psrc, pdst);

    // input projections + constants (edge features written in slot order)
    proj_relu<64><<<Nn / BM, 256, 0, stream>>>(x, Wn, bn_, hxp, nullptr);
    proj_relu<32><<<En / BM, 256, 0, stream>>>(ea, We, be_, hep, perm);
    init_u_k<<<(Gn * H) / 256, 256, 0, stream>>>(u, up, u0);

    for (int l = 0; l < 2; ++l) {
        // hoisted per-graph u-segment partial products (fp32 exact)
        useg_k<<<Gn, H, 0, stream>>>(u, eW1 + 384 * H, usegE);
        useg_k<<<Gn, H, 0, stream>>>(u, nW1 + 256 * H, usegN);
        // per-node partial products for edge MLP
        xpart_k<<<Nn / 64, 256, 0, stream>>>(hxp, eW1h, eW1l, Pa, Pb);
        // edge update (in-place on hep, slot order) + fused emean pool
        hipMemsetAsync(emean, 0, Gn * H * sizeof(float), stream);
        mfma_mlp_ln<1, true, true><<<En / 64, 256, 0, stream>>>(
            hep, nullptr, nullptr, nullptr, nullptr, nullptr,
            psrc, pdst, Pa, Pb,
            eW1h + 8 * SLAB, eW1l + 8 * SLAB, eW2h, eW2l, eb1, eb2, eg, ebn, usegE,
            hep, nullptr, emean, 12, 1.f / EPGn, (En / 64) / 8);
        // agg = mean of incoming edge messages (contiguous streaming read)
        gather_agg_k<<<Nn / 8, 256, 0, stream>>>(hep, off, cnt, aggp, (Nn / 8) / 8);
        // node update (in-place on hxp) + fused nmean pool
        hipMemsetAsync(nmean, 0, Gn * H * sizeof(float), stream);
        mfma_mlp_ln<2, true, false><<<Nn / 64, 256, 0, stream>>>(
            hxp, nullptr, aggp, nullptr, nullptr, nullptr,
            nullptr, nullptr, nullptr, nullptr,
            nW1h, nW1l, nW2h, nW2l, nb1, nb2, ng, nbn, usegN,
            hxp, nullptr, nmean, 9, 1.f / Pn, (Nn / 64) / 8);
        // global update (fp32 sources; writes planes + fp32 u)
        mfma_mlp_ln<3, false, false><<<1, 256, 0, stream>>>(
            u, nullptr, nmean, nullptr, emean, nullptr,
            nullptr, nullptr, nullptr, nullptr,
            gW1h, gW1l, gW2h, gW2l, gb1, gb2, gg, gbn, nullptr,
            up, u, nullptr, 0, 0.f, 0);
    }

    head_mlp<<<Nn / BM, 256, 0, stream>>>(hxp, aW1, ab1, aW2, ab2, logits);
    softmax_head_k<<<Gn, 256, 0, stream>>>(logits, outp);
    head_mlp<<<1, 256, 0, stream>>>(up, cW1, cb1, cW2, cb2, outp + 3 * Gn);
}

// Round 13
// 544.888 us; speedup vs baseline: 1.2121x; 1.2121x over previous
//
#include <hip/hip_runtime.h>
#include <cstddef>

namespace {

constexpr int Gn  = 64;
constexpr int Pn  = 512;
constexpr int EPGn= 4096;
constexpr int Nn  = Gn * Pn;    // 32768 nodes
constexpr int En  = Gn * EPGn;  // 262144 edges
constexpr int H   = 128;

constexpr int BM = 64, BK = 32, BN = 128;
constexpr int LDA = BK + 4;
constexpr int RS  = 256;        // bf16-plane row stride (hi 128 | lo 128)
constexpr int SLAB = 4096;      // elements per 32k-slab in frag layout

typedef __bf16 bf16_t;
typedef bf16_t bf16x8 __attribute__((ext_vector_type(8)));
typedef bf16_t bf16x4 __attribute__((ext_vector_type(4)));
typedef float  f32x4  __attribute__((ext_vector_type(4)));

__device__ __forceinline__ float4 ld4(const float* p) { return *reinterpret_cast<const float4*>(p); }
__device__ __forceinline__ void st4(float* p, const float4 v) { *reinterpret_cast<float4*>(p) = v; }
__device__ __forceinline__ f32x4 mfma16(bf16x8 a, bf16x8 b, f32x4 c) {
    return __builtin_amdgcn_mfma_f32_16x16x32_bf16(a, b, c, 0, 0, 0);
}

// bijective XCD swizzle: grid must be divisible by 8; cpx = grid/8
__device__ __forceinline__ int xcd_swz(int bid, int cpx)
{
    return (bid & 7) * cpx + (bid >> 3);
}

// async global->LDS, 16B per lane; LDS dest = wave-uniform base + lane*16
__device__ __forceinline__ void gload_lds16(const bf16_t* g, bf16_t* l)
{
    typedef __attribute__((address_space(1))) const unsigned int* gp_t;
    typedef __attribute__((address_space(3))) unsigned int* lp_t;
    __builtin_amdgcn_global_load_lds((gp_t)(const void*)g, (lp_t)(void*)l, 16, 0, 0);
}

// ---------------------------------------------------------------------------
// Weight prep: fp32 W[K][128] -> bf16 hi/lo in MFMA B-fragment-major layout.
// ---------------------------------------------------------------------------
__global__ void prep_wfrag(const float* __restrict__ W, bf16_t* __restrict__ Bh,
                           bf16_t* __restrict__ Bl)
{
    const int i = blockIdx.x * 256 + threadIdx.x;   // i < K*128
    const int k = i >> 7, n = i & 127;
    const float v = W[i];
    const bf16_t h = (bf16_t)v;
    const bf16_t l = (bf16_t)(v - (float)h);
    const int idx = ((((k >> 5) * 8) + (n >> 4)) * 64 + ((k >> 3) & 3) * 16 + (n & 15)) * 8 + (k & 7);
    Bh[idx] = h; Bl[idx] = l;
}

// per-graph hoisted u-segment partial product: out[g][c] = sum_k u[g][k]*W[k][c]
__global__ void useg_k(const float* __restrict__ u, const float* __restrict__ W,
                       float* __restrict__ outp)
{
    __shared__ float su[H];
    const int g = blockIdx.x, c = threadIdx.x;
    su[c] = u[g * H + c];
    __syncthreads();
    float s = 0.f;
#pragma unroll 8
    for (int k = 0; k < H; ++k) s = fmaf(su[k], W[k * H + c], s);
    outp[g * H + c] = s;
}

__device__ __forceinline__ void split8(const float4 a, const float4 b, bf16x8& h, bf16x8& l)
{
    const float v[8] = {a.x, a.y, a.z, a.w, b.x, b.y, b.z, b.w};
#pragma unroll
    for (int j = 0; j < 8; ++j) {
        const bf16_t hh = (bf16_t)v[j];
        h[j] = hh;
        l[j] = (bf16_t)(v[j] - (float)hh);
    }
}

// load one wave's 32-col weight slice for one 32-k slab (2 n-tiles, hi+lo)
__device__ __forceinline__ void loadB(const bf16_t* __restrict__ Wh, const bf16_t* __restrict__ Wl,
                                      int kc32, int wn, int lane, bf16x8* Bh, bf16x8* Bl)
{
#pragma unroll
    for (int nt = 0; nt < 2; ++nt) {
        const size_t idx = (size_t)(((kc32 * 8) + wn * 2 + nt) * 64 + lane) * 8;
        Bh[nt] = *reinterpret_cast<const bf16x8*>(Wh + idx);
        Bl[nt] = *reinterpret_cast<const bf16x8*>(Wl + idx);
    }
}

// ---------------------------------------------------------------------------
// xpart_k: per-node partial products for the edge MLP.
// Pa[n] = x[n] @ eW1[0:128] ; Pb[n] = x[n] @ eW1[128:256]  (fp32 out)
// ---------------------------------------------------------------------------
__global__ __launch_bounds__(256, 4)
void xpart_k(const bf16_t* __restrict__ xp,
             const bf16_t* __restrict__ Wh, const bf16_t* __restrict__ Wl,
             float* __restrict__ Pa, float* __restrict__ Pb)
{
    __shared__ __align__(16) char smem[32 * 1024];
    const int t = threadIdx.x, lane = t & 63, wv = t >> 6;
    const int wn = wv;
    const int l15 = lane & 15, l4 = lane >> 4;
    const int row0 = blockIdx.x * 64;

    f32x4 accA[4][2], accB[4][2];
#pragma unroll
    for (int mt = 0; mt < 4; ++mt)
#pragma unroll
        for (int nt = 0; nt < 2; ++nt) { accA[mt][nt] = (f32x4)0.f; accB[mt][nt] = (f32x4)0.f; }

    auto stage = [&](int kc, int bufi) {
        const bf16_t* rp = xp + (size_t)(row0 + lane) * RS + kc * 64 + wv * 8;
        bf16_t* base = (bf16_t*)(smem + bufi * 16384);
        gload_lds16(rp,       base + wv * 512);
        gload_lds16(rp + 32,  base + (wv + 4) * 512);
        gload_lds16(rp + 128, base + 4096 + wv * 512);
        gload_lds16(rp + 160, base + 4096 + (wv + 4) * 512);
    };

    stage(0, 0);
    stage(1, 1);
    __syncthreads();

#pragma unroll
    for (int kc = 0; kc < 2; ++kc) {
        const bf16_t* aH = (const bf16_t*)(smem + (size_t)kc * 16384);
        const bf16_t* aL = aH + 4096;
#pragma unroll
        for (int ks = 0; ks < 2; ++ks) {
            const int slab = kc * 2 + ks;
            bf16x8 BhA[2], BlA[2], BhB[2], BlB[2];
            loadB(Wh, Wl, slab,     wn, lane, BhA, BlA);
            loadB(Wh, Wl, slab + 4, wn, lane, BhB, BlB);
#pragma unroll
            for (int mt = 0; mt < 4; ++mt) {
                const int ro = mt * 16 + l15;
                const bf16x8 Ah = *reinterpret_cast<const bf16x8*>(aH + ((ks * 4 + l4) * 64 + ro) * 8);
                const bf16x8 Al = *reinterpret_cast<const bf16x8*>(aL + ((ks * 4 + l4) * 64 + ro) * 8);
#pragma unroll
                for (int nt = 0; nt < 2; ++nt) {
                    accA[mt][nt] = mfma16(Al, BhA[nt], accA[mt][nt]);
                    accA[mt][nt] = mfma16(Ah, BlA[nt], accA[mt][nt]);
                    accA[mt][nt] = mfma16(Ah, BhA[nt], accA[mt][nt]);
                    accB[mt][nt] = mfma16(Al, BhB[nt], accB[mt][nt]);
                    accB[mt][nt] = mfma16(Ah, BlB[nt], accB[mt][nt]);
                    accB[mt][nt] = mfma16(Ah, BhB[nt], accB[mt][nt]);
                }
            }
        }
    }

#pragma unroll
    for (int mt = 0; mt < 4; ++mt)
#pragma unroll
        for (int r2 = 0; r2 < 4; ++r2) {
            const int row = mt * 16 + l4 * 4 + r2;
#pragma unroll
            for (int nt = 0; nt < 2; ++nt) {
                const int col = wn * 32 + nt * 16 + l15;
                Pa[(size_t)(row0 + row) * H + col] = accA[mt][nt][r2];
                Pb[(size_t)(row0 + row) * H + col] = accB[mt][nt][r2];
            }
        }
}

// ---------------------------------------------------------------------------
// MFMA fused 2-layer MLP + LN, bf16x3 precision.
// 4-way N-split waves; weight registers prefetched one slab ahead (static idx).
// PRE=true: acc initialized with gathered fp32 Pa[iA]+Pb[iB] (R11-proven: no
// long-live-range pre[] regs -> no spill); staging seg0 is direct.
// ---------------------------------------------------------------------------
template<int NSEG, bool PLANES, bool PRE>
__global__ __launch_bounds__(256, 4)
void mfma_mlp_ln(const void* __restrict__ p0v, const int* __restrict__ i0,
                 const void* __restrict__ p1v, const int* __restrict__ i1,
                 const void* __restrict__ p2v, const int* __restrict__ i2,
                 const int* __restrict__ iA, const int* __restrict__ iB,
                 const float* __restrict__ Pa, const float* __restrict__ Pb,
                 const bf16_t* __restrict__ W1h, const bf16_t* __restrict__ W1l,
                 const bf16_t* __restrict__ W2h, const bf16_t* __restrict__ W2l,
                 const float* __restrict__ b1, const float* __restrict__ b2,
                 const float* __restrict__ gam, const float* __restrict__ bet,
                 const float* __restrict__ useg,
                 bf16_t* __restrict__ outP, float* __restrict__ out32,
                 float* __restrict__ pool, int gshift, float pscale, int cpx)
{
    // Overlay: phase1 A-tiles (2 bufs x [hi 8KB | lo 8KB]) alias phase2 hidden.
    __shared__ __align__(16) char smem[32 * 1024];
    __shared__ float redS[4][64], redQ[4][64];

    const int t = threadIdx.x;
    const int lane = t & 63;
    const int wv = t >> 6;          // wave id == staging k-subgroup == wn
    const int wn = wv;              // 4-way N split
    const int l15 = lane & 15, l4 = lane >> 4;
    const int bid = (cpx > 0) ? xcd_swz(blockIdx.x, cpx) : blockIdx.x;
    const int row0 = bid * 64;

    // staging row indices per segment (PRE: seg0 is direct)
    const int s0 = (PRE || !i0) ? row0 + lane : i0[row0 + lane];
    const int s1 = (NSEG > 1) ? (i1 ? i1[row0 + lane] : row0 + lane) : 0;
    const int s2 = (NSEG > 2) ? (i2 ? i2[row0 + lane] : row0 + lane) : 0;

    f32x4 acc[4][2];
#pragma unroll
    for (int mt = 0; mt < 4; ++mt)
#pragma unroll
        for (int nt = 0; nt < 2; ++nt) acc[mt][nt] = (f32x4)0.f;

    constexpr int NC = NSEG * 2;    // 64-wide K chunks
    constexpr int NS1 = NC * 2;     // 32-wide K slabs in phase 1

    auto stage_async = [&](int kc, int bufi) {
        const int seg = kc >> 1, kh = kc & 1;
        const bf16_t* p; int srow;
        if (seg == 0)      { p = (const bf16_t*)p0v; srow = s0; }
        else if (seg == 1) { p = (const bf16_t*)p1v; srow = s1; }
        else               { p = (const bf16_t*)p2v; srow = s2; }
        const bf16_t* rp = p + (size_t)srow * RS + kh * 64 + wv * 8;
        bf16_t* base = (bf16_t*)(smem + bufi * 16384);
        gload_lds16(rp,        base + wv * 512);              // hi, kg=wv
        gload_lds16(rp + 32,   base + (wv + 4) * 512);        // hi, kg=wv+4
        gload_lds16(rp + 128,  base + 4096 + wv * 512);       // lo, kg=wv
        gload_lds16(rp + 160,  base + 4096 + (wv + 4) * 512); // lo, kg=wv+4
    };

    auto stage_f32 = [&](int kc, int bufi) {
        const int seg = kc >> 1, kh = kc & 1;
        const float* p; int srow;
        if (seg == 0)      { p = (const float*)p0v; srow = s0; }
        else if (seg == 1) { p = (const float*)p1v; srow = s1; }
        else               { p = (const float*)p2v; srow = s2; }
        const float* sp = p + (size_t)srow * H + kh * 64 + wv * 8;
        bf16_t* base = (bf16_t*)(smem + bufi * 16384);
        bf16x8 h, l;
        split8(ld4(sp), ld4(sp + 4), h, l);
        *reinterpret_cast<bf16x8*>(base + ((wv)     * 64 + lane) * 8) = h;
        *reinterpret_cast<bf16x8*>(base + 4096 + ((wv)     * 64 + lane) * 8) = l;
        split8(ld4(sp + 32), ld4(sp + 36), h, l);
        *reinterpret_cast<bf16x8*>(base + ((wv + 4) * 64 + lane) * 8) = h;
        *reinterpret_cast<bf16x8*>(base + 4096 + ((wv + 4) * 64 + lane) * 8) = l;
    };

    // named static double buffers for weight prefetch (rule #20 safe)
    bf16x8 BhA[2], BlA[2], BhB[2], BlB[2];
    loadB(W1h, W1l, 0, wn, lane, BhA, BlA);
    if constexpr (PLANES) stage_async(0, 0); else stage_f32(0, 0);

    // PRE: init acc with gathered per-node partials (consumed immediately
    // into acc -> short live range, no spill; R11-proven at 117 us)
    if constexpr (PRE) {
        const int ia = iA[row0 + lane];
        const int ib = iB[row0 + lane];
#pragma unroll
        for (int mt = 0; mt < 4; ++mt)
#pragma unroll
            for (int r2 = 0; r2 < 4; ++r2) {
                const int r = mt * 16 + l4 * 4 + r2;
                const int sa = __shfl(ia, r);
                const int sb = __shfl(ib, r);
#pragma unroll
                for (int nt = 0; nt < 2; ++nt) {
                    const int col = wn * 32 + nt * 16 + l15;
                    acc[mt][nt][r2] = Pa[(size_t)sa * H + col] + Pb[(size_t)sb * H + col];
                }
            }
    }
    __syncthreads();

    // ---- phase 1: hidden = A @ W1 (weight regs ping-pong, static idx) ----
#pragma unroll 1
    for (int kc = 0; kc < NC; ++kc) {
        if (kc + 1 < NC) {
            if constexpr (PLANES) stage_async(kc + 1, (kc & 1) ^ 1);
            else                  stage_f32(kc + 1, (kc & 1) ^ 1);
        }
        const bf16_t* aH = (const bf16_t*)(smem + (size_t)(kc & 1) * 16384);
        const bf16_t* aL = aH + 4096;

        // ---- ks = 0: compute from A-buffer, prefetch into B-buffer ----
        {
            const int slab = kc * 2;
            if (slab + 1 < NS1)
                loadB(W1h, W1l, slab + 1, wn, lane, BhB, BlB);
#pragma unroll
            for (int mt = 0; mt < 4; ++mt) {
                const int ro = mt * 16 + l15;
                const bf16x8 Ah = *reinterpret_cast<const bf16x8*>(aH + ((l4) * 64 + ro) * 8);
                const bf16x8 Al = *reinterpret_cast<const bf16x8*>(aL + ((l4) * 64 + ro) * 8);
#pragma unroll
                for (int nt = 0; nt < 2; ++nt) {
                    acc[mt][nt] = mfma16(Al, BhA[nt], acc[mt][nt]);
                    acc[mt][nt] = mfma16(Ah, BlA[nt], acc[mt][nt]);
                    acc[mt][nt] = mfma16(Ah, BhA[nt], acc[mt][nt]);
                }
            }
        }
        // ---- ks = 1: compute from B-buffer, prefetch into A-buffer ----
        {
            const int slab = kc * 2 + 1;
            if (slab + 1 < NS1)
                loadB(W1h, W1l, slab + 1, wn, lane, BhA, BlA);
#pragma unroll
            for (int mt = 0; mt < 4; ++mt) {
                const int ro = mt * 16 + l15;
                const bf16x8 Ah = *reinterpret_cast<const bf16x8*>(aH + ((4 + l4) * 64 + ro) * 8);
                const bf16x8 Al = *reinterpret_cast<const bf16x8*>(aL + ((4 + l4) * 64 + ro) * 8);
#pragma unroll
                for (int nt = 0; nt < 2; ++nt) {
                    acc[mt][nt] = mfma16(Al, BhB[nt], acc[mt][nt]);
                    acc[mt][nt] = mfma16(Ah, BlB[nt], acc[mt][nt]);
                    acc[mt][nt] = mfma16(Ah, BhB[nt], acc[mt][nt]);
                }
            }
        }
        __syncthreads();   // drains vmcnt (async stage) + orders LDS reuse
    }

    // ---- transition: hidden = relu(acc + b1 + useg), split -> LDS frag ----
    {
        const int g = row0 >> gshift;
        bf16_t* sHh = (bf16_t*)smem;
        bf16_t* sHl = sHh + 8192;
#pragma unroll
        for (int mt = 0; mt < 4; ++mt)
#pragma unroll
            for (int nt = 0; nt < 2; ++nt) {
                const int col = wn * 32 + nt * 16 + l15;
                float bb = b1[col];
                if (useg) bb += useg[(size_t)g * H + col];
#pragma unroll
                for (int r2 = 0; r2 < 4; ++r2) {
                    const int rloc = mt * 16 + l4 * 4 + r2;
                    float v = acc[mt][nt][r2] + bb;
                    v = v > 0.f ? v : 0.f;
                    const bf16_t h = (bf16_t)v;
                    const int sidx = (col >> 3) * 512 + rloc * 8 + (col & 7);
                    sHh[sidx] = h;
                    sHl[sidx] = (bf16_t)(v - (float)h);
                    acc[mt][nt][r2] = 0.f;
                }
            }
    }
    __syncthreads();

    // ---- phase 2: out = hidden @ W2 (fully unrolled, static idx) ----
    {
        const bf16_t* sHh = (const bf16_t*)smem;
        const bf16_t* sHl = sHh + 8192;
        loadB(W2h, W2l, 0, wn, lane, BhA, BlA);
#pragma unroll
        for (int kc2 = 0; kc2 < 4; ++kc2) {
            if (kc2 + 1 < 4) {
                if ((kc2 & 1) == 0) loadB(W2h, W2l, kc2 + 1, wn, lane, BhB, BlB);
                else                loadB(W2h, W2l, kc2 + 1, wn, lane, BhA, BlA);
            }
#pragma unroll
            for (int mt = 0; mt < 4; ++mt) {
                const int ro = mt * 16 + l15;
                const bf16x8 Ah = *reinterpret_cast<const bf16x8*>(sHh + ((kc2 * 4 + l4) * 64 + ro) * 8);
                const bf16x8 Al = *reinterpret_cast<const bf16x8*>(sHl + ((kc2 * 4 + l4) * 64 + ro) * 8);
#pragma unroll
                for (int nt = 0; nt < 2; ++nt) {
                    if ((kc2 & 1) == 0) {
                        acc[mt][nt] = mfma16(Al, BhA[nt], acc[mt][nt]);
                        acc[mt][nt] = mfma16(Ah, BlA[nt], acc[mt][nt]);
                        acc[mt][nt] = mfma16(Ah, BhA[nt], acc[mt][nt]);
                    } else {
                        acc[mt][nt] = mfma16(Al, BhB[nt], acc[mt][nt]);
                        acc[mt][nt] = mfma16(Ah, BlB[nt], acc[mt][nt]);
                        acc[mt][nt] = mfma16(Ah, BhB[nt], acc[mt][nt]);
                    }
                }
            }
        }
    }

    // ---- epilogue: bias2 + LayerNorm + affine (+ fused pool) ----
    float bb2[2], ggv[2], btv[2];
#pragma unroll
    for (int nt = 0; nt < 2; ++nt) {
        const int col = wn * 32 + nt * 16 + l15;
        bb2[nt] = b2[col]; ggv[nt] = gam[col]; btv[nt] = bet[col];
    }
#pragma unroll
    for (int mt = 0; mt < 4; ++mt)
#pragma unroll
        for (int r2 = 0; r2 < 4; ++r2) {
            float s = 0.f, q = 0.f;
#pragma unroll
            for (int nt = 0; nt < 2; ++nt) {
                const float v = acc[mt][nt][r2] + bb2[nt];
                s += v; q += v * v;
            }
            s += __shfl_xor(s, 1, 16); s += __shfl_xor(s, 2, 16);
            s += __shfl_xor(s, 4, 16); s += __shfl_xor(s, 8, 16);
            q += __shfl_xor(q, 1, 16); q += __shfl_xor(q, 2, 16);
            q += __shfl_xor(q, 4, 16); q += __shfl_xor(q, 8, 16);
            if (l15 == 0) {
                const int row = mt * 16 + l4 * 4 + r2;
                redS[wn][row] = s; redQ[wn][row] = q;
            }
        }
    __syncthreads();

    float cs[2] = {0.f, 0.f};
#pragma unroll
    for (int mt = 0; mt < 4; ++mt)
#pragma unroll
        for (int r2 = 0; r2 < 4; ++r2) {
            const int row = mt * 16 + l4 * 4 + r2;
            const float S = redS[0][row] + redS[1][row] + redS[2][row] + redS[3][row];
            const float Q = redQ[0][row] + redQ[1][row] + redQ[2][row] + redQ[3][row];
            const float mean = S * (1.f / 128.f);
            const float var  = Q * (1.f / 128.f) - mean * mean;
            const float rstd = rsqrtf(var + 1e-5f);
            bf16_t* opP = outP + (size_t)(row0 + row) * RS;
#pragma unroll
            for (int nt = 0; nt < 2; ++nt) {
                const int col = wn * 32 + nt * 16 + l15;
                const float v = acc[mt][nt][r2] + bb2[nt];
                const float o = (v - mean) * rstd * ggv[nt] + btv[nt];
                const bf16_t oh = (bf16_t)o;
                opP[col]       = oh;
                opP[col + 128] = (bf16_t)(o - (float)oh);
                if (out32) out32[(size_t)(row0 + row) * H + col] = o;
                cs[nt] += o;
            }
        }

    if (pool != nullptr) {
        const int g = row0 >> gshift;
#pragma unroll
        for (int nt = 0; nt < 2; ++nt) {
            float s = cs[nt];
            s += __shfl_xor(s, 16);
            s += __shfl_xor(s, 32);
            if (l4 == 0)
                atomicAdd(&pool[(size_t)g * H + wn * 32 + nt * 16 + l15], s * pscale);
        }
    }
}

// ---------------------------------------------------------------------------
// Input projection (fp32 in, bf16-plane out); optional input-row gather
// ---------------------------------------------------------------------------
template<int K>
__global__ __launch_bounds__(256, 2)
void proj_relu(const float* __restrict__ in, const float* __restrict__ W,
               const float* __restrict__ b, bf16_t* __restrict__ outP,
               const int* __restrict__ ridx)
{
    constexpr int LDAP = K + 4;
    __shared__ float sA[BM * LDAP];
    __shared__ float sWp[K * BN];

    const int tid = threadIdx.x;
    const int rg = tid >> 4, cg = tid & 15;
    const int m0 = rg * 4, n0 = cg * 8;
    const int row0 = blockIdx.x * BM;

    if constexpr (K == 64) {
        const int lr = tid >> 2, lc = (tid & 3) * 16;
        const int srow = ridx ? ridx[row0 + lr] : row0 + lr;
        const float* srcp = in + (size_t)srow * K + lc;
#pragma unroll
        for (int q = 0; q < 16; q += 4) st4(&sA[lr * LDAP + lc + q], ld4(srcp + q));
        const int wrk = tid >> 2, wck = (tid & 3) * 32;
        const float* wsp = W + (size_t)wrk * BN + wck;
#pragma unroll
        for (int q = 0; q < 32; q += 4) st4(&sWp[wrk * BN + wck + q], ld4(wsp + q));
    } else {
        const int lr = tid >> 2, lc = (tid & 3) * 8;
        const int srow = ridx ? ridx[row0 + lr] : row0 + lr;
        const float* srcp = in + (size_t)srow * K + lc;
        st4(&sA[lr * LDAP + lc],     ld4(srcp));
        st4(&sA[lr * LDAP + lc + 4], ld4(srcp + 4));
        const int wrk = tid >> 3, wck = (tid & 7) * 16;
        const float* wsp = W + (size_t)wrk * BN + wck;
#pragma unroll
        for (int q = 0; q < 16; q += 4) st4(&sWp[wrk * BN + wck + q], ld4(wsp + q));
    }
    __syncthreads();

    float acc[4][8];
#pragma unroll
    for (int i = 0; i < 4; ++i)
#pragma unroll
        for (int j = 0; j < 8; ++j) acc[i][j] = 0.f;

#pragma unroll 8
    for (int k = 0; k < K; ++k) {
        float a[4];
#pragma unroll
        for (int i = 0; i < 4; ++i) a[i] = sA[(m0 + i) * LDAP + k];
        const float4 wA = ld4(&sWp[k * BN + n0]);
        const float4 wB = ld4(&sWp[k * BN + n0 + 4]);
        const float w[8] = {wA.x, wA.y, wA.z, wA.w, wB.x, wB.y, wB.z, wB.w};
#pragma unroll
        for (int i = 0; i < 4; ++i)
#pragma unroll
            for (int j = 0; j < 8; ++j)
                acc[i][j] = fmaf(a[i], w[j], acc[i][j]);
    }

    const float4 bA = ld4(&b[n0]), bB = ld4(&b[n0 + 4]);
    const float bb[8] = {bA.x, bA.y, bA.z, bA.w, bB.x, bB.y, bB.z, bB.w};
#pragma unroll
    for (int i = 0; i < 4; ++i) {
        bf16x8 hv, lv;
#pragma unroll
        for (int j = 0; j < 8; ++j) {
            float v = acc[i][j] + bb[j];
            v = v > 0.f ? v : 0.f;
            const bf16_t h = (bf16_t)v;
            hv[j] = h;
            lv[j] = (bf16_t)(v - (float)h);
        }
        bf16_t* op = outP + (size_t)(row0 + m0 + i) * RS + n0;
        *reinterpret_cast<bf16x8*>(op)       = hv;
        *reinterpret_cast<bf16x8*>(op + 128) = lv;
    }
}

// ---------------------------------------------------------------------------
// Head: out[row] = relu(in[row,:] @ W1 + b1) . w2 + b2[0]; bf16-plane input
// ---------------------------------------------------------------------------
__global__ __launch_bounds__(256, 2)
void head_mlp(const bf16_t* __restrict__ inP, const float* __restrict__ W1,
              const float* __restrict__ b1, const float* __restrict__ w2,
              const float* __restrict__ b2, float* __restrict__ outp)
{
    __shared__ float sA[BM * LDA];
    __shared__ float sW[BK * BN];

    const int tid = threadIdx.x;
    const int rg = tid >> 4, cg = tid & 15;
    const int m0 = rg * 4, n0 = cg * 8;
    const int row0 = blockIdx.x * BM;
    const int lr = tid >> 2, lc = (tid & 3) * 8;
    const int wr = tid >> 3, wc = (tid & 7) * 16;

    float acc[4][8];
#pragma unroll
    for (int i = 0; i < 4; ++i)
#pragma unroll
        for (int j = 0; j < 8; ++j) acc[i][j] = 0.f;

#pragma unroll 1
    for (int kc = 0; kc < 4; ++kc) {
        const int koff = kc * 32;
        const bf16_t* rp = inP + (size_t)(row0 + lr) * RS + koff + lc;
        const bf16x8 h = *reinterpret_cast<const bf16x8*>(rp);
        const bf16x8 l = *reinterpret_cast<const bf16x8*>(rp + 128);
        float a[8];
#pragma unroll
        for (int j = 0; j < 8; ++j) a[j] = (float)h[j] + (float)l[j];
        st4(&sA[lr * LDA + lc],     make_float4(a[0], a[1], a[2], a[3]));
        st4(&sA[lr * LDA + lc + 4], make_float4(a[4], a[5], a[6], a[7]));
        const float* wsrc = W1 + (size_t)koff * BN + wr * BN + wc;
        st4(&sW[wr * BN + wc],      ld4(wsrc));
        st4(&sW[wr * BN + wc + 4],  ld4(wsrc + 4));
        st4(&sW[wr * BN + wc + 8],  ld4(wsrc + 8));
        st4(&sW[wr * BN + wc + 12], ld4(wsrc + 12));
        __syncthreads();
#pragma unroll
        for (int kk = 0; kk < BK; ++kk) {
            float a2[4];
#pragma unroll
            for (int i = 0; i < 4; ++i) a2[i] = sA[(m0 + i) * LDA + kk];
            const float4 wA = ld4(&sW[kk * BN + n0]);
            const float4 wB = ld4(&sW[kk * BN + n0 + 4]);
            const float w[8] = {wA.x, wA.y, wA.z, wA.w, wB.x, wB.y, wB.z, wB.w};
#pragma unroll
            for (int i = 0; i < 4; ++i)
#pragma unroll
                for (int j = 0; j < 8; ++j)
                    acc[i][j] = fmaf(a2[i], w[j], acc[i][j]);
        }
        __syncthreads();
    }

    const float4 bA = ld4(&b1[n0]),  bB = ld4(&b1[n0 + 4]);
    const float4 vA = ld4(&w2[n0]),  vB = ld4(&w2[n0 + 4]);
    const float bb[8] = {bA.x, bA.y, bA.z, bA.w, bB.x, bB.y, bB.z, bB.w};
    const float vv[8] = {vA.x, vA.y, vA.z, vA.w, vB.x, vB.y, vB.z, vB.w};
#pragma unroll
    for (int i = 0; i < 4; ++i) {
        float p = 0.f;
#pragma unroll
        for (int j = 0; j < 8; ++j) {
            float h = acc[i][j] + bb[j];
            h = h > 0.f ? h : 0.f;
            p = fmaf(h, vv[j], p);
        }
        p += __shfl_xor(p, 1, 16); p += __shfl_xor(p, 2, 16);
        p += __shfl_xor(p, 4, 16); p += __shfl_xor(p, 8, 16);
        if (cg == 0) outp[row0 + m0 + i] = p + b2[0];
    }
}

// ---------------------------------------------------------------------------
// CSR build (once per launch; edge_index is fixed)
// ---------------------------------------------------------------------------
__global__ void count_int_k(const int* __restrict__ dst, int* __restrict__ cnt)
{
    const int i = blockIdx.x * 256 + threadIdx.x;
    atomicAdd(&cnt[dst[i]], 1);
}

__global__ void scan_graph_k(const int* __restrict__ cnt, int* __restrict__ off)
{
    __shared__ int s[256];
    const int g = blockIdx.x;
    const int t = threadIdx.x;
    const int a = cnt[g * Pn + 2 * t];
    const int b = cnt[g * Pn + 2 * t + 1];
    s[t] = a + b;
    __syncthreads();
    for (int d = 1; d < 256; d <<= 1) {
        const int v = (t >= d) ? s[t - d] : 0;
        __syncthreads();
        s[t] += v;
        __syncthreads();
    }
    const int excl = s[t] - (a + b);
    off[g * Pn + 2 * t]     = g * EPGn + excl;
    off[g * Pn + 2 * t + 1] = g * EPGn + excl + a;
}

__global__ void place_k(const int* __restrict__ dst, const int* __restrict__ off,
                        int* __restrict__ cur, int* __restrict__ perm)
{
    const int i = blockIdx.x * 256 + threadIdx.x;
    const int d = dst[i];
    const int p = off[d] + atomicAdd(&cur[d], 1);
    perm[p] = i;
}

__global__ void sort_bucket_k(int* __restrict__ perm, const int* __restrict__ off,
                              const int* __restrict__ cnt)
{
    const int n = blockIdx.x * 256 + threadIdx.x;
    if (n >= Nn) return;
    const int o = off[n], c = cnt[n];
    for (int i = 1; i < c; ++i) {
        const int key = perm[o + i];
        int j = i - 1;
        while (j >= 0 && perm[o + j] > key) { perm[o + j + 1] = perm[o + j]; --j; }
        perm[o + j + 1] = key;
    }
}

// psrc/pdst[slot] = src/dst[perm[slot]]
__global__ void make_pidx_k(const int* __restrict__ perm, const int* __restrict__ src,
                            const int* __restrict__ dst, int* __restrict__ psrc,
                            int* __restrict__ pdst)
{
    const int s = blockIdx.x * 256 + threadIdx.x;
    const int e = perm[s];
    psrc[s] = src[e];
    pdst[s] = dst[e];
}

// agg[n] = mean of incoming edge messages; he stored in CSR-slot order, so
// node n's rows are CONTIGUOUS at slots off[n]..off[n]+cnt[n] (streaming).
__global__ __launch_bounds__(256)
void gather_agg_k(const bf16_t* __restrict__ hep, const int* __restrict__ off,
                  const int* __restrict__ cnt, bf16_t* __restrict__ aggp, int cpx)
{
    const int tid = threadIdx.x;
    const int bid = xcd_swz(blockIdx.x, cpx);
    const int n = bid * 8 + (tid >> 5);
    const int q = tid & 31;
    const int o = off[n], c = cnt[n];
    float a0 = 0.f, a1 = 0.f, a2 = 0.f, a3 = 0.f;
    const bf16_t* rp = hep + (size_t)o * RS + q * 4;
    for (int k = 0; k < c; ++k, rp += RS) {
        const bf16x4 h = *reinterpret_cast<const bf16x4*>(rp);
        const bf16x4 l = *reinterpret_cast<const bf16x4*>(rp + 128);
        a0 += (float)h[0] + (float)l[0];
        a1 += (float)h[1] + (float)l[1];
        a2 += (float)h[2] + (float)l[2];
        a3 += (float)h[3] + (float)l[3];
    }
    const float inv = 1.f / fmaxf((float)c, 1.f);
    const float v[4] = {a0 * inv, a1 * inv, a2 * inv, a3 * inv};
    bf16x4 hv, lv;
#pragma unroll
    for (int j = 0; j < 4; ++j) {
        const bf16_t h = (bf16_t)v[j];
        hv[j] = h;
        lv[j] = (bf16_t)(v[j] - (float)h);
    }
    bf16_t* op = aggp + (size_t)n * RS + q * 4;
    *reinterpret_cast<bf16x4*>(op)       = hv;
    *reinterpret_cast<bf16x4*>(op + 128) = lv;
}

// ---------------------------------------------------------------------------
// small utility kernels
// ---------------------------------------------------------------------------
__global__ void init_u_k(float* __restrict__ u, bf16_t* __restrict__ up,
                         const float* __restrict__ u0)
{
    const int idx = blockIdx.x * 256 + threadIdx.x;   // < 64*128
    const int g = idx >> 7, col = idx & 127;
    const float v = u0[col];
    u[idx] = v;
    const bf16_t h = (bf16_t)v;
    up[(size_t)g * RS + col]       = h;
    up[(size_t)g * RS + 128 + col] = (bf16_t)(v - (float)h);
}

__global__ void softmax_head_k(const float* __restrict__ logits, float* __restrict__ outp)
{
    const int g = blockIdx.x;
    const int tid = threadIdx.x;
    const float* lg = logits + (size_t)g * Pn;
    const float v0 = lg[tid], v1 = lg[tid + 256];
    float bv; int bi;
    if (v1 > v0) { bv = v1; bi = tid + 256; } else { bv = v0; bi = tid; }

    __shared__ float sv[256];
    __shared__ int   si[256];
    sv[tid] = bv; si[tid] = bi;
    __syncthreads();
    for (int s = 128; s > 0; s >>= 1) {
        if (tid < s) {
            const float ov = sv[tid + s]; const int oi = si[tid + s];
            if (ov > sv[tid] || (ov == sv[tid] && oi < si[tid])) { sv[tid] = ov; si[tid] = oi; }
        }
        __syncthreads();
    }
    const float mx = sv[0];
    const int ai = si[0];
    __syncthreads();

    const float d0 = v0 - mx, d1 = v1 - mx;
    const float e0 = __expf(d0), e1 = __expf(d1);
    __shared__ float ss[256];
    __shared__ float st[256];
    ss[tid] = e0 + e1;
    st[tid] = e0 * d0 + e1 * d1;
    __syncthreads();
    for (int s = 128; s > 0; s >>= 1) {
        if (tid < s) { ss[tid] += ss[tid + s]; st[tid] += st[tid + s]; }
        __syncthreads();
    }
    if (tid == 0) {
        const float S = ss[0];
        const float logS = logf(S);
        outp[g]            = (float)ai;
        outp[Gn + g]       = -logS;
        outp[2 * Gn + g]   = logS - st[0] / S;
    }
}

} // namespace

extern "C" void kernel_launch(void* const* d_in, const int* in_sizes, int n_in,
                              void* d_out, int out_size, void* d_ws, size_t ws_size,
                              hipStream_t stream)
{
    (void)in_sizes; (void)n_in; (void)out_size; (void)ws_size;

    const float* x     = (const float*)d_in[0];
    const float* ea    = (const float*)d_in[1];
    const int*   ei    = (const int*)d_in[2];
    const float* Wn  = (const float*)d_in[6];
    const float* bn_ = (const float*)d_in[7];
    const float* We  = (const float*)d_in[8];
    const float* be_ = (const float*)d_in[9];
    const float* u0  = (const float*)d_in[10];
    const float* eW1 = (const float*)d_in[11];
    const float* eb1 = (const float*)d_in[12];
    const float* eW2 = (const float*)d_in[13];
    const float* eb2 = (const float*)d_in[14];
    const float* eg  = (const float*)d_in[15];
    const float* ebn = (const float*)d_in[16];
    const float* nW1 = (const float*)d_in[17];
    const float* nb1 = (const float*)d_in[18];
    const float* nW2 = (const float*)d_in[19];
    const float* nb2 = (const float*)d_in[20];
    const float* ng  = (const float*)d_in[21];
    const float* nbn = (const float*)d_in[22];
    const float* gW1 = (const float*)d_in[23];
    const float* gb1 = (const float*)d_in[24];
    const float* gW2 = (const float*)d_in[25];
    const float* gb2 = (const float*)d_in[26];
    const float* gg  = (const float*)d_in[27];
    const float* gbn = (const float*)d_in[28];
    const float* aW1 = (const float*)d_in[29];
    const float* ab1 = (const float*)d_in[30];
    const float* aW2 = (const float*)d_in[31];
    const float* ab2 = (const float*)d_in[32];
    const float* cW1 = (const float*)d_in[33];
    const float* cb1 = (const float*)d_in[34];
    const float* cW2 = (const float*)d_in[35];
    const float* cb2 = (const float*)d_in[36];

    const int* srcI = ei;
    const int* dstI = ei + En;

    // workspace layout
    float* ws     = (float*)d_ws;
    float* u      = ws;                              // 64*128 fp32
    float* nmean  = u + Gn * H;                      // 64*128
    float* emean  = nmean + Gn * H;                  // 64*128
    float* usegE  = emean + Gn * H;                  // 64*128
    float* usegN  = usegE + Gn * H;                  // 64*128
    float* Pa     = usegN + Gn * H;                  // N*128 fp32
    float* Pb     = Pa + (size_t)Nn * H;             // N*128 fp32
    float* logits = Pb + (size_t)Nn * H;             // N
    int*   cnt    = (int*)(logits + Nn);             // N
    int*   off    = cnt + Nn;                        // N
    int*   cur    = off + Nn;                        // N
    int*   perm   = cur + Nn;                        // E
    int*   psrc   = perm + En;                       // E
    int*   pdst   = psrc + En;                       // E
    bf16_t* bfb  = (bf16_t*)(pdst + En);
    bf16_t* hxp  = bfb;                              // N*256
    bf16_t* hep  = hxp + (size_t)Nn * RS;            // E*256  (CSR-slot order)
    bf16_t* aggp = hep + (size_t)En * RS;            // N*256
    bf16_t* up   = aggp + (size_t)Nn * RS;           // 64*256
    bf16_t* frag = up + Gn * RS;
    bf16_t* eW1h = frag;              bf16_t* eW1l = eW1h + 384 * 128;   frag += 2 * 384 * 128;
    bf16_t* eW2h = frag;              bf16_t* eW2l = eW2h + 128 * 128;   frag += 2 * 128 * 128;
    bf16_t* nW1h = frag;              bf16_t* nW1l = nW1h + 256 * 128;   frag += 2 * 256 * 128;
    bf16_t* nW2h = frag;              bf16_t* nW2l = nW2h + 128 * 128;   frag += 2 * 128 * 128;
    bf16_t* gW1h = frag;              bf16_t* gW1l = gW1h + 384 * 128;   frag += 2 * 384 * 128;
    bf16_t* gW2h = frag;              bf16_t* gW2l = gW2h + 128 * 128;

    float* outp = (float*)d_out;

    // weight prep (eW1 rows 0-383: x-src/x-dst/e slabs; u-seg hoisted)
    prep_wfrag<<<(384 * 128) / 256, 256, 0, stream>>>(eW1, eW1h, eW1l);
    prep_wfrag<<<(128 * 128) / 256, 256, 0, stream>>>(eW2, eW2h, eW2l);
    prep_wfrag<<<(256 * 128) / 256, 256, 0, stream>>>(nW1, nW1h, nW1l);
    prep_wfrag<<<(128 * 128) / 256, 256, 0, stream>>>(nW2, nW2h, nW2l);
    prep_wfrag<<<(384 * 128) / 256, 256, 0, stream>>>(gW1, gW1h, gW1l);
    prep_wfrag<<<(128 * 128) / 256, 256, 0, stream>>>(gW2, gW2h, gW2l);

    // CSR build (dst fixed across layers); edges processed in slot order
    hipMemsetAsync(cnt, 0, Nn * sizeof(int), stream);
    hipMemsetAsync(cur, 0, Nn * sizeof(int), stream);
    count_int_k<<<En / 256, 256, 0, stream>>>(dstI, cnt);
    scan_graph_k<<<Gn, 256, 0, stream>>>(cnt, off);
    place_k<<<En / 256, 256, 0, stream>>>(dstI, off, cur, perm);
    sort_bucket_k<<<(Nn + 255) / 256, 256, 0, stream>>>(perm, off, cnt);
    make_pidx_k<<<En / 256, 256, 0, stream>>>(perm, srcI, dstI, psrc, pdst);

    // input projections + constants (edge features written in slot order)
    proj_relu<64><<<Nn / BM, 256, 0, stream>>>(x, Wn, bn_, hxp, nullptr);
    proj_relu<32><<<En / BM, 256, 0, stream>>>(ea, We, be_, hep, perm);
    init_u_k<<<(Gn * H) / 256, 256, 0, stream>>>(u, up, u0);

    for (int l = 0; l < 2; ++l) {
        // hoisted per-graph u-segment partial products (fp32 exact)
        useg_k<<<Gn, H, 0, stream>>>(u, eW1 + 384 * H, usegE);
        useg_k<<<Gn, H, 0, stream>>>(u, nW1 + 256 * H, usegN);
        // per-node partial products for edge MLP
        xpart_k<<<Nn / 64, 256, 0, stream>>>(hxp, eW1h, eW1l, Pa, Pb);
        // edge update (in-place on hep, slot order) + fused emean pool
        hipMemsetAsync(emean, 0, Gn * H * sizeof(float), stream);
        mfma_mlp_ln<1, true, true><<<En / 64, 256, 0, stream>>>(
            hep, nullptr, nullptr, nullptr, nullptr, nullptr,
            psrc, pdst, Pa, Pb,
            eW1h + 8 * SLAB, eW1l + 8 * SLAB, eW2h, eW2l, eb1, eb2, eg, ebn, usegE,
            hep, nullptr, emean, 12, 1.f / EPGn, (En / 64) / 8);
        // agg = mean of incoming edge messages (contiguous streaming read)
        gather_agg_k<<<Nn / 8, 256, 0, stream>>>(hep, off, cnt, aggp, (Nn / 8) / 8);
        // node update (in-place on hxp) + fused nmean pool
        hipMemsetAsync(nmean, 0, Gn * H * sizeof(float), stream);
        mfma_mlp_ln<2, true, false><<<Nn / 64, 256, 0, stream>>>(
            hxp, nullptr, aggp, nullptr, nullptr, nullptr,
            nullptr, nullptr, nullptr, nullptr,
            nW1h, nW1l, nW2h, nW2l, nb1, nb2, ng, nbn, usegN,
            hxp, nullptr, nmean, 9, 1.f / Pn, (Nn / 64) / 8);
        // global update (fp32 sources; writes planes + fp32 u)
        mfma_mlp_ln<3, false, false><<<1, 256, 0, stream>>>(
            u, nullptr, nmean, nullptr, emean, nullptr,
            nullptr, nullptr, nullptr, nullptr,
            gW1h, gW1l, gW2h, gW2l, gb1, gb2, gg, gbn, nullptr,
            up, u, nullptr, 0, 0.f, 0);
    }

    head_mlp<<<Nn / BM, 256, 0, stream>>>(hxp, aW1, ab1, aW2, ab2, logits);
    softmax_head_k<<<Gn, 256, 0, stream>>>(logits, outp);
    head_mlp<<<1, 256, 0, stream>>>(up, cW1, cb1, cW2, cb2, outp + 3 * Gn);
}

// Round 14
// 523.458 us; speedup vs baseline: 1.2617x; 1.0409x over previous
//
#include <hip/hip_runtime.h>
#include <cstddef>

namespace {

constexpr int Gn  = 64;
constexpr int Pn  = 512;
constexpr int EPGn= 4096;
constexpr int Nn  = Gn * Pn;    // 32768 nodes
constexpr int En  = Gn * EPGn;  // 262144 edges
constexpr int H   = 128;

constexpr int BM = 64, BK = 32, BN = 128;
constexpr int LDA = BK + 4;
constexpr int RS  = 256;        // bf16-plane row stride (hi 128 | lo 128)
constexpr int SLAB = 4096;      // elements per 32k-slab in frag layout

typedef __bf16 bf16_t;
typedef bf16_t bf16x8 __attribute__((ext_vector_type(8)));
typedef bf16_t bf16x4 __attribute__((ext_vector_type(4)));
typedef float  f32x4  __attribute__((ext_vector_type(4)));

__device__ __forceinline__ float4 ld4(const float* p) { return *reinterpret_cast<const float4*>(p); }
__device__ __forceinline__ void st4(float* p, const float4 v) { *reinterpret_cast<float4*>(p) = v; }
__device__ __forceinline__ f32x4 mfma16(bf16x8 a, bf16x8 b, f32x4 c) {
    return __builtin_amdgcn_mfma_f32_16x16x32_bf16(a, b, c, 0, 0, 0);
}

// bijective XCD swizzle: grid must be divisible by 8; cpx = grid/8
__device__ __forceinline__ int xcd_swz(int bid, int cpx)
{
    return (bid & 7) * cpx + (bid >> 3);
}

// async global->LDS, 16B per lane; LDS dest = wave-uniform base + lane*16
__device__ __forceinline__ void gload_lds16(const bf16_t* g, bf16_t* l)
{
    typedef __attribute__((address_space(1))) const unsigned int* gp_t;
    typedef __attribute__((address_space(3))) unsigned int* lp_t;
    __builtin_amdgcn_global_load_lds((gp_t)(const void*)g, (lp_t)(void*)l, 16, 0, 0);
}

// ---------------------------------------------------------------------------
// Weight prep: fp32 W[K][128] -> bf16 hi/lo in MFMA B-fragment-major layout.
// ---------------------------------------------------------------------------
__global__ void prep_wfrag(const float* __restrict__ W, bf16_t* __restrict__ Bh,
                           bf16_t* __restrict__ Bl)
{
    const int i = blockIdx.x * 256 + threadIdx.x;   // i < K*128
    const int k = i >> 7, n = i & 127;
    const float v = W[i];
    const bf16_t h = (bf16_t)v;
    const bf16_t l = (bf16_t)(v - (float)h);
    const int idx = ((((k >> 5) * 8) + (n >> 4)) * 64 + ((k >> 3) & 3) * 16 + (n & 15)) * 8 + (k & 7);
    Bh[idx] = h; Bl[idx] = l;
}

// merged per-graph hoisted u-segment partials: blocks 0-63 -> E, 64-127 -> N
__global__ void useg2_k(const float* __restrict__ u, const float* __restrict__ WE,
                        const float* __restrict__ WN, float* __restrict__ outE,
                        float* __restrict__ outN)
{
    __shared__ float su[H];
    const bool isE = blockIdx.x < Gn;
    const int g = isE ? blockIdx.x : blockIdx.x - Gn;
    const int c = threadIdx.x;
    const float* W = isE ? WE : WN;
    float* outp = isE ? outE : outN;
    su[c] = u[g * H + c];
    __syncthreads();
    float s = 0.f;
#pragma unroll 8
    for (int k = 0; k < H; ++k) s = fmaf(su[k], W[k * H + c], s);
    outp[g * H + c] = s;
}

__device__ __forceinline__ void split8(const float4 a, const float4 b, bf16x8& h, bf16x8& l)
{
    const float v[8] = {a.x, a.y, a.z, a.w, b.x, b.y, b.z, b.w};
#pragma unroll
    for (int j = 0; j < 8; ++j) {
        const bf16_t hh = (bf16_t)v[j];
        h[j] = hh;
        l[j] = (bf16_t)(v[j] - (float)hh);
    }
}

// load one wave's 32-col weight slice for one 32-k slab (2 n-tiles, hi+lo)
__device__ __forceinline__ void loadB(const bf16_t* __restrict__ Wh, const bf16_t* __restrict__ Wl,
                                      int kc32, int wn, int lane, bf16x8* Bh, bf16x8* Bl)
{
#pragma unroll
    for (int nt = 0; nt < 2; ++nt) {
        const size_t idx = (size_t)(((kc32 * 8) + wn * 2 + nt) * 64 + lane) * 8;
        Bh[nt] = *reinterpret_cast<const bf16x8*>(Wh + idx);
        Bl[nt] = *reinterpret_cast<const bf16x8*>(Wl + idx);
    }
}

// ---------------------------------------------------------------------------
// xpart_k: per-node partial products for the edge MLP.
// Pa[n] = x[n] @ eW1[0:128] ; Pb[n] = x[n] @ eW1[128:256]  (fp32 out)
// ---------------------------------------------------------------------------
__global__ __launch_bounds__(256, 4)
void xpart_k(const bf16_t* __restrict__ xp,
             const bf16_t* __restrict__ Wh, const bf16_t* __restrict__ Wl,
             float* __restrict__ Pa, float* __restrict__ Pb)
{
    __shared__ __align__(16) char smem[32 * 1024];
    const int t = threadIdx.x, lane = t & 63, wv = t >> 6;
    const int wn = wv;
    const int l15 = lane & 15, l4 = lane >> 4;
    const int row0 = blockIdx.x * 64;

    f32x4 accA[4][2], accB[4][2];
#pragma unroll
    for (int mt = 0; mt < 4; ++mt)
#pragma unroll
        for (int nt = 0; nt < 2; ++nt) { accA[mt][nt] = (f32x4)0.f; accB[mt][nt] = (f32x4)0.f; }

    auto stage = [&](int kc, int bufi) {
        const bf16_t* rp = xp + (size_t)(row0 + lane) * RS + kc * 64 + wv * 8;
        bf16_t* base = (bf16_t*)(smem + bufi * 16384);
        gload_lds16(rp,       base + wv * 512);
        gload_lds16(rp + 32,  base + (wv + 4) * 512);
        gload_lds16(rp + 128, base + 4096 + wv * 512);
        gload_lds16(rp + 160, base + 4096 + (wv + 4) * 512);
    };

    stage(0, 0);
    stage(1, 1);
    __syncthreads();

#pragma unroll
    for (int kc = 0; kc < 2; ++kc) {
        const bf16_t* aH = (const bf16_t*)(smem + (size_t)kc * 16384);
        const bf16_t* aL = aH + 4096;
#pragma unroll
        for (int ks = 0; ks < 2; ++ks) {
            const int slab = kc * 2 + ks;
            bf16x8 BhA[2], BlA[2], BhB[2], BlB[2];
            loadB(Wh, Wl, slab,     wn, lane, BhA, BlA);
            loadB(Wh, Wl, slab + 4, wn, lane, BhB, BlB);
#pragma unroll
            for (int mt = 0; mt < 4; ++mt) {
                const int ro = mt * 16 + l15;
                const bf16x8 Ah = *reinterpret_cast<const bf16x8*>(aH + ((ks * 4 + l4) * 64 + ro) * 8);
                const bf16x8 Al = *reinterpret_cast<const bf16x8*>(aL + ((ks * 4 + l4) * 64 + ro) * 8);
#pragma unroll
                for (int nt = 0; nt < 2; ++nt) {
                    accA[mt][nt] = mfma16(Al, BhA[nt], accA[mt][nt]);
                    accA[mt][nt] = mfma16(Ah, BlA[nt], accA[mt][nt]);
                    accA[mt][nt] = mfma16(Ah, BhA[nt], accA[mt][nt]);
                    accB[mt][nt] = mfma16(Al, BhB[nt], accB[mt][nt]);
                    accB[mt][nt] = mfma16(Ah, BlB[nt], accB[mt][nt]);
                    accB[mt][nt] = mfma16(Ah, BhB[nt], accB[mt][nt]);
                }
            }
        }
    }

#pragma unroll
    for (int mt = 0; mt < 4; ++mt)
#pragma unroll
        for (int r2 = 0; r2 < 4; ++r2) {
            const int row = mt * 16 + l4 * 4 + r2;
#pragma unroll
            for (int nt = 0; nt < 2; ++nt) {
                const int col = wn * 32 + nt * 16 + l15;
                Pa[(size_t)(row0 + row) * H + col] = accA[mt][nt][r2];
                Pb[(size_t)(row0 + row) * H + col] = accB[mt][nt][r2];
            }
        }
}

// ---------------------------------------------------------------------------
// proj32_mfma_k: he[slot] = relu(ea[perm[slot]] @ We + be), K=32, bf16x3.
// ---------------------------------------------------------------------------
__global__ __launch_bounds__(256, 4)
void proj32_mfma_k(const float* __restrict__ in, const int* __restrict__ ridx,
                   const bf16_t* __restrict__ Wh, const bf16_t* __restrict__ Wl,
                   const float* __restrict__ b, bf16_t* __restrict__ outP)
{
    __shared__ __align__(16) bf16_t sA[2][2048];   // [hi/lo] 4KB each
    const int t = threadIdx.x, lane = t & 63, wv = t >> 6;
    const int wn = wv;
    const int l15 = lane & 15, l4 = lane >> 4;
    const int row0 = blockIdx.x * 64;

    const int srow = ridx ? ridx[row0 + lane] : row0 + lane;
    const float* sp = in + (size_t)srow * 32 + wv * 8;
    bf16x8 h8, l8;
    split8(ld4(sp), ld4(sp + 4), h8, l8);
    *reinterpret_cast<bf16x8*>(&sA[0][(wv * 64 + lane) * 8]) = h8;
    *reinterpret_cast<bf16x8*>(&sA[1][(wv * 64 + lane) * 8]) = l8;
    __syncthreads();

    f32x4 acc[4][2];
#pragma unroll
    for (int mt = 0; mt < 4; ++mt)
#pragma unroll
        for (int nt = 0; nt < 2; ++nt) acc[mt][nt] = (f32x4)0.f;

    bf16x8 Bh[2], Bl[2];
    loadB(Wh, Wl, 0, wn, lane, Bh, Bl);
#pragma unroll
    for (int mt = 0; mt < 4; ++mt) {
        const int ro = mt * 16 + l15;
        const bf16x8 Ah = *reinterpret_cast<const bf16x8*>(&sA[0][(l4 * 64 + ro) * 8]);
        const bf16x8 Al = *reinterpret_cast<const bf16x8*>(&sA[1][(l4 * 64 + ro) * 8]);
#pragma unroll
        for (int nt = 0; nt < 2; ++nt) {
            acc[mt][nt] = mfma16(Al, Bh[nt], acc[mt][nt]);
            acc[mt][nt] = mfma16(Ah, Bl[nt], acc[mt][nt]);
            acc[mt][nt] = mfma16(Ah, Bh[nt], acc[mt][nt]);
        }
    }

    float bb[2];
#pragma unroll
    for (int nt = 0; nt < 2; ++nt) bb[nt] = b[wn * 32 + nt * 16 + l15];
#pragma unroll
    for (int mt = 0; mt < 4; ++mt)
#pragma unroll
        for (int r2 = 0; r2 < 4; ++r2) {
            const int row = mt * 16 + l4 * 4 + r2;
            bf16_t* opP = outP + (size_t)(row0 + row) * RS;
#pragma unroll
            for (int nt = 0; nt < 2; ++nt) {
                const int col = wn * 32 + nt * 16 + l15;
                float v = acc[mt][nt][r2] + bb[nt];
                v = v > 0.f ? v : 0.f;
                const bf16_t oh = (bf16_t)v;
                opP[col]       = oh;
                opP[col + 128] = (bf16_t)(v - (float)oh);
            }
        }
}

// ---------------------------------------------------------------------------
// head_mfma_k: logits[row] = relu(x[row] @ aW1 + ab1) . aW2 + ab2, bf16x3.
// ---------------------------------------------------------------------------
__global__ __launch_bounds__(256, 4)
void head_mfma_k(const bf16_t* __restrict__ xp,
                 const bf16_t* __restrict__ W1h, const bf16_t* __restrict__ W1l,
                 const float* __restrict__ b1, const float* __restrict__ w2,
                 const float* __restrict__ b2, float* __restrict__ logits)
{
    __shared__ __align__(16) char smem[32 * 1024];
    __shared__ float redS[4][64];
    const int t = threadIdx.x, lane = t & 63, wv = t >> 6;
    const int wn = wv;
    const int l15 = lane & 15, l4 = lane >> 4;
    const int row0 = blockIdx.x * 64;

    f32x4 acc[4][2];
#pragma unroll
    for (int mt = 0; mt < 4; ++mt)
#pragma unroll
        for (int nt = 0; nt < 2; ++nt) acc[mt][nt] = (f32x4)0.f;

    auto stage = [&](int kh, int bufi) {
        const bf16_t* rp = xp + (size_t)(row0 + lane) * RS + kh * 64 + wv * 8;
        bf16_t* base = (bf16_t*)(smem + bufi * 16384);
        gload_lds16(rp,       base + wv * 512);
        gload_lds16(rp + 32,  base + (wv + 4) * 512);
        gload_lds16(rp + 128, base + 4096 + wv * 512);
        gload_lds16(rp + 160, base + 4096 + (wv + 4) * 512);
    };
    stage(0, 0);
    stage(1, 1);
    __syncthreads();

#pragma unroll
    for (int kc = 0; kc < 2; ++kc) {
        const bf16_t* aH = (const bf16_t*)(smem + (size_t)kc * 16384);
        const bf16_t* aL = aH + 4096;
#pragma unroll
        for (int ks = 0; ks < 2; ++ks) {
            bf16x8 Bh[2], Bl[2];
            loadB(W1h, W1l, kc * 2 + ks, wn, lane, Bh, Bl);
#pragma unroll
            for (int mt = 0; mt < 4; ++mt) {
                const int ro = mt * 16 + l15;
                const bf16x8 Ah = *reinterpret_cast<const bf16x8*>(aH + ((ks * 4 + l4) * 64 + ro) * 8);
                const bf16x8 Al = *reinterpret_cast<const bf16x8*>(aL + ((ks * 4 + l4) * 64 + ro) * 8);
#pragma unroll
                for (int nt = 0; nt < 2; ++nt) {
                    acc[mt][nt] = mfma16(Al, Bh[nt], acc[mt][nt]);
                    acc[mt][nt] = mfma16(Ah, Bl[nt], acc[mt][nt]);
                    acc[mt][nt] = mfma16(Ah, Bh[nt], acc[mt][nt]);
                }
            }
        }
    }

    float bb[2], vv[2];
#pragma unroll
    for (int nt = 0; nt < 2; ++nt) {
        const int col = wn * 32 + nt * 16 + l15;
        bb[nt] = b1[col]; vv[nt] = w2[col];
    }
#pragma unroll
    for (int mt = 0; mt < 4; ++mt)
#pragma unroll
        for (int r2 = 0; r2 < 4; ++r2) {
            float pp = 0.f;
#pragma unroll
            for (int nt = 0; nt < 2; ++nt) {
                float h = acc[mt][nt][r2] + bb[nt];
                h = h > 0.f ? h : 0.f;
                pp = fmaf(h, vv[nt], pp);
            }
            pp += __shfl_xor(pp, 1, 16); pp += __shfl_xor(pp, 2, 16);
            pp += __shfl_xor(pp, 4, 16); pp += __shfl_xor(pp, 8, 16);
            if (l15 == 0) redS[wn][mt * 16 + l4 * 4 + r2] = pp;
        }
    __syncthreads();
    if (t < 64)
        logits[row0 + t] = redS[0][t] + redS[1][t] + redS[2][t] + redS[3][t] + b2[0];
}

// ---------------------------------------------------------------------------
// MFMA fused 2-layer MLP + LN, bf16x3 precision. (R13-proven)
// ---------------------------------------------------------------------------
template<int NSEG, bool PLANES, bool PRE>
__global__ __launch_bounds__(256, 4)
void mfma_mlp_ln(const void* __restrict__ p0v, const int* __restrict__ i0,
                 const void* __restrict__ p1v, const int* __restrict__ i1,
                 const void* __restrict__ p2v, const int* __restrict__ i2,
                 const int* __restrict__ iA, const int* __restrict__ iB,
                 const float* __restrict__ Pa, const float* __restrict__ Pb,
                 const bf16_t* __restrict__ W1h, const bf16_t* __restrict__ W1l,
                 const bf16_t* __restrict__ W2h, const bf16_t* __restrict__ W2l,
                 const float* __restrict__ b1, const float* __restrict__ b2,
                 const float* __restrict__ gam, const float* __restrict__ bet,
                 const float* __restrict__ useg,
                 bf16_t* __restrict__ outP, float* __restrict__ out32,
                 float* __restrict__ pool, int gshift, float pscale, int cpx)
{
    __shared__ __align__(16) char smem[32 * 1024];
    __shared__ float redS[4][64], redQ[4][64];

    const int t = threadIdx.x;
    const int lane = t & 63;
    const int wv = t >> 6;
    const int wn = wv;
    const int l15 = lane & 15, l4 = lane >> 4;
    const int bid = (cpx > 0) ? xcd_swz(blockIdx.x, cpx) : blockIdx.x;
    const int row0 = bid * 64;

    const int s0 = (PRE || !i0) ? row0 + lane : i0[row0 + lane];
    const int s1 = (NSEG > 1) ? (i1 ? i1[row0 + lane] : row0 + lane) : 0;
    const int s2 = (NSEG > 2) ? (i2 ? i2[row0 + lane] : row0 + lane) : 0;

    f32x4 acc[4][2];
#pragma unroll
    for (int mt = 0; mt < 4; ++mt)
#pragma unroll
        for (int nt = 0; nt < 2; ++nt) acc[mt][nt] = (f32x4)0.f;

    constexpr int NC = NSEG * 2;
    constexpr int NS1 = NC * 2;

    auto stage_async = [&](int kc, int bufi) {
        const int seg = kc >> 1, kh = kc & 1;
        const bf16_t* p; int srow;
        if (seg == 0)      { p = (const bf16_t*)p0v; srow = s0; }
        else if (seg == 1) { p = (const bf16_t*)p1v; srow = s1; }
        else               { p = (const bf16_t*)p2v; srow = s2; }
        const bf16_t* rp = p + (size_t)srow * RS + kh * 64 + wv * 8;
        bf16_t* base = (bf16_t*)(smem + bufi * 16384);
        gload_lds16(rp,        base + wv * 512);
        gload_lds16(rp + 32,   base + (wv + 4) * 512);
        gload_lds16(rp + 128,  base + 4096 + wv * 512);
        gload_lds16(rp + 160,  base + 4096 + (wv + 4) * 512);
    };

    auto stage_f32 = [&](int kc, int bufi) {
        const int seg = kc >> 1, kh = kc & 1;
        const float* p; int srow;
        if (seg == 0)      { p = (const float*)p0v; srow = s0; }
        else if (seg == 1) { p = (const float*)p1v; srow = s1; }
        else               { p = (const float*)p2v; srow = s2; }
        const float* sp = p + (size_t)srow * H + kh * 64 + wv * 8;
        bf16_t* base = (bf16_t*)(smem + bufi * 16384);
        bf16x8 h, l;
        split8(ld4(sp), ld4(sp + 4), h, l);
        *reinterpret_cast<bf16x8*>(base + ((wv)     * 64 + lane) * 8) = h;
        *reinterpret_cast<bf16x8*>(base + 4096 + ((wv)     * 64 + lane) * 8) = l;
        split8(ld4(sp + 32), ld4(sp + 36), h, l);
        *reinterpret_cast<bf16x8*>(base + ((wv + 4) * 64 + lane) * 8) = h;
        *reinterpret_cast<bf16x8*>(base + 4096 + ((wv + 4) * 64 + lane) * 8) = l;
    };

    bf16x8 BhA[2], BlA[2], BhB[2], BlB[2];
    loadB(W1h, W1l, 0, wn, lane, BhA, BlA);
    if constexpr (PLANES) stage_async(0, 0); else stage_f32(0, 0);

    if constexpr (PRE) {
        const int ia = iA[row0 + lane];
        const int ib = iB[row0 + lane];
#pragma unroll
        for (int mt = 0; mt < 4; ++mt)
#pragma unroll
            for (int r2 = 0; r2 < 4; ++r2) {
                const int r = mt * 16 + l4 * 4 + r2;
                const int sa = __shfl(ia, r);
                const int sb = __shfl(ib, r);
#pragma unroll
                for (int nt = 0; nt < 2; ++nt) {
                    const int col = wn * 32 + nt * 16 + l15;
                    acc[mt][nt][r2] = Pa[(size_t)sa * H + col] + Pb[(size_t)sb * H + col];
                }
            }
    }
    __syncthreads();

#pragma unroll 1
    for (int kc = 0; kc < NC; ++kc) {
        if (kc + 1 < NC) {
            if constexpr (PLANES) stage_async(kc + 1, (kc & 1) ^ 1);
            else                  stage_f32(kc + 1, (kc & 1) ^ 1);
        }
        const bf16_t* aH = (const bf16_t*)(smem + (size_t)(kc & 1) * 16384);
        const bf16_t* aL = aH + 4096;

        {
            const int slab = kc * 2;
            if (slab + 1 < NS1)
                loadB(W1h, W1l, slab + 1, wn, lane, BhB, BlB);
#pragma unroll
            for (int mt = 0; mt < 4; ++mt) {
                const int ro = mt * 16 + l15;
                const bf16x8 Ah = *reinterpret_cast<const bf16x8*>(aH + ((l4) * 64 + ro) * 8);
                const bf16x8 Al = *reinterpret_cast<const bf16x8*>(aL + ((l4) * 64 + ro) * 8);
#pragma unroll
                for (int nt = 0; nt < 2; ++nt) {
                    acc[mt][nt] = mfma16(Al, BhA[nt], acc[mt][nt]);
                    acc[mt][nt] = mfma16(Ah, BlA[nt], acc[mt][nt]);
                    acc[mt][nt] = mfma16(Ah, BhA[nt], acc[mt][nt]);
                }
            }
        }
        {
            const int slab = kc * 2 + 1;
            if (slab + 1 < NS1)
                loadB(W1h, W1l, slab + 1, wn, lane, BhA, BlA);
#pragma unroll
            for (int mt = 0; mt < 4; ++mt) {
                const int ro = mt * 16 + l15;
                const bf16x8 Ah = *reinterpret_cast<const bf16x8*>(aH + ((4 + l4) * 64 + ro) * 8);
                const bf16x8 Al = *reinterpret_cast<const bf16x8*>(aL + ((4 + l4) * 64 + ro) * 8);
#pragma unroll
                for (int nt = 0; nt < 2; ++nt) {
                    acc[mt][nt] = mfma16(Al, BhB[nt], acc[mt][nt]);
                    acc[mt][nt] = mfma16(Ah, BlB[nt], acc[mt][nt]);
                    acc[mt][nt] = mfma16(Ah, BhB[nt], acc[mt][nt]);
                }
            }
        }
        __syncthreads();
    }

    // ---- transition: hidden = relu(acc + b1 + useg), split -> LDS frag ----
    {
        const int g = row0 >> gshift;
        bf16_t* sHh = (bf16_t*)smem;
        bf16_t* sHl = sHh + 8192;
#pragma unroll
        for (int mt = 0; mt < 4; ++mt)
#pragma unroll
            for (int nt = 0; nt < 2; ++nt) {
                const int col = wn * 32 + nt * 16 + l15;
                float bb = b1[col];
                if (useg) bb += useg[(size_t)g * H + col];
#pragma unroll
                for (int r2 = 0; r2 < 4; ++r2) {
                    const int rloc = mt * 16 + l4 * 4 + r2;
                    float v = acc[mt][nt][r2] + bb;
                    v = v > 0.f ? v : 0.f;
                    const bf16_t h = (bf16_t)v;
                    const int sidx = (col >> 3) * 512 + rloc * 8 + (col & 7);
                    sHh[sidx] = h;
                    sHl[sidx] = (bf16_t)(v - (float)h);
                    acc[mt][nt][r2] = 0.f;
                }
            }
    }
    __syncthreads();

    // ---- phase 2: out = hidden @ W2 ----
    {
        const bf16_t* sHh = (const bf16_t*)smem;
        const bf16_t* sHl = sHh + 8192;
        loadB(W2h, W2l, 0, wn, lane, BhA, BlA);
#pragma unroll
        for (int kc2 = 0; kc2 < 4; ++kc2) {
            if (kc2 + 1 < 4) {
                if ((kc2 & 1) == 0) loadB(W2h, W2l, kc2 + 1, wn, lane, BhB, BlB);
                else                loadB(W2h, W2l, kc2 + 1, wn, lane, BhA, BlA);
            }
#pragma unroll
            for (int mt = 0; mt < 4; ++mt) {
                const int ro = mt * 16 + l15;
                const bf16x8 Ah = *reinterpret_cast<const bf16x8*>(sHh + ((kc2 * 4 + l4) * 64 + ro) * 8);
                const bf16x8 Al = *reinterpret_cast<const bf16x8*>(sHl + ((kc2 * 4 + l4) * 64 + ro) * 8);
#pragma unroll
                for (int nt = 0; nt < 2; ++nt) {
                    if ((kc2 & 1) == 0) {
                        acc[mt][nt] = mfma16(Al, BhA[nt], acc[mt][nt]);
                        acc[mt][nt] = mfma16(Ah, BlA[nt], acc[mt][nt]);
                        acc[mt][nt] = mfma16(Ah, BhA[nt], acc[mt][nt]);
                    } else {
                        acc[mt][nt] = mfma16(Al, BhB[nt], acc[mt][nt]);
                        acc[mt][nt] = mfma16(Ah, BlB[nt], acc[mt][nt]);
                        acc[mt][nt] = mfma16(Ah, BhB[nt], acc[mt][nt]);
                    }
                }
            }
        }
    }

    // ---- epilogue: bias2 + LayerNorm + affine (+ fused pool) ----
    float bb2[2], ggv[2], btv[2];
#pragma unroll
    for (int nt = 0; nt < 2; ++nt) {
        const int col = wn * 32 + nt * 16 + l15;
        bb2[nt] = b2[col]; ggv[nt] = gam[col]; btv[nt] = bet[col];
    }
#pragma unroll
    for (int mt = 0; mt < 4; ++mt)
#pragma unroll
        for (int r2 = 0; r2 < 4; ++r2) {
            float s = 0.f, q = 0.f;
#pragma unroll
            for (int nt = 0; nt < 2; ++nt) {
                const float v = acc[mt][nt][r2] + bb2[nt];
                s += v; q += v * v;
            }
            s += __shfl_xor(s, 1, 16); s += __shfl_xor(s, 2, 16);
            s += __shfl_xor(s, 4, 16); s += __shfl_xor(s, 8, 16);
            q += __shfl_xor(q, 1, 16); q += __shfl_xor(q, 2, 16);
            q += __shfl_xor(q, 4, 16); q += __shfl_xor(q, 8, 16);
            if (l15 == 0) {
                const int row = mt * 16 + l4 * 4 + r2;
                redS[wn][row] = s; redQ[wn][row] = q;
            }
        }
    __syncthreads();

    float cs[2] = {0.f, 0.f};
#pragma unroll
    for (int mt = 0; mt < 4; ++mt)
#pragma unroll
        for (int r2 = 0; r2 < 4; ++r2) {
            const int row = mt * 16 + l4 * 4 + r2;
            const float S = redS[0][row] + redS[1][row] + redS[2][row] + redS[3][row];
            const float Q = redQ[0][row] + redQ[1][row] + redQ[2][row] + redQ[3][row];
            const float mean = S * (1.f / 128.f);
            const float var  = Q * (1.f / 128.f) - mean * mean;
            const float rstd = rsqrtf(var + 1e-5f);
            bf16_t* opP = outP + (size_t)(row0 + row) * RS;
#pragma unroll
            for (int nt = 0; nt < 2; ++nt) {
                const int col = wn * 32 + nt * 16 + l15;
                const float v = acc[mt][nt][r2] + bb2[nt];
                const float o = (v - mean) * rstd * ggv[nt] + btv[nt];
                const bf16_t oh = (bf16_t)o;
                opP[col]       = oh;
                opP[col + 128] = (bf16_t)(o - (float)oh);
                if (out32) out32[(size_t)(row0 + row) * H + col] = o;
                cs[nt] += o;
            }
        }

    if (pool != nullptr) {
        const int g = row0 >> gshift;
#pragma unroll
        for (int nt = 0; nt < 2; ++nt) {
            float s = cs[nt];
            s += __shfl_xor(s, 16);
            s += __shfl_xor(s, 32);
            if (l4 == 0)
                atomicAdd(&pool[(size_t)g * H + wn * 32 + nt * 16 + l15], s * pscale);
        }
    }
}

// ---------------------------------------------------------------------------
// Input projection (fp32 in, bf16-plane out) — node features (K=64)
// ---------------------------------------------------------------------------
template<int K>
__global__ __launch_bounds__(256, 2)
void proj_relu(const float* __restrict__ in, const float* __restrict__ W,
               const float* __restrict__ b, bf16_t* __restrict__ outP,
               const int* __restrict__ ridx)
{
    constexpr int LDAP = K + 4;
    __shared__ float sA[BM * LDAP];
    __shared__ float sWp[K * BN];

    const int tid = threadIdx.x;
    const int rg = tid >> 4, cg = tid & 15;
    const int m0 = rg * 4, n0 = cg * 8;
    const int row0 = blockIdx.x * BM;

    if constexpr (K == 64) {
        const int lr = tid >> 2, lc = (tid & 3) * 16;
        const int srow = ridx ? ridx[row0 + lr] : row0 + lr;
        const float* srcp = in + (size_t)srow * K + lc;
#pragma unroll
        for (int q = 0; q < 16; q += 4) st4(&sA[lr * LDAP + lc + q], ld4(srcp + q));
        const int wrk = tid >> 2, wck = (tid & 3) * 32;
        const float* wsp = W + (size_t)wrk * BN + wck;
#pragma unroll
        for (int q = 0; q < 32; q += 4) st4(&sWp[wrk * BN + wck + q], ld4(wsp + q));
    } else {
        const int lr = tid >> 2, lc = (tid & 3) * 8;
        const int srow = ridx ? ridx[row0 + lr] : row0 + lr;
        const float* srcp = in + (size_t)srow * K + lc;
        st4(&sA[lr * LDAP + lc],     ld4(srcp));
        st4(&sA[lr * LDAP + lc + 4], ld4(srcp + 4));
        const int wrk = tid >> 3, wck = (tid & 7) * 16;
        const float* wsp = W + (size_t)wrk * BN + wck;
#pragma unroll
        for (int q = 0; q < 16; q += 4) st4(&sWp[wrk * BN + wck + q], ld4(wsp + q));
    }
    __syncthreads();

    float acc[4][8];
#pragma unroll
    for (int i = 0; i < 4; ++i)
#pragma unroll
        for (int j = 0; j < 8; ++j) acc[i][j] = 0.f;

#pragma unroll 8
    for (int k = 0; k < K; ++k) {
        float a[4];
#pragma unroll
        for (int i = 0; i < 4; ++i) a[i] = sA[(m0 + i) * LDAP + k];
        const float4 wA = ld4(&sWp[k * BN + n0]);
        const float4 wB = ld4(&sWp[k * BN + n0 + 4]);
        const float w[8] = {wA.x, wA.y, wA.z, wA.w, wB.x, wB.y, wB.z, wB.w};
#pragma unroll
        for (int i = 0; i < 4; ++i)
#pragma unroll
            for (int j = 0; j < 8; ++j)
                acc[i][j] = fmaf(a[i], w[j], acc[i][j]);
    }

    const float4 bA = ld4(&b[n0]), bB = ld4(&b[n0 + 4]);
    const float bb[8] = {bA.x, bA.y, bA.z, bA.w, bB.x, bB.y, bB.z, bB.w};
#pragma unroll
    for (int i = 0; i < 4; ++i) {
        bf16x8 hv, lv;
#pragma unroll
        for (int j = 0; j < 8; ++j) {
            float v = acc[i][j] + bb[j];
            v = v > 0.f ? v : 0.f;
            const bf16_t h = (bf16_t)v;
            hv[j] = h;
            lv[j] = (bf16_t)(v - (float)h);
        }
        bf16_t* op = outP + (size_t)(row0 + m0 + i) * RS + n0;
        *reinterpret_cast<bf16x8*>(op)       = hv;
        *reinterpret_cast<bf16x8*>(op + 128) = lv;
    }
}

// ---------------------------------------------------------------------------
// Head (fp32, bf16-plane input) — value head only (1 block)
// ---------------------------------------------------------------------------
__global__ __launch_bounds__(256, 2)
void head_mlp(const bf16_t* __restrict__ inP, const float* __restrict__ W1,
              const float* __restrict__ b1, const float* __restrict__ w2,
              const float* __restrict__ b2, float* __restrict__ outp)
{
    __shared__ float sA[BM * LDA];
    __shared__ float sW[BK * BN];

    const int tid = threadIdx.x;
    const int rg = tid >> 4, cg = tid & 15;
    const int m0 = rg * 4, n0 = cg * 8;
    const int row0 = blockIdx.x * BM;
    const int lr = tid >> 2, lc = (tid & 3) * 8;
    const int wr = tid >> 3, wc = (tid & 7) * 16;

    float acc[4][8];
#pragma unroll
    for (int i = 0; i < 4; ++i)
#pragma unroll
        for (int j = 0; j < 8; ++j) acc[i][j] = 0.f;

#pragma unroll 1
    for (int kc = 0; kc < 4; ++kc) {
        const int koff = kc * 32;
        const bf16_t* rp = inP + (size_t)(row0 + lr) * RS + koff + lc;
        const bf16x8 h = *reinterpret_cast<const bf16x8*>(rp);
        const bf16x8 l = *reinterpret_cast<const bf16x8*>(rp + 128);
        float a[8];
#pragma unroll
        for (int j = 0; j < 8; ++j) a[j] = (float)h[j] + (float)l[j];
        st4(&sA[lr * LDA + lc],     make_float4(a[0], a[1], a[2], a[3]));
        st4(&sA[lr * LDA + lc + 4], make_float4(a[4], a[5], a[6], a[7]));
        const float* wsrc = W1 + (size_t)koff * BN + wr * BN + wc;
        st4(&sW[wr * BN + wc],      ld4(wsrc));
        st4(&sW[wr * BN + wc + 4],  ld4(wsrc + 4));
        st4(&sW[wr * BN + wc + 8],  ld4(wsrc + 8));
        st4(&sW[wr * BN + wc + 12], ld4(wsrc + 12));
        __syncthreads();
#pragma unroll
        for (int kk = 0; kk < BK; ++kk) {
            float a2[4];
#pragma unroll
            for (int i = 0; i < 4; ++i) a2[i] = sA[(m0 + i) * LDA + kk];
            const float4 wA = ld4(&sW[kk * BN + n0]);
            const float4 wB = ld4(&sW[kk * BN + n0 + 4]);
            const float w[8] = {wA.x, wA.y, wA.z, wA.w, wB.x, wB.y, wB.z, wB.w};
#pragma unroll
            for (int i = 0; i < 4; ++i)
#pragma unroll
                for (int j = 0; j < 8; ++j)
                    acc[i][j] = fmaf(a2[i], w[j], acc[i][j]);
        }
        __syncthreads();
    }

    const float4 bA = ld4(&b1[n0]),  bB = ld4(&b1[n0 + 4]);
    const float4 vA = ld4(&w2[n0]),  vB = ld4(&w2[n0 + 4]);
    const float bb[8] = {bA.x, bA.y, bA.z, bA.w, bB.x, bB.y, bB.z, bB.w};
    const float vv[8] = {vA.x, vA.y, vA.z, vA.w, vB.x, vB.y, vB.z, vB.w};
#pragma unroll
    for (int i = 0; i < 4; ++i) {
        float p = 0.f;
#pragma unroll
        for (int j = 0; j < 8; ++j) {
            float h = acc[i][j] + bb[j];
            h = h > 0.f ? h : 0.f;
            p = fmaf(h, vv[j], p);
        }
        p += __shfl_xor(p, 1, 16); p += __shfl_xor(p, 2, 16);
        p += __shfl_xor(p, 4, 16); p += __shfl_xor(p, 8, 16);
        if (cg == 0) outp[row0 + m0 + i] = p + b2[0];
    }
}

// ---------------------------------------------------------------------------
// CSR build (once per launch; edge_index is fixed)
// ---------------------------------------------------------------------------
__global__ void count_int_k(const int* __restrict__ dst, int* __restrict__ cnt)
{
    const int i = blockIdx.x * 256 + threadIdx.x;
    atomicAdd(&cnt[dst[i]], 1);
}

__global__ void scan_graph_k(const int* __restrict__ cnt, int* __restrict__ off)
{
    __shared__ int s[256];
    const int g = blockIdx.x;
    const int t = threadIdx.x;
    const int a = cnt[g * Pn + 2 * t];
    const int b = cnt[g * Pn + 2 * t + 1];
    s[t] = a + b;
    __syncthreads();
    for (int d = 1; d < 256; d <<= 1) {
        const int v = (t >= d) ? s[t - d] : 0;
        __syncthreads();
        s[t] += v;
        __syncthreads();
    }
    const int excl = s[t] - (a + b);
    off[g * Pn + 2 * t]     = g * EPGn + excl;
    off[g * Pn + 2 * t + 1] = g * EPGn + excl + a;
}

__global__ void place_k(const int* __restrict__ dst, const int* __restrict__ off,
                        int* __restrict__ cur, int* __restrict__ perm)
{
    const int i = blockIdx.x * 256 + threadIdx.x;
    const int d = dst[i];
    const int p = off[d] + atomicAdd(&cur[d], 1);
    perm[p] = i;
}

__global__ void sort_bucket_k(int* __restrict__ perm, const int* __restrict__ off,
                              const int* __restrict__ cnt)
{
    const int n = blockIdx.x * 256 + threadIdx.x;
    if (n >= Nn) return;
    const int o = off[n], c = cnt[n];
    for (int i = 1; i < c; ++i) {
        const int key = perm[o + i];
        int j = i - 1;
        while (j >= 0 && perm[o + j] > key) { perm[o + j + 1] = perm[o + j]; --j; }
        perm[o + j + 1] = key;
    }
}

// psrc/pdst[slot] = src/dst[perm[slot]]
__global__ void make_pidx_k(const int* __restrict__ perm, const int* __restrict__ src,
                            const int* __restrict__ dst, int* __restrict__ psrc,
                            int* __restrict__ pdst)
{
    const int s = blockIdx.x * 256 + threadIdx.x;
    const int e = perm[s];
    psrc[s] = src[e];
    pdst[s] = dst[e];
}

// agg[n] = mean of incoming edge rows (contiguous CSR-slot order).
// 16 lanes/node, bf16x8 (16B) loads; 16 nodes/block.
__global__ __launch_bounds__(256)
void gather_agg_k(const bf16_t* __restrict__ hep, const int* __restrict__ off,
                  const int* __restrict__ cnt, bf16_t* __restrict__ aggp, int cpx)
{
    const int tid = threadIdx.x;
    const int bid = xcd_swz(blockIdx.x, cpx);
    const int n = bid * 16 + (tid >> 4);
    const int q = tid & 15;           // 8 cols per lane
    const int o = off[n], c = cnt[n];
    float a[8] = {0.f, 0.f, 0.f, 0.f, 0.f, 0.f, 0.f, 0.f};
    const bf16_t* rp = hep + (size_t)o * RS + q * 8;
    for (int k = 0; k < c; ++k, rp += RS) {
        const bf16x8 h = *reinterpret_cast<const bf16x8*>(rp);
        const bf16x8 l = *reinterpret_cast<const bf16x8*>(rp + 128);
#pragma unroll
        for (int j = 0; j < 8; ++j) a[j] += (float)h[j] + (float)l[j];
    }
    const float inv = 1.f / fmaxf((float)c, 1.f);
    bf16x8 hv, lv;
#pragma unroll
    for (int j = 0; j < 8; ++j) {
        const float v = a[j] * inv;
        const bf16_t h = (bf16_t)v;
        hv[j] = h;
        lv[j] = (bf16_t)(v - (float)h);
    }
    bf16_t* op = aggp + (size_t)n * RS + q * 8;
    *reinterpret_cast<bf16x8*>(op)       = hv;
    *reinterpret_cast<bf16x8*>(op + 128) = lv;
}

// ---------------------------------------------------------------------------
// small utility kernels
// ---------------------------------------------------------------------------
__global__ void init_u_k(float* __restrict__ u, bf16_t* __restrict__ up,
                         const float* __restrict__ u0)
{
    const int idx = blockIdx.x * 256 + threadIdx.x;   // < 64*128
    const int g = idx >> 7, col = idx & 127;
    const float v = u0[col];
    u[idx] = v;
    const bf16_t h = (bf16_t)v;
    up[(size_t)g * RS + col]       = h;
    up[(size_t)g * RS + 128 + col] = (bf16_t)(v - (float)h);
}

__global__ void softmax_head_k(const float* __restrict__ logits, float* __restrict__ outp)
{
    const int g = blockIdx.x;
    const int tid = threadIdx.x;
    const float* lg = logits + (size_t)g * Pn;
    const float v0 = lg[tid], v1 = lg[tid + 256];
    float bv; int bi;
    if (v1 > v0) { bv = v1; bi = tid + 256; } else { bv = v0; bi = tid; }

    __shared__ float sv[256];
    __shared__ int   si[256];
    sv[tid] = bv; si[tid] = bi;
    __syncthreads();
    for (int s = 128; s > 0; s >>= 1) {
        if (tid < s) {
            const float ov = sv[tid + s]; const int oi = si[tid + s];
            if (ov > sv[tid] || (ov == sv[tid] && oi < si[tid])) { sv[tid] = ov; si[tid] = oi; }
        }
        __syncthreads();
    }
    const float mx = sv[0];
    const int ai = si[0];
    __syncthreads();

    const float d0 = v0 - mx, d1 = v1 - mx;
    const float e0 = __expf(d0), e1 = __expf(d1);
    __shared__ float ss[256];
    __shared__ float st[256];
    ss[tid] = e0 + e1;
    st[tid] = e0 * d0 + e1 * d1;
    __syncthreads();
    for (int s = 128; s > 0; s >>= 1) {
        if (tid < s) { ss[tid] += ss[tid + s]; st[tid] += st[tid + s]; }
        __syncthreads();
    }
    if (tid == 0) {
        const float S = ss[0];
        const float logS = logf(S);
        outp[g]            = (float)ai;
        outp[Gn + g]       = -logS;
        outp[2 * Gn + g]   = logS - st[0] / S;
    }
}

} // namespace

extern "C" void kernel_launch(void* const* d_in, const int* in_sizes, int n_in,
                              void* d_out, int out_size, void* d_ws, size_t ws_size,
                              hipStream_t stream)
{
    (void)in_sizes; (void)n_in; (void)out_size; (void)ws_size;

    const float* x     = (const float*)d_in[0];
    const float* ea    = (const float*)d_in[1];
    const int*   ei    = (const int*)d_in[2];
    const float* Wn  = (const float*)d_in[6];
    const float* bn_ = (const float*)d_in[7];
    const float* We  = (const float*)d_in[8];
    const float* be_ = (const float*)d_in[9];
    const float* u0  = (const float*)d_in[10];
    const float* eW1 = (const float*)d_in[11];
    const float* eb1 = (const float*)d_in[12];
    const float* eW2 = (const float*)d_in[13];
    const float* eb2 = (const float*)d_in[14];
    const float* eg  = (const float*)d_in[15];
    const float* ebn = (const float*)d_in[16];
    const float* nW1 = (const float*)d_in[17];
    const float* nb1 = (const float*)d_in[18];
    const float* nW2 = (const float*)d_in[19];
    const float* nb2 = (const float*)d_in[20];
    const float* ng  = (const float*)d_in[21];
    const float* nbn = (const float*)d_in[22];
    const float* gW1 = (const float*)d_in[23];
    const float* gb1 = (const float*)d_in[24];
    const float* gW2 = (const float*)d_in[25];
    const float* gb2 = (const float*)d_in[26];
    const float* gg  = (const float*)d_in[27];
    const float* gbn = (const float*)d_in[28];
    const float* aW1 = (const float*)d_in[29];
    const float* ab1 = (const float*)d_in[30];
    const float* aW2 = (const float*)d_in[31];
    const float* ab2 = (const float*)d_in[32];
    const float* cW1 = (const float*)d_in[33];
    const float* cb1 = (const float*)d_in[34];
    const float* cW2 = (const float*)d_in[35];
    const float* cb2 = (const float*)d_in[36];

    const int* srcI = ei;
    const int* dstI = ei + En;

    // workspace layout
    float* ws     = (float*)d_ws;
    float* u      = ws;                              // 64*128 fp32
    float* nmean  = u + Gn * H;                      // 64*128
    float* emean  = nmean + Gn * H;                  // 64*128
    float* usegE  = emean + Gn * H;                  // 64*128
    float* usegN  = usegE + Gn * H;                  // 64*128
    float* Pa     = usegN + Gn * H;                  // N*128 fp32
    float* Pb     = Pa + (size_t)Nn * H;             // N*128 fp32
    float* logits = Pb + (size_t)Nn * H;             // N
    int*   cnt    = (int*)(logits + Nn);             // N
    int*   off    = cnt + Nn;                        // N
    int*   cur    = off + Nn;                        // N
    int*   perm   = cur + Nn;                        // E
    int*   psrc   = perm + En;                       // E
    int*   pdst   = psrc + En;                       // E
    bf16_t* bfb  = (bf16_t*)(pdst + En);
    bf16_t* hxp  = bfb;                              // N*256
    bf16_t* hep  = hxp + (size_t)Nn * RS;            // E*256  (CSR-slot order)
    bf16_t* aggp = hep + (size_t)En * RS;            // N*256
    bf16_t* up   = aggp + (size_t)Nn * RS;           // 64*256
    bf16_t* frag = up + Gn * RS;
    bf16_t* eW1h = frag;              bf16_t* eW1l = eW1h + 384 * 128;   frag += 2 * 384 * 128;
    bf16_t* eW2h = frag;              bf16_t* eW2l = eW2h + 128 * 128;   frag += 2 * 128 * 128;
    bf16_t* nW1h = frag;              bf16_t* nW1l = nW1h + 256 * 128;   frag += 2 * 256 * 128;
    bf16_t* nW2h = frag;              bf16_t* nW2l = nW2h + 128 * 128;   frag += 2 * 128 * 128;
    bf16_t* gW1h = frag;              bf16_t* gW1l = gW1h + 384 * 128;   frag += 2 * 384 * 128;
    bf16_t* gW2h = frag;              bf16_t* gW2l = gW2h + 128 * 128;   frag += 2 * 128 * 128;
    bf16_t* Weh  = frag;              bf16_t* Wel  = Weh + 32 * 128;     frag += 2 * 32 * 128;
    bf16_t* aW1h = frag;              bf16_t* aW1l = aW1h + 128 * 128;

    float* outp = (float*)d_out;

    // weight prep
    prep_wfrag<<<(384 * 128) / 256, 256, 0, stream>>>(eW1, eW1h, eW1l);
    prep_wfrag<<<(128 * 128) / 256, 256, 0, stream>>>(eW2, eW2h, eW2l);
    prep_wfrag<<<(256 * 128) / 256, 256, 0, stream>>>(nW1, nW1h, nW1l);
    prep_wfrag<<<(128 * 128) / 256, 256, 0, stream>>>(nW2, nW2h, nW2l);
    prep_wfrag<<<(384 * 128) / 256, 256, 0, stream>>>(gW1, gW1h, gW1l);
    prep_wfrag<<<(128 * 128) / 256, 256, 0, stream>>>(gW2, gW2h, gW2l);
    prep_wfrag<<<(32 * 128) / 256, 256, 0, stream>>>(We, Weh, Wel);
    prep_wfrag<<<(128 * 128) / 256, 256, 0, stream>>>(aW1, aW1h, aW1l);

    // CSR build (dst fixed across layers); edges processed in slot order
    hipMemsetAsync(cnt, 0, Nn * sizeof(int), stream);
    hipMemsetAsync(cur, 0, Nn * sizeof(int), stream);
    count_int_k<<<En / 256, 256, 0, stream>>>(dstI, cnt);
    scan_graph_k<<<Gn, 256, 0, stream>>>(cnt, off);
    place_k<<<En / 256, 256, 0, stream>>>(dstI, off, cur, perm);
    sort_bucket_k<<<(Nn + 255) / 256, 256, 0, stream>>>(perm, off, cnt);
    make_pidx_k<<<En / 256, 256, 0, stream>>>(perm, srcI, dstI, psrc, pdst);

    // input projections + constants (edge features written in slot order)
    proj_relu<64><<<Nn / BM, 256, 0, stream>>>(x, Wn, bn_, hxp, nullptr);
    proj32_mfma_k<<<En / 64, 256, 0, stream>>>(ea, perm, Weh, Wel, be_, hep);
    init_u_k<<<(Gn * H) / 256, 256, 0, stream>>>(u, up, u0);

    for (int l = 0; l < 2; ++l) {
        // hoisted per-graph u-segment partial products (fp32 exact)
        useg2_k<<<2 * Gn, H, 0, stream>>>(u, eW1 + 384 * H, nW1 + 256 * H, usegE, usegN);
        // per-node partial products for edge MLP
        xpart_k<<<Nn / 64, 256, 0, stream>>>(hxp, eW1h, eW1l, Pa, Pb);
        // edge update (in-place on hep, slot order) + fused emean pool
        hipMemsetAsync(emean, 0, Gn * H * sizeof(float), stream);
        mfma_mlp_ln<1, true, true><<<En / 64, 256, 0, stream>>>(
            hep, nullptr, nullptr, nullptr, nullptr, nullptr,
            psrc, pdst, Pa, Pb,
            eW1h + 8 * SLAB, eW1l + 8 * SLAB, eW2h, eW2l, eb1, eb2, eg, ebn, usegE,
            hep, nullptr, emean, 12, 1.f / EPGn, (En / 64) / 8);
        // agg = mean of incoming edge messages (contiguous streaming read)
        gather_agg_k<<<Nn / 16, 256, 0, stream>>>(hep, off, cnt, aggp, (Nn / 16) / 8);
        // node update (in-place on hxp) + fused nmean pool
        hipMemsetAsync(nmean, 0, Gn * H * sizeof(float), stream);
        mfma_mlp_ln<2, true, false><<<Nn / 64, 256, 0, stream>>>(
            hxp, nullptr, aggp, nullptr, nullptr, nullptr,
            nullptr, nullptr, nullptr, nullptr,
            nW1h, nW1l, nW2h, nW2l, nb1, nb2, ng, nbn, usegN,
            hxp, nullptr, nmean, 9, 1.f / Pn, (Nn / 64) / 8);
        // global update (fp32 sources; writes planes + fp32 u)
        mfma_mlp_ln<3, false, false><<<1, 256, 0, stream>>>(
            u, nullptr, nmean, nullptr, emean, nullptr,
            nullptr, nullptr, nullptr, nullptr,
            gW1h, gW1l, gW2h, gW2l, gb1, gb2, gg, gbn, nullptr,
            up, u, nullptr, 0, 0.f, 0);
    }

    head_mfma_k<<<Nn / 64, 256, 0, stream>>>(hxp, aW1h, aW1l, ab1, aW2, ab2, logits);
    softmax_head_k<<<Gn, 256, 0, stream>>>(logits, outp);
    head_mlp<<<1, 256, 0, stream>>>(up, cW1, cb1, cW2, cb2, outp + 3 * Gn);
}

// Round 15
// 508.668 us; speedup vs baseline: 1.2984x; 1.0291x over previous
//
#include <hip/hip_runtime.h>
#include <cstddef>

namespace {

constexpr int Gn  = 64;
constexpr int Pn  = 512;
constexpr int EPGn= 4096;
constexpr int Nn  = Gn * Pn;    // 32768 nodes
constexpr int En  = Gn * EPGn;  // 262144 edges
constexpr int H   = 128;

constexpr int BM = 64, BK = 32, BN = 128;
constexpr int LDA = BK + 4;
constexpr int RS  = 256;        // bf16-plane row stride (hi 128 | lo 128)
constexpr int SLAB = 4096;      // elements per 32k-slab in frag layout

typedef __bf16 bf16_t;
typedef bf16_t bf16x8 __attribute__((ext_vector_type(8)));
typedef bf16_t bf16x4 __attribute__((ext_vector_type(4)));
typedef float  f32x4  __attribute__((ext_vector_type(4)));

__device__ __forceinline__ float4 ld4(const float* p) { return *reinterpret_cast<const float4*>(p); }
__device__ __forceinline__ void st4(float* p, const float4 v) { *reinterpret_cast<float4*>(p) = v; }
__device__ __forceinline__ f32x4 mfma16(bf16x8 a, bf16x8 b, f32x4 c) {
    return __builtin_amdgcn_mfma_f32_16x16x32_bf16(a, b, c, 0, 0, 0);
}

__device__ __forceinline__ int xcd_swz(int bid, int cpx)
{
    return (bid & 7) * cpx + (bid >> 3);
}

__device__ __forceinline__ void gload_lds16(const bf16_t* g, bf16_t* l)
{
    typedef __attribute__((address_space(1))) const unsigned int* gp_t;
    typedef __attribute__((address_space(3))) unsigned int* lp_t;
    __builtin_amdgcn_global_load_lds((gp_t)(const void*)g, (lp_t)(void*)l, 16, 0, 0);
}

__device__ __forceinline__ int wfrag_idx(int k, int n)
{
    return ((((k >> 5) * 8) + (n >> 4)) * 64 + ((k >> 3) & 3) * 16 + (n & 15)) * 8 + (k & 7);
}

// ---------------------------------------------------------------------------
// prep_all_k: 8 fp32 weight arrays -> bf16 hi/lo MFMA-frag region, one launch.
// Segments (K rows): eW1:384 eW2:128 nW1:256 nW2:128 gW1:384 gW2:128 We:32 aW1:128
// ---------------------------------------------------------------------------
__global__ void prep_all_k(const float* __restrict__ s0, const float* __restrict__ s1,
                           const float* __restrict__ s2, const float* __restrict__ s3,
                           const float* __restrict__ s4, const float* __restrict__ s5,
                           const float* __restrict__ s6, const float* __restrict__ s7,
                           bf16_t* __restrict__ frag)
{
    const int i = blockIdx.x * 256 + threadIdx.x;     // < 200704
    const float* src; int li; int dh; int sz;
    if      (i < 49152)  { src = s0; li = i;          dh = 0;      sz = 49152; }
    else if (i < 65536)  { src = s1; li = i - 49152;  dh = 98304;  sz = 16384; }
    else if (i < 98304)  { src = s2; li = i - 65536;  dh = 131072; sz = 32768; }
    else if (i < 114688) { src = s3; li = i - 98304;  dh = 196608; sz = 16384; }
    else if (i < 163840) { src = s4; li = i - 114688; dh = 229376; sz = 49152; }
    else if (i < 180224) { src = s5; li = i - 163840; dh = 327680; sz = 16384; }
    else if (i < 184320) { src = s6; li = i - 180224; dh = 360448; sz = 4096;  }
    else                 { src = s7; li = i - 184320; dh = 368640; sz = 16384; }
    const int k = li >> 7, n = li & 127;
    const float v = src[li];
    const bf16_t h = (bf16_t)v;
    const bf16_t l = (bf16_t)(v - (float)h);
    const int idx = wfrag_idx(k, n);
    frag[dh + idx]      = h;
    frag[dh + sz + idx] = l;
}

// single-segment prep for Wn (64x128)
__global__ void prep_wn_k(const float* __restrict__ W, bf16_t* __restrict__ Bh,
                          bf16_t* __restrict__ Bl)
{
    const int i = blockIdx.x * 256 + threadIdx.x;   // < 8192
    const int k = i >> 7, n = i & 127;
    const float v = W[i];
    const bf16_t h = (bf16_t)v;
    const bf16_t l = (bf16_t)(v - (float)h);
    const int idx = wfrag_idx(k, n);
    Bh[idx] = h; Bl[idx] = l;
}

// merged per-graph hoisted u-segment partials
__global__ void useg2_k(const float* __restrict__ u, const float* __restrict__ WE,
                        const float* __restrict__ WN, float* __restrict__ outE,
                        float* __restrict__ outN)
{
    __shared__ float su[H];
    const bool isE = blockIdx.x < Gn;
    const int g = isE ? blockIdx.x : blockIdx.x - Gn;
    const int c = threadIdx.x;
    const float* W = isE ? WE : WN;
    float* outp = isE ? outE : outN;
    su[c] = u[g * H + c];
    __syncthreads();
    float s = 0.f;
#pragma unroll 8
    for (int k = 0; k < H; ++k) s = fmaf(su[k], W[k * H + c], s);
    outp[g * H + c] = s;
}

__device__ __forceinline__ void split8(const float4 a, const float4 b, bf16x8& h, bf16x8& l)
{
    const float v[8] = {a.x, a.y, a.z, a.w, b.x, b.y, b.z, b.w};
#pragma unroll
    for (int j = 0; j < 8; ++j) {
        const bf16_t hh = (bf16_t)v[j];
        h[j] = hh;
        l[j] = (bf16_t)(v[j] - (float)hh);
    }
}

__device__ __forceinline__ void loadB(const bf16_t* __restrict__ Wh, const bf16_t* __restrict__ Wl,
                                      int kc32, int wn, int lane, bf16x8* Bh, bf16x8* Bl)
{
#pragma unroll
    for (int nt = 0; nt < 2; ++nt) {
        const size_t idx = (size_t)(((kc32 * 8) + wn * 2 + nt) * 64 + lane) * 8;
        Bh[nt] = *reinterpret_cast<const bf16x8*>(Wh + idx);
        Bl[nt] = *reinterpret_cast<const bf16x8*>(Wl + idx);
    }
}

// ---------------------------------------------------------------------------
// xpart_k: Pa[n] = x[n] @ eW1[0:128] ; Pb[n] = x[n] @ eW1[128:256]
// ---------------------------------------------------------------------------
__global__ __launch_bounds__(256, 4)
void xpart_k(const bf16_t* __restrict__ xp,
             const bf16_t* __restrict__ Wh, const bf16_t* __restrict__ Wl,
             float* __restrict__ Pa, float* __restrict__ Pb)
{
    __shared__ __align__(16) char smem[32 * 1024];
    const int t = threadIdx.x, lane = t & 63, wv = t >> 6;
    const int wn = wv;
    const int l15 = lane & 15, l4 = lane >> 4;
    const int row0 = blockIdx.x * 64;

    f32x4 accA[4][2], accB[4][2];
#pragma unroll
    for (int mt = 0; mt < 4; ++mt)
#pragma unroll
        for (int nt = 0; nt < 2; ++nt) { accA[mt][nt] = (f32x4)0.f; accB[mt][nt] = (f32x4)0.f; }

    auto stage = [&](int kc, int bufi) {
        const bf16_t* rp = xp + (size_t)(row0 + lane) * RS + kc * 64 + wv * 8;
        bf16_t* base = (bf16_t*)(smem + bufi * 16384);
        gload_lds16(rp,       base + wv * 512);
        gload_lds16(rp + 32,  base + (wv + 4) * 512);
        gload_lds16(rp + 128, base + 4096 + wv * 512);
        gload_lds16(rp + 160, base + 4096 + (wv + 4) * 512);
    };

    stage(0, 0);
    stage(1, 1);
    __syncthreads();

#pragma unroll
    for (int kc = 0; kc < 2; ++kc) {
        const bf16_t* aH = (const bf16_t*)(smem + (size_t)kc * 16384);
        const bf16_t* aL = aH + 4096;
#pragma unroll
        for (int ks = 0; ks < 2; ++ks) {
            const int slab = kc * 2 + ks;
            bf16x8 BhA[2], BlA[2], BhB[2], BlB[2];
            loadB(Wh, Wl, slab,     wn, lane, BhA, BlA);
            loadB(Wh, Wl, slab + 4, wn, lane, BhB, BlB);
#pragma unroll
            for (int mt = 0; mt < 4; ++mt) {
                const int ro = mt * 16 + l15;
                const bf16x8 Ah = *reinterpret_cast<const bf16x8*>(aH + ((ks * 4 + l4) * 64 + ro) * 8);
                const bf16x8 Al = *reinterpret_cast<const bf16x8*>(aL + ((ks * 4 + l4) * 64 + ro) * 8);
#pragma unroll
                for (int nt = 0; nt < 2; ++nt) {
                    accA[mt][nt] = mfma16(Al, BhA[nt], accA[mt][nt]);
                    accA[mt][nt] = mfma16(Ah, BlA[nt], accA[mt][nt]);
                    accA[mt][nt] = mfma16(Ah, BhA[nt], accA[mt][nt]);
                    accB[mt][nt] = mfma16(Al, BhB[nt], accB[mt][nt]);
                    accB[mt][nt] = mfma16(Ah, BlB[nt], accB[mt][nt]);
                    accB[mt][nt] = mfma16(Ah, BhB[nt], accB[mt][nt]);
                }
            }
        }
    }

#pragma unroll
    for (int mt = 0; mt < 4; ++mt)
#pragma unroll
        for (int r2 = 0; r2 < 4; ++r2) {
            const int row = mt * 16 + l4 * 4 + r2;
#pragma unroll
            for (int nt = 0; nt < 2; ++nt) {
                const int col = wn * 32 + nt * 16 + l15;
                Pa[(size_t)(row0 + row) * H + col] = accA[mt][nt][r2];
                Pb[(size_t)(row0 + row) * H + col] = accB[mt][nt][r2];
            }
        }
}

// ---------------------------------------------------------------------------
// proj32_mfma_k: he[slot] = relu(ea[perm[slot]] @ We + be), K=32
// ---------------------------------------------------------------------------
__global__ __launch_bounds__(256, 4)
void proj32_mfma_k(const float* __restrict__ in, const int* __restrict__ ridx,
                   const bf16_t* __restrict__ Wh, const bf16_t* __restrict__ Wl,
                   const float* __restrict__ b, bf16_t* __restrict__ outP)
{
    __shared__ __align__(16) bf16_t sA[2][2048];
    const int t = threadIdx.x, lane = t & 63, wv = t >> 6;
    const int wn = wv;
    const int l15 = lane & 15, l4 = lane >> 4;
    const int row0 = blockIdx.x * 64;

    const int srow = ridx ? ridx[row0 + lane] : row0 + lane;
    const float* sp = in + (size_t)srow * 32 + wv * 8;
    bf16x8 h8, l8;
    split8(ld4(sp), ld4(sp + 4), h8, l8);
    *reinterpret_cast<bf16x8*>(&sA[0][(wv * 64 + lane) * 8]) = h8;
    *reinterpret_cast<bf16x8*>(&sA[1][(wv * 64 + lane) * 8]) = l8;
    __syncthreads();

    f32x4 acc[4][2];
#pragma unroll
    for (int mt = 0; mt < 4; ++mt)
#pragma unroll
        for (int nt = 0; nt < 2; ++nt) acc[mt][nt] = (f32x4)0.f;

    bf16x8 Bh[2], Bl[2];
    loadB(Wh, Wl, 0, wn, lane, Bh, Bl);
#pragma unroll
    for (int mt = 0; mt < 4; ++mt) {
        const int ro = mt * 16 + l15;
        const bf16x8 Ah = *reinterpret_cast<const bf16x8*>(&sA[0][(l4 * 64 + ro) * 8]);
        const bf16x8 Al = *reinterpret_cast<const bf16x8*>(&sA[1][(l4 * 64 + ro) * 8]);
#pragma unroll
        for (int nt = 0; nt < 2; ++nt) {
            acc[mt][nt] = mfma16(Al, Bh[nt], acc[mt][nt]);
            acc[mt][nt] = mfma16(Ah, Bl[nt], acc[mt][nt]);
            acc[mt][nt] = mfma16(Ah, Bh[nt], acc[mt][nt]);
        }
    }

    float bb[2];
#pragma unroll
    for (int nt = 0; nt < 2; ++nt) bb[nt] = b[wn * 32 + nt * 16 + l15];
#pragma unroll
    for (int mt = 0; mt < 4; ++mt)
#pragma unroll
        for (int r2 = 0; r2 < 4; ++r2) {
            const int row = mt * 16 + l4 * 4 + r2;
            bf16_t* opP = outP + (size_t)(row0 + row) * RS;
#pragma unroll
            for (int nt = 0; nt < 2; ++nt) {
                const int col = wn * 32 + nt * 16 + l15;
                float v = acc[mt][nt][r2] + bb[nt];
                v = v > 0.f ? v : 0.f;
                const bf16_t oh = (bf16_t)v;
                opP[col]       = oh;
                opP[col + 128] = (bf16_t)(v - (float)oh);
            }
        }
}

// ---------------------------------------------------------------------------
// proj64_mfma_k: hx[row] = relu(x[row] @ Wn + bn), K=64
// ---------------------------------------------------------------------------
__global__ __launch_bounds__(256, 4)
void proj64_mfma_k(const float* __restrict__ in,
                   const bf16_t* __restrict__ Wh, const bf16_t* __restrict__ Wl,
                   const float* __restrict__ b, bf16_t* __restrict__ outP)
{
    __shared__ __align__(16) bf16_t sA[2][4096];
    const int t = threadIdx.x, lane = t & 63, wv = t >> 6;
    const int wn = wv;
    const int l15 = lane & 15, l4 = lane >> 4;
    const int row0 = blockIdx.x * 64;

    const float* sp = in + (size_t)(row0 + lane) * 64 + wv * 16;
    bf16x8 h8, l8;
    split8(ld4(sp), ld4(sp + 4), h8, l8);
    *reinterpret_cast<bf16x8*>(&sA[0][((wv * 2)     * 64 + lane) * 8]) = h8;
    *reinterpret_cast<bf16x8*>(&sA[1][((wv * 2)     * 64 + lane) * 8]) = l8;
    split8(ld4(sp + 8), ld4(sp + 12), h8, l8);
    *reinterpret_cast<bf16x8*>(&sA[0][((wv * 2 + 1) * 64 + lane) * 8]) = h8;
    *reinterpret_cast<bf16x8*>(&sA[1][((wv * 2 + 1) * 64 + lane) * 8]) = l8;
    __syncthreads();

    f32x4 acc[4][2];
#pragma unroll
    for (int mt = 0; mt < 4; ++mt)
#pragma unroll
        for (int nt = 0; nt < 2; ++nt) acc[mt][nt] = (f32x4)0.f;

#pragma unroll
    for (int ks = 0; ks < 2; ++ks) {
        bf16x8 Bh[2], Bl[2];
        loadB(Wh, Wl, ks, wn, lane, Bh, Bl);
#pragma unroll
        for (int mt = 0; mt < 4; ++mt) {
            const int ro = mt * 16 + l15;
            const bf16x8 Ah = *reinterpret_cast<const bf16x8*>(&sA[0][((ks * 4 + l4) * 64 + ro) * 8]);
            const bf16x8 Al = *reinterpret_cast<const bf16x8*>(&sA[1][((ks * 4 + l4) * 64 + ro) * 8]);
#pragma unroll
            for (int nt = 0; nt < 2; ++nt) {
                acc[mt][nt] = mfma16(Al, Bh[nt], acc[mt][nt]);
                acc[mt][nt] = mfma16(Ah, Bl[nt], acc[mt][nt]);
                acc[mt][nt] = mfma16(Ah, Bh[nt], acc[mt][nt]);
            }
        }
    }

    float bb[2];
#pragma unroll
    for (int nt = 0; nt < 2; ++nt) bb[nt] = b[wn * 32 + nt * 16 + l15];
#pragma unroll
    for (int mt = 0; mt < 4; ++mt)
#pragma unroll
        for (int r2 = 0; r2 < 4; ++r2) {
            const int row = mt * 16 + l4 * 4 + r2;
            bf16_t* opP = outP + (size_t)(row0 + row) * RS;
#pragma unroll
            for (int nt = 0; nt < 2; ++nt) {
                const int col = wn * 32 + nt * 16 + l15;
                float v = acc[mt][nt][r2] + bb[nt];
                v = v > 0.f ? v : 0.f;
                const bf16_t oh = (bf16_t)v;
                opP[col]       = oh;
                opP[col + 128] = (bf16_t)(v - (float)oh);
            }
        }
}

// ---------------------------------------------------------------------------
// head_mfma_k: logits[row] = relu(x[row] @ aW1 + ab1) . aW2 + ab2
// ---------------------------------------------------------------------------
__global__ __launch_bounds__(256, 4)
void head_mfma_k(const bf16_t* __restrict__ xp,
                 const bf16_t* __restrict__ W1h, const bf16_t* __restrict__ W1l,
                 const float* __restrict__ b1, const float* __restrict__ w2,
                 const float* __restrict__ b2, float* __restrict__ logits)
{
    __shared__ __align__(16) char smem[32 * 1024];
    __shared__ float redS[4][64];
    const int t = threadIdx.x, lane = t & 63, wv = t >> 6;
    const int wn = wv;
    const int l15 = lane & 15, l4 = lane >> 4;
    const int row0 = blockIdx.x * 64;

    f32x4 acc[4][2];
#pragma unroll
    for (int mt = 0; mt < 4; ++mt)
#pragma unroll
        for (int nt = 0; nt < 2; ++nt) acc[mt][nt] = (f32x4)0.f;

    auto stage = [&](int kh, int bufi) {
        const bf16_t* rp = xp + (size_t)(row0 + lane) * RS + kh * 64 + wv * 8;
        bf16_t* base = (bf16_t*)(smem + bufi * 16384);
        gload_lds16(rp,       base + wv * 512);
        gload_lds16(rp + 32,  base + (wv + 4) * 512);
        gload_lds16(rp + 128, base + 4096 + wv * 512);
        gload_lds16(rp + 160, base + 4096 + (wv + 4) * 512);
    };
    stage(0, 0);
    stage(1, 1);
    __syncthreads();

#pragma unroll
    for (int kc = 0; kc < 2; ++kc) {
        const bf16_t* aH = (const bf16_t*)(smem + (size_t)kc * 16384);
        const bf16_t* aL = aH + 4096;
#pragma unroll
        for (int ks = 0; ks < 2; ++ks) {
            bf16x8 Bh[2], Bl[2];
            loadB(W1h, W1l, kc * 2 + ks, wn, lane, Bh, Bl);
#pragma unroll
            for (int mt = 0; mt < 4; ++mt) {
                const int ro = mt * 16 + l15;
                const bf16x8 Ah = *reinterpret_cast<const bf16x8*>(aH + ((ks * 4 + l4) * 64 + ro) * 8);
                const bf16x8 Al = *reinterpret_cast<const bf16x8*>(aL + ((ks * 4 + l4) * 64 + ro) * 8);
#pragma unroll
                for (int nt = 0; nt < 2; ++nt) {
                    acc[mt][nt] = mfma16(Al, Bh[nt], acc[mt][nt]);
                    acc[mt][nt] = mfma16(Ah, Bl[nt], acc[mt][nt]);
                    acc[mt][nt] = mfma16(Ah, Bh[nt], acc[mt][nt]);
                }
            }
        }
    }

    float bb[2], vv[2];
#pragma unroll
    for (int nt = 0; nt < 2; ++nt) {
        const int col = wn * 32 + nt * 16 + l15;
        bb[nt] = b1[col]; vv[nt] = w2[col];
    }
#pragma unroll
    for (int mt = 0; mt < 4; ++mt)
#pragma unroll
        for (int r2 = 0; r2 < 4; ++r2) {
            float pp = 0.f;
#pragma unroll
            for (int nt = 0; nt < 2; ++nt) {
                float h = acc[mt][nt][r2] + bb[nt];
                h = h > 0.f ? h : 0.f;
                pp = fmaf(h, vv[nt], pp);
            }
            pp += __shfl_xor(pp, 1, 16); pp += __shfl_xor(pp, 2, 16);
            pp += __shfl_xor(pp, 4, 16); pp += __shfl_xor(pp, 8, 16);
            if (l15 == 0) redS[wn][mt * 16 + l4 * 4 + r2] = pp;
        }
    __syncthreads();
    if (t < 64)
        logits[row0 + t] = redS[0][t] + redS[1][t] + redS[2][t] + redS[3][t] + b2[0];
}

// ---------------------------------------------------------------------------
// MFMA fused 2-layer MLP + LN, bf16x3 precision. (R13-proven)
// ---------------------------------------------------------------------------
template<int NSEG, bool PLANES, bool PRE>
__global__ __launch_bounds__(256, 4)
void mfma_mlp_ln(const void* __restrict__ p0v, const int* __restrict__ i0,
                 const void* __restrict__ p1v, const int* __restrict__ i1,
                 const void* __restrict__ p2v, const int* __restrict__ i2,
                 const int* __restrict__ iA, const int* __restrict__ iB,
                 const float* __restrict__ Pa, const float* __restrict__ Pb,
                 const bf16_t* __restrict__ W1h, const bf16_t* __restrict__ W1l,
                 const bf16_t* __restrict__ W2h, const bf16_t* __restrict__ W2l,
                 const float* __restrict__ b1, const float* __restrict__ b2,
                 const float* __restrict__ gam, const float* __restrict__ bet,
                 const float* __restrict__ useg,
                 bf16_t* __restrict__ outP, float* __restrict__ out32,
                 float* __restrict__ pool, int gshift, float pscale, int cpx)
{
    __shared__ __align__(16) char smem[32 * 1024];
    __shared__ float redS[4][64], redQ[4][64];

    const int t = threadIdx.x;
    const int lane = t & 63;
    const int wv = t >> 6;
    const int wn = wv;
    const int l15 = lane & 15, l4 = lane >> 4;
    const int bid = (cpx > 0) ? xcd_swz(blockIdx.x, cpx) : blockIdx.x;
    const int row0 = bid * 64;

    const int s0 = (PRE || !i0) ? row0 + lane : i0[row0 + lane];
    const int s1 = (NSEG > 1) ? (i1 ? i1[row0 + lane] : row0 + lane) : 0;
    const int s2 = (NSEG > 2) ? (i2 ? i2[row0 + lane] : row0 + lane) : 0;

    f32x4 acc[4][2];
#pragma unroll
    for (int mt = 0; mt < 4; ++mt)
#pragma unroll
        for (int nt = 0; nt < 2; ++nt) acc[mt][nt] = (f32x4)0.f;

    constexpr int NC = NSEG * 2;
    constexpr int NS1 = NC * 2;

    auto stage_async = [&](int kc, int bufi) {
        const int seg = kc >> 1, kh = kc & 1;
        const bf16_t* p; int srow;
        if (seg == 0)      { p = (const bf16_t*)p0v; srow = s0; }
        else if (seg == 1) { p = (const bf16_t*)p1v; srow = s1; }
        else               { p = (const bf16_t*)p2v; srow = s2; }
        const bf16_t* rp = p + (size_t)srow * RS + kh * 64 + wv * 8;
        bf16_t* base = (bf16_t*)(smem + bufi * 16384);
        gload_lds16(rp,        base + wv * 512);
        gload_lds16(rp + 32,   base + (wv + 4) * 512);
        gload_lds16(rp + 128,  base + 4096 + wv * 512);
        gload_lds16(rp + 160,  base + 4096 + (wv + 4) * 512);
    };

    auto stage_f32 = [&](int kc, int bufi) {
        const int seg = kc >> 1, kh = kc & 1;
        const float* p; int srow;
        if (seg == 0)      { p = (const float*)p0v; srow = s0; }
        else if (seg == 1) { p = (const float*)p1v; srow = s1; }
        else               { p = (const float*)p2v; srow = s2; }
        const float* sp = p + (size_t)srow * H + kh * 64 + wv * 8;
        bf16_t* base = (bf16_t*)(smem + bufi * 16384);
        bf16x8 h, l;
        split8(ld4(sp), ld4(sp + 4), h, l);
        *reinterpret_cast<bf16x8*>(base + ((wv)     * 64 + lane) * 8) = h;
        *reinterpret_cast<bf16x8*>(base + 4096 + ((wv)     * 64 + lane) * 8) = l;
        split8(ld4(sp + 32), ld4(sp + 36), h, l);
        *reinterpret_cast<bf16x8*>(base + ((wv + 4) * 64 + lane) * 8) = h;
        *reinterpret_cast<bf16x8*>(base + 4096 + ((wv + 4) * 64 + lane) * 8) = l;
    };

    bf16x8 BhA[2], BlA[2], BhB[2], BlB[2];
    loadB(W1h, W1l, 0, wn, lane, BhA, BlA);
    if constexpr (PLANES) stage_async(0, 0); else stage_f32(0, 0);

    if constexpr (PRE) {
        const int ia = iA[row0 + lane];
        const int ib = iB[row0 + lane];
#pragma unroll
        for (int mt = 0; mt < 4; ++mt)
#pragma unroll
            for (int r2 = 0; r2 < 4; ++r2) {
                const int r = mt * 16 + l4 * 4 + r2;
                const int sa = __shfl(ia, r);
                const int sb = __shfl(ib, r);
#pragma unroll
                for (int nt = 0; nt < 2; ++nt) {
                    const int col = wn * 32 + nt * 16 + l15;
                    acc[mt][nt][r2] = Pa[(size_t)sa * H + col] + Pb[(size_t)sb * H + col];
                }
            }
    }
    __syncthreads();

#pragma unroll 1
    for (int kc = 0; kc < NC; ++kc) {
        if (kc + 1 < NC) {
            if constexpr (PLANES) stage_async(kc + 1, (kc & 1) ^ 1);
            else                  stage_f32(kc + 1, (kc & 1) ^ 1);
        }
        const bf16_t* aH = (const bf16_t*)(smem + (size_t)(kc & 1) * 16384);
        const bf16_t* aL = aH + 4096;

        {
            const int slab = kc * 2;
            if (slab + 1 < NS1)
                loadB(W1h, W1l, slab + 1, wn, lane, BhB, BlB);
#pragma unroll
            for (int mt = 0; mt < 4; ++mt) {
                const int ro = mt * 16 + l15;
                const bf16x8 Ah = *reinterpret_cast<const bf16x8*>(aH + ((l4) * 64 + ro) * 8);
                const bf16x8 Al = *reinterpret_cast<const bf16x8*>(aL + ((l4) * 64 + ro) * 8);
#pragma unroll
                for (int nt = 0; nt < 2; ++nt) {
                    acc[mt][nt] = mfma16(Al, BhA[nt], acc[mt][nt]);
                    acc[mt][nt] = mfma16(Ah, BlA[nt], acc[mt][nt]);
                    acc[mt][nt] = mfma16(Ah, BhA[nt], acc[mt][nt]);
                }
            }
        }
        {
            const int slab = kc * 2 + 1;
            if (slab + 1 < NS1)
                loadB(W1h, W1l, slab + 1, wn, lane, BhA, BlA);
#pragma unroll
            for (int mt = 0; mt < 4; ++mt) {
                const int ro = mt * 16 + l15;
                const bf16x8 Ah = *reinterpret_cast<const bf16x8*>(aH + ((4 + l4) * 64 + ro) * 8);
                const bf16x8 Al = *reinterpret_cast<const bf16x8*>(aL + ((4 + l4) * 64 + ro) * 8);
#pragma unroll
                for (int nt = 0; nt < 2; ++nt) {
                    acc[mt][nt] = mfma16(Al, BhB[nt], acc[mt][nt]);
                    acc[mt][nt] = mfma16(Ah, BlB[nt], acc[mt][nt]);
                    acc[mt][nt] = mfma16(Ah, BhB[nt], acc[mt][nt]);
                }
            }
        }
        __syncthreads();
    }

    {
        const int g = row0 >> gshift;
        bf16_t* sHh = (bf16_t*)smem;
        bf16_t* sHl = sHh + 8192;
#pragma unroll
        for (int mt = 0; mt < 4; ++mt)
#pragma unroll
            for (int nt = 0; nt < 2; ++nt) {
                const int col = wn * 32 + nt * 16 + l15;
                float bb = b1[col];
                if (useg) bb += useg[(size_t)g * H + col];
#pragma unroll
                for (int r2 = 0; r2 < 4; ++r2) {
                    const int rloc = mt * 16 + l4 * 4 + r2;
                    float v = acc[mt][nt][r2] + bb;
                    v = v > 0.f ? v : 0.f;
                    const bf16_t h = (bf16_t)v;
                    const int sidx = (col >> 3) * 512 + rloc * 8 + (col & 7);
                    sHh[sidx] = h;
                    sHl[sidx] = (bf16_t)(v - (float)h);
                    acc[mt][nt][r2] = 0.f;
                }
            }
    }
    __syncthreads();

    {
        const bf16_t* sHh = (const bf16_t*)smem;
        const bf16_t* sHl = sHh + 8192;
        loadB(W2h, W2l, 0, wn, lane, BhA, BlA);
#pragma unroll
        for (int kc2 = 0; kc2 < 4; ++kc2) {
            if (kc2 + 1 < 4) {
                if ((kc2 & 1) == 0) loadB(W2h, W2l, kc2 + 1, wn, lane, BhB, BlB);
                else                loadB(W2h, W2l, kc2 + 1, wn, lane, BhA, BlA);
            }
#pragma unroll
            for (int mt = 0; mt < 4; ++mt) {
                const int ro = mt * 16 + l15;
                const bf16x8 Ah = *reinterpret_cast<const bf16x8*>(sHh + ((kc2 * 4 + l4) * 64 + ro) * 8);
                const bf16x8 Al = *reinterpret_cast<const bf16x8*>(sHl + ((kc2 * 4 + l4) * 64 + ro) * 8);
#pragma unroll
                for (int nt = 0; nt < 2; ++nt) {
                    if ((kc2 & 1) == 0) {
                        acc[mt][nt] = mfma16(Al, BhA[nt], acc[mt][nt]);
                        acc[mt][nt] = mfma16(Ah, BlA[nt], acc[mt][nt]);
                        acc[mt][nt] = mfma16(Ah, BhA[nt], acc[mt][nt]);
                    } else {
                        acc[mt][nt] = mfma16(Al, BhB[nt], acc[mt][nt]);
                        acc[mt][nt] = mfma16(Ah, BlB[nt], acc[mt][nt]);
                        acc[mt][nt] = mfma16(Ah, BhB[nt], acc[mt][nt]);
                    }
                }
            }
        }
    }

    float bb2[2], ggv[2], btv[2];
#pragma unroll
    for (int nt = 0; nt < 2; ++nt) {
        const int col = wn * 32 + nt * 16 + l15;
        bb2[nt] = b2[col]; ggv[nt] = gam[col]; btv[nt] = bet[col];
    }
#pragma unroll
    for (int mt = 0; mt < 4; ++mt)
#pragma unroll
        for (int r2 = 0; r2 < 4; ++r2) {
            float s = 0.f, q = 0.f;
#pragma unroll
            for (int nt = 0; nt < 2; ++nt) {
                const float v = acc[mt][nt][r2] + bb2[nt];
                s += v; q += v * v;
            }
            s += __shfl_xor(s, 1, 16); s += __shfl_xor(s, 2, 16);
            s += __shfl_xor(s, 4, 16); s += __shfl_xor(s, 8, 16);
            q += __shfl_xor(q, 1, 16); q += __shfl_xor(q, 2, 16);
            q += __shfl_xor(q, 4, 16); q += __shfl_xor(q, 8, 16);
            if (l15 == 0) {
                const int row = mt * 16 + l4 * 4 + r2;
                redS[wn][row] = s; redQ[wn][row] = q;
            }
        }
    __syncthreads();

    float cs[2] = {0.f, 0.f};
#pragma unroll
    for (int mt = 0; mt < 4; ++mt)
#pragma unroll
        for (int r2 = 0; r2 < 4; ++r2) {
            const int row = mt * 16 + l4 * 4 + r2;
            const float S = redS[0][row] + redS[1][row] + redS[2][row] + redS[3][row];
            const float Q = redQ[0][row] + redQ[1][row] + redQ[2][row] + redQ[3][row];
            const float mean = S * (1.f / 128.f);
            const float var  = Q * (1.f / 128.f) - mean * mean;
            const float rstd = rsqrtf(var + 1e-5f);
            bf16_t* opP = outP + (size_t)(row0 + row) * RS;
#pragma unroll
            for (int nt = 0; nt < 2; ++nt) {
                const int col = wn * 32 + nt * 16 + l15;
                const float v = acc[mt][nt][r2] + bb2[nt];
                const float o = (v - mean) * rstd * ggv[nt] + btv[nt];
                const bf16_t oh = (bf16_t)o;
                opP[col]       = oh;
                opP[col + 128] = (bf16_t)(o - (float)oh);
                if (out32) out32[(size_t)(row0 + row) * H + col] = o;
                cs[nt] += o;
            }
        }

    if (pool != nullptr) {
        const int g = row0 >> gshift;
#pragma unroll
        for (int nt = 0; nt < 2; ++nt) {
            float s = cs[nt];
            s += __shfl_xor(s, 16);
            s += __shfl_xor(s, 32);
            if (l4 == 0)
                atomicAdd(&pool[(size_t)g * H + wn * 32 + nt * 16 + l15], s * pscale);
        }
    }
}

// ---------------------------------------------------------------------------
// Head (fp32, bf16-plane input) — value head only (1 block)
// ---------------------------------------------------------------------------
__global__ __launch_bounds__(256, 2)
void head_mlp(const bf16_t* __restrict__ inP, const float* __restrict__ W1,
              const float* __restrict__ b1, const float* __restrict__ w2,
              const float* __restrict__ b2, float* __restrict__ outp)
{
    __shared__ float sA[BM * LDA];
    __shared__ float sW[BK * BN];

    const int tid = threadIdx.x;
    const int rg = tid >> 4, cg = tid & 15;
    const int m0 = rg * 4, n0 = cg * 8;
    const int row0 = blockIdx.x * BM;
    const int lr = tid >> 2, lc = (tid & 3) * 8;
    const int wr = tid >> 3, wc = (tid & 7) * 16;

    float acc[4][8];
#pragma unroll
    for (int i = 0; i < 4; ++i)
#pragma unroll
        for (int j = 0; j < 8; ++j) acc[i][j] = 0.f;

#pragma unroll 1
    for (int kc = 0; kc < 4; ++kc) {
        const int koff = kc * 32;
        const bf16_t* rp = inP + (size_t)(row0 + lr) * RS + koff + lc;
        const bf16x8 h = *reinterpret_cast<const bf16x8*>(rp);
        const bf16x8 l = *reinterpret_cast<const bf16x8*>(rp + 128);
        float a[8];
#pragma unroll
        for (int j = 0; j < 8; ++j) a[j] = (float)h[j] + (float)l[j];
        st4(&sA[lr * LDA + lc],     make_float4(a[0], a[1], a[2], a[3]));
        st4(&sA[lr * LDA + lc + 4], make_float4(a[4], a[5], a[6], a[7]));
        const float* wsrc = W1 + (size_t)koff * BN + wr * BN + wc;
        st4(&sW[wr * BN + wc],      ld4(wsrc));
        st4(&sW[wr * BN + wc + 4],  ld4(wsrc + 4));
        st4(&sW[wr * BN + wc + 8],  ld4(wsrc + 8));
        st4(&sW[wr * BN + wc + 12], ld4(wsrc + 12));
        __syncthreads();
#pragma unroll
        for (int kk = 0; kk < BK; ++kk) {
            float a2[4];
#pragma unroll
            for (int i = 0; i < 4; ++i) a2[i] = sA[(m0 + i) * LDA + kk];
            const float4 wA = ld4(&sW[kk * BN + n0]);
            const float4 wB = ld4(&sW[kk * BN + n0 + 4]);
            const float w[8] = {wA.x, wA.y, wA.z, wA.w, wB.x, wB.y, wB.z, wB.w};
#pragma unroll
            for (int i = 0; i < 4; ++i)
#pragma unroll
                for (int j = 0; j < 8; ++j)
                    acc[i][j] = fmaf(a2[i], w[j], acc[i][j]);
        }
        __syncthreads();
    }

    const float4 bA = ld4(&b1[n0]),  bB = ld4(&b1[n0 + 4]);
    const float4 vA = ld4(&w2[n0]),  vB = ld4(&w2[n0 + 4]);
    const float bb[8] = {bA.x, bA.y, bA.z, bA.w, bB.x, bB.y, bB.z, bB.w};
    const float vv[8] = {vA.x, vA.y, vA.z, vA.w, vB.x, vB.y, vB.z, vB.w};
#pragma unroll
    for (int i = 0; i < 4; ++i) {
        float p = 0.f;
#pragma unroll
        for (int j = 0; j < 8; ++j) {
            float h = acc[i][j] + bb[j];
            h = h > 0.f ? h : 0.f;
            p = fmaf(h, vv[j], p);
        }
        p += __shfl_xor(p, 1, 16); p += __shfl_xor(p, 2, 16);
        p += __shfl_xor(p, 4, 16); p += __shfl_xor(p, 8, 16);
        if (cg == 0) outp[row0 + m0 + i] = p + b2[0];
    }
}

// ---------------------------------------------------------------------------
// CSR build
// ---------------------------------------------------------------------------
__global__ void count_int_k(const int* __restrict__ dst, int* __restrict__ cnt)
{
    const int i = blockIdx.x * 256 + threadIdx.x;
    atomicAdd(&cnt[dst[i]], 1);
}

__global__ void scan_graph_k(const int* __restrict__ cnt, int* __restrict__ off)
{
    __shared__ int s[256];
    const int g = blockIdx.x;
    const int t = threadIdx.x;
    const int a = cnt[g * Pn + 2 * t];
    const int b = cnt[g * Pn + 2 * t + 1];
    s[t] = a + b;
    __syncthreads();
    for (int d = 1; d < 256; d <<= 1) {
        const int v = (t >= d) ? s[t - d] : 0;
        __syncthreads();
        s[t] += v;
        __syncthreads();
    }
    const int excl = s[t] - (a + b);
    off[g * Pn + 2 * t]     = g * EPGn + excl;
    off[g * Pn + 2 * t + 1] = g * EPGn + excl + a;
}

__global__ void place_k(const int* __restrict__ dst, const int* __restrict__ off,
                        int* __restrict__ cur, int* __restrict__ perm)
{
    const int i = blockIdx.x * 256 + threadIdx.x;
    const int d = dst[i];
    const int p = off[d] + atomicAdd(&cur[d], 1);
    perm[p] = i;
}

__global__ void sort_bucket_k(int* __restrict__ perm, const int* __restrict__ off,
                              const int* __restrict__ cnt)
{
    const int n = blockIdx.x * 256 + threadIdx.x;
    if (n >= Nn) return;
    const int o = off[n], c = cnt[n];
    for (int i = 1; i < c; ++i) {
        const int key = perm[o + i];
        int j = i - 1;
        while (j >= 0 && perm[o + j] > key) { perm[o + j + 1] = perm[o + j]; --j; }
        perm[o + j + 1] = key;
    }
}

__global__ void make_pidx_k(const int* __restrict__ perm, const int* __restrict__ src,
                            const int* __restrict__ dst, int* __restrict__ psrc,
                            int* __restrict__ pdst)
{
    const int s = blockIdx.x * 256 + threadIdx.x;
    const int e = perm[s];
    psrc[s] = src[e];
    pdst[s] = dst[e];
}

// agg[n] = mean of incoming edge rows (contiguous CSR-slot order)
__global__ __launch_bounds__(256)
void gather_agg_k(const bf16_t* __restrict__ hep, const int* __restrict__ off,
                  const int* __restrict__ cnt, bf16_t* __restrict__ aggp, int cpx)
{
    const int tid = threadIdx.x;
    const int bid = xcd_swz(blockIdx.x, cpx);
    const int n = bid * 16 + (tid >> 4);
    const int q = tid & 15;
    const int o = off[n], c = cnt[n];
    float a[8] = {0.f, 0.f, 0.f, 0.f, 0.f, 0.f, 0.f, 0.f};
    const bf16_t* rp = hep + (size_t)o * RS + q * 8;
    for (int k = 0; k < c; ++k, rp += RS) {
        const bf16x8 h = *reinterpret_cast<const bf16x8*>(rp);
        const bf16x8 l = *reinterpret_cast<const bf16x8*>(rp + 128);
#pragma unroll
        for (int j = 0; j < 8; ++j) a[j] += (float)h[j] + (float)l[j];
    }
    const float inv = 1.f / fmaxf((float)c, 1.f);
    bf16x8 hv, lv;
#pragma unroll
    for (int j = 0; j < 8; ++j) {
        const float v = a[j] * inv;
        const bf16_t h = (bf16_t)v;
        hv[j] = h;
        lv[j] = (bf16_t)(v - (float)h);
    }
    bf16_t* op = aggp + (size_t)n * RS + q * 8;
    *reinterpret_cast<bf16x8*>(op)       = hv;
    *reinterpret_cast<bf16x8*>(op + 128) = lv;
}

__global__ void init_u_k(float* __restrict__ u, bf16_t* __restrict__ up,
                         const float* __restrict__ u0)
{
    const int idx = blockIdx.x * 256 + threadIdx.x;
    const int g = idx >> 7, col = idx & 127;
    const float v = u0[col];
    u[idx] = v;
    const bf16_t h = (bf16_t)v;
    up[(size_t)g * RS + col]       = h;
    up[(size_t)g * RS + 128 + col] = (bf16_t)(v - (float)h);
}

__global__ void softmax_head_k(const float* __restrict__ logits, float* __restrict__ outp)
{
    const int g = blockIdx.x;
    const int tid = threadIdx.x;
    const float* lg = logits + (size_t)g * Pn;
    const float v0 = lg[tid], v1 = lg[tid + 256];
    float bv; int bi;
    if (v1 > v0) { bv = v1; bi = tid + 256; } else { bv = v0; bi = tid; }

    __shared__ float sv[256];
    __shared__ int   si[256];
    sv[tid] = bv; si[tid] = bi;
    __syncthreads();
    for (int s = 128; s > 0; s >>= 1) {
        if (tid < s) {
            const float ov = sv[tid + s]; const int oi = si[tid + s];
            if (ov > sv[tid] || (ov == sv[tid] && oi < si[tid])) { sv[tid] = ov; si[tid] = oi; }
        }
        __syncthreads();
    }
    const float mx = sv[0];
    const int ai = si[0];
    __syncthreads();

    const float d0 = v0 - mx, d1 = v1 - mx;
    const float e0 = __expf(d0), e1 = __expf(d1);
    __shared__ float ss[256];
    __shared__ float st[256];
    ss[tid] = e0 + e1;
    st[tid] = e0 * d0 + e1 * d1;
    __syncthreads();
    for (int s = 128; s > 0; s >>= 1) {
        if (tid < s) { ss[tid] += ss[tid + s]; st[tid] += st[tid + s]; }
        __syncthreads();
    }
    if (tid == 0) {
        const float S = ss[0];
        const float logS = logf(S);
        outp[g]            = (float)ai;
        outp[Gn + g]       = -logS;
        outp[2 * Gn + g]   = logS - st[0] / S;
    }
}

} // namespace

extern "C" void kernel_launch(void* const* d_in, const int* in_sizes, int n_in,
                              void* d_out, int out_size, void* d_ws, size_t ws_size,
                              hipStream_t stream)
{
    (void)in_sizes; (void)n_in; (void)out_size; (void)ws_size;

    const float* x     = (const float*)d_in[0];
    const float* ea    = (const float*)d_in[1];
    const int*   ei    = (const int*)d_in[2];
    const float* Wn  = (const float*)d_in[6];
    const float* bn_ = (const float*)d_in[7];
    const float* We  = (const float*)d_in[8];
    const float* be_ = (const float*)d_in[9];
    const float* u0  = (const float*)d_in[10];
    const float* eW1 = (const float*)d_in[11];
    const float* eb1 = (const float*)d_in[12];
    const float* eW2 = (const float*)d_in[13];
    const float* eb2 = (const float*)d_in[14];
    const float* eg  = (const float*)d_in[15];
    const float* ebn = (const float*)d_in[16];
    const float* nW1 = (const float*)d_in[17];
    const float* nb1 = (const float*)d_in[18];
    const float* nW2 = (const float*)d_in[19];
    const float* nb2 = (const float*)d_in[20];
    const float* ng  = (const float*)d_in[21];
    const float* nbn = (const float*)d_in[22];
    const float* gW1 = (const float*)d_in[23];
    const float* gb1 = (const float*)d_in[24];
    const float* gW2 = (const float*)d_in[25];
    const float* gb2 = (const float*)d_in[26];
    const float* gg  = (const float*)d_in[27];
    const float* gbn = (const float*)d_in[28];
    const float* aW1 = (const float*)d_in[29];
    const float* ab1 = (const float*)d_in[30];
    const float* aW2 = (const float*)d_in[31];
    const float* ab2 = (const float*)d_in[32];
    const float* cW1 = (const float*)d_in[33];
    const float* cb1 = (const float*)d_in[34];
    const float* cW2 = (const float*)d_in[35];
    const float* cb2 = (const float*)d_in[36];

    const int* srcI = ei;
    const int* dstI = ei + En;

    // workspace layout
    float* ws     = (float*)d_ws;
    float* u      = ws;                              // 64*128 fp32
    float* nmean  = u + Gn * H;                      // 64*128
    float* emean  = nmean + Gn * H;                  // 64*128 (adjacent)
    float* usegE  = emean + Gn * H;                  // 64*128
    float* usegN  = usegE + Gn * H;                  // 64*128
    float* Pa     = usegN + Gn * H;                  // N*128 fp32
    float* Pb     = Pa + (size_t)Nn * H;             // N*128 fp32
    float* logits = Pb + (size_t)Nn * H;             // N
    int*   cnt    = (int*)(logits + Nn);             // N
    int*   off    = cnt + Nn;                        // N
    int*   cur    = off + Nn;                        // N
    int*   perm   = cur + Nn;                        // E
    int*   psrc   = perm + En;                       // E
    int*   pdst   = psrc + En;                       // E
    bf16_t* bfb  = (bf16_t*)(pdst + En);
    bf16_t* hxp  = bfb;                              // N*256
    bf16_t* hep  = hxp + (size_t)Nn * RS;            // E*256 (CSR-slot order)
    bf16_t* aggp = hep + (size_t)En * RS;            // N*256
    bf16_t* up   = aggp + (size_t)Nn * RS;           // 64*256
    bf16_t* frag = up + Gn * RS;
    // frag offsets must match prep_all_k's table:
    bf16_t* eW1h = frag;              bf16_t* eW1l = eW1h + 49152;
    bf16_t* eW2h = frag + 98304;      bf16_t* eW2l = eW2h + 16384;
    bf16_t* nW1h = frag + 131072;     bf16_t* nW1l = nW1h + 32768;
    bf16_t* nW2h = frag + 196608;     bf16_t* nW2l = nW2h + 16384;
    bf16_t* gW1h = frag + 229376;     bf16_t* gW1l = gW1h + 49152;
    bf16_t* gW2h = frag + 327680;     bf16_t* gW2l = gW2h + 16384;
    bf16_t* Weh  = frag + 360448;     bf16_t* Wel  = Weh + 4096;
    bf16_t* aW1h = frag + 368640;     bf16_t* aW1l = aW1h + 16384;
    bf16_t* Wnh  = frag + 401408;     bf16_t* Wnl  = Wnh + 8192;

    float* outp = (float*)d_out;

    // weight prep: one big launch + one small for Wn
    prep_all_k<<<200704 / 256, 256, 0, stream>>>(eW1, eW2, nW1, nW2, gW1, gW2, We, aW1, frag);
    prep_wn_k<<<(64 * 128) / 256, 256, 0, stream>>>(Wn, Wnh, Wnl);

    // CSR build; cnt+cur zeroed in one pass (off overwritten by scan)
    hipMemsetAsync(cnt, 0, 3 * Nn * sizeof(int), stream);
    count_int_k<<<En / 256, 256, 0, stream>>>(dstI, cnt);
    scan_graph_k<<<Gn, 256, 0, stream>>>(cnt, off);
    place_k<<<En / 256, 256, 0, stream>>>(dstI, off, cur, perm);
    sort_bucket_k<<<(Nn + 255) / 256, 256, 0, stream>>>(perm, off, cnt);
    make_pidx_k<<<En / 256, 256, 0, stream>>>(perm, srcI, dstI, psrc, pdst);

    // input projections + constants
    proj64_mfma_k<<<Nn / 64, 256, 0, stream>>>(x, Wnh, Wnl, bn_, hxp);
    proj32_mfma_k<<<En / 64, 256, 0, stream>>>(ea, perm, Weh, Wel, be_, hep);
    init_u_k<<<(Gn * H) / 256, 256, 0, stream>>>(u, up, u0);

    for (int l = 0; l < 2; ++l) {
        useg2_k<<<2 * Gn, H, 0, stream>>>(u, eW1 + 384 * H, nW1 + 256 * H, usegE, usegN);
        xpart_k<<<Nn / 64, 256, 0, stream>>>(hxp, eW1h, eW1l, Pa, Pb);
        hipMemsetAsync(nmean, 0, 2 * Gn * H * sizeof(float), stream);   // nmean+emean
        mfma_mlp_ln<1, true, true><<<En / 64, 256, 0, stream>>>(
            hep, nullptr, nullptr, nullptr, nullptr, nullptr,
            psrc, pdst, Pa, Pb,
            eW1h + 8 * SLAB, eW1l + 8 * SLAB, eW2h, eW2l, eb1, eb2, eg, ebn, usegE,
            hep, nullptr, emean, 12, 1.f / EPGn, (En / 64) / 8);
        gather_agg_k<<<Nn / 16, 256, 0, stream>>>(hep, off, cnt, aggp, (Nn / 16) / 8);
        mfma_mlp_ln<2, true, false><<<Nn / 64, 256, 0, stream>>>(
            hxp, nullptr, aggp, nullptr, nullptr, nullptr,
            nullptr, nullptr, nullptr, nullptr,
            nW1h, nW1l, nW2h, nW2l, nb1, nb2, ng, nbn, usegN,
            hxp, nullptr, nmean, 9, 1.f / Pn, (Nn / 64) / 8);
        mfma_mlp_ln<3, false, false><<<1, 256, 0, stream>>>(
            u, nullptr, nmean, nullptr, emean, nullptr,
            nullptr, nullptr, nullptr, nullptr,
            gW1h, gW1l, gW2h, gW2l, gb1, gb2, gg, gbn, nullptr,
            up, u, nullptr, 0, 0.f, 0);
    }

    head_mfma_k<<<Nn / 64, 256, 0, stream>>>(hxp, aW1h, aW1l, ab1, aW2, ab2, logits);
    softmax_head_k<<<Gn, 256, 0, stream>>>(logits, outp);
    head_mlp<<<1, 256, 0, stream>>>(up, cW1, cb1, cW2, cb2, outp + 3 * Gn);
}

// Round 16
// 504.154 us; speedup vs baseline: 1.3100x; 1.0090x over previous
//
#include <hip/hip_runtime.h>
#include <cstddef>

namespace {

constexpr int Gn  = 64;
constexpr int Pn  = 512;
constexpr int EPGn= 4096;
constexpr int Nn  = Gn * Pn;    // 32768 nodes
constexpr int En  = Gn * EPGn;  // 262144 edges
constexpr int H   = 128;

constexpr int BM = 64, BK = 32, BN = 128;
constexpr int LDA = BK + 4;
constexpr int RS  = 256;        // bf16-plane row stride (hi 128 | lo 128)
constexpr int SLAB = 4096;      // elements per 32k-slab in frag layout

typedef __bf16 bf16_t;
typedef bf16_t bf16x8 __attribute__((ext_vector_type(8)));
typedef bf16_t bf16x4 __attribute__((ext_vector_type(4)));
typedef float  f32x4  __attribute__((ext_vector_type(4)));

__device__ __forceinline__ float4 ld4(const float* p) { return *reinterpret_cast<const float4*>(p); }
__device__ __forceinline__ void st4(float* p, const float4 v) { *reinterpret_cast<float4*>(p) = v; }
__device__ __forceinline__ f32x4 mfma16(bf16x8 a, bf16x8 b, f32x4 c) {
    return __builtin_amdgcn_mfma_f32_16x16x32_bf16(a, b, c, 0, 0, 0);
}

__device__ __forceinline__ int xcd_swz(int bid, int cpx)
{
    return (bid & 7) * cpx + (bid >> 3);
}

__device__ __forceinline__ void gload_lds16(const bf16_t* g, bf16_t* l)
{
    typedef __attribute__((address_space(1))) const unsigned int* gp_t;
    typedef __attribute__((address_space(3))) unsigned int* lp_t;
    __builtin_amdgcn_global_load_lds((gp_t)(const void*)g, (lp_t)(void*)l, 16, 0, 0);
}

__device__ __forceinline__ int wfrag_idx(int k, int n)
{
    return ((((k >> 5) * 8) + (n >> 4)) * 64 + ((k >> 3) & 3) * 16 + (n & 15)) * 8 + (k & 7);
}

// ---------------------------------------------------------------------------
// prep_all_k: 8 fp32 weight arrays -> bf16 hi/lo MFMA-frag region, one launch.
// Segments (K rows): eW1:384 eW2:128 nW1:256 nW2:128 gW1:384 gW2:128 We:32 aW1:128
// ---------------------------------------------------------------------------
__global__ void prep_all_k(const float* __restrict__ s0, const float* __restrict__ s1,
                           const float* __restrict__ s2, const float* __restrict__ s3,
                           const float* __restrict__ s4, const float* __restrict__ s5,
                           const float* __restrict__ s6, const float* __restrict__ s7,
                           bf16_t* __restrict__ frag)
{
    const int i = blockIdx.x * 256 + threadIdx.x;     // < 200704
    const float* src; int li; int dh; int sz;
    if      (i < 49152)  { src = s0; li = i;          dh = 0;      sz = 49152; }
    else if (i < 65536)  { src = s1; li = i - 49152;  dh = 98304;  sz = 16384; }
    else if (i < 98304)  { src = s2; li = i - 65536;  dh = 131072; sz = 32768; }
    else if (i < 114688) { src = s3; li = i - 98304;  dh = 196608; sz = 16384; }
    else if (i < 163840) { src = s4; li = i - 114688; dh = 229376; sz = 49152; }
    else if (i < 180224) { src = s5; li = i - 163840; dh = 327680; sz = 16384; }
    else if (i < 184320) { src = s6; li = i - 180224; dh = 360448; sz = 4096;  }
    else                 { src = s7; li = i - 184320; dh = 368640; sz = 16384; }
    const int k = li >> 7, n = li & 127;
    const float v = src[li];
    const bf16_t h = (bf16_t)v;
    const bf16_t l = (bf16_t)(v - (float)h);
    const int idx = wfrag_idx(k, n);
    frag[dh + idx]      = h;
    frag[dh + sz + idx] = l;
}

// single-segment prep for Wn (64x128)
__global__ void prep_wn_k(const float* __restrict__ W, bf16_t* __restrict__ Bh,
                          bf16_t* __restrict__ Bl)
{
    const int i = blockIdx.x * 256 + threadIdx.x;   // < 8192
    const int k = i >> 7, n = i & 127;
    const float v = W[i];
    const bf16_t h = (bf16_t)v;
    const bf16_t l = (bf16_t)(v - (float)h);
    const int idx = wfrag_idx(k, n);
    Bh[idx] = h; Bl[idx] = l;
}

// merged per-graph hoisted u-segment partials
__global__ void useg2_k(const float* __restrict__ u, const float* __restrict__ WE,
                        const float* __restrict__ WN, float* __restrict__ outE,
                        float* __restrict__ outN)
{
    __shared__ float su[H];
    const bool isE = blockIdx.x < Gn;
    const int g = isE ? blockIdx.x : blockIdx.x - Gn;
    const int c = threadIdx.x;
    const float* W = isE ? WE : WN;
    float* outp = isE ? outE : outN;
    su[c] = u[g * H + c];
    __syncthreads();
    float s = 0.f;
#pragma unroll 8
    for (int k = 0; k < H; ++k) s = fmaf(su[k], W[k * H + c], s);
    outp[g * H + c] = s;
}

__device__ __forceinline__ void split8(const float4 a, const float4 b, bf16x8& h, bf16x8& l)
{
    const float v[8] = {a.x, a.y, a.z, a.w, b.x, b.y, b.z, b.w};
#pragma unroll
    for (int j = 0; j < 8; ++j) {
        const bf16_t hh = (bf16_t)v[j];
        h[j] = hh;
        l[j] = (bf16_t)(v[j] - (float)hh);
    }
}

__device__ __forceinline__ void loadB(const bf16_t* __restrict__ Wh, const bf16_t* __restrict__ Wl,
                                      int kc32, int wn, int lane, bf16x8* Bh, bf16x8* Bl)
{
#pragma unroll
    for (int nt = 0; nt < 2; ++nt) {
        const size_t idx = (size_t)(((kc32 * 8) + wn * 2 + nt) * 64 + lane) * 8;
        Bh[nt] = *reinterpret_cast<const bf16x8*>(Wh + idx);
        Bl[nt] = *reinterpret_cast<const bf16x8*>(Wl + idx);
    }
}

// ---------------------------------------------------------------------------
// xpart_k: Pa[n] = x[n] @ eW1[0:128] ; Pb[n] = x[n] @ eW1[128:256]
// ---------------------------------------------------------------------------
__global__ __launch_bounds__(256, 4)
void xpart_k(const bf16_t* __restrict__ xp,
             const bf16_t* __restrict__ Wh, const bf16_t* __restrict__ Wl,
             float* __restrict__ Pa, float* __restrict__ Pb)
{
    __shared__ __align__(16) char smem[32 * 1024];
    const int t = threadIdx.x, lane = t & 63, wv = t >> 6;
    const int wn = wv;
    const int l15 = lane & 15, l4 = lane >> 4;
    const int row0 = blockIdx.x * 64;

    f32x4 accA[4][2], accB[4][2];
#pragma unroll
    for (int mt = 0; mt < 4; ++mt)
#pragma unroll
        for (int nt = 0; nt < 2; ++nt) { accA[mt][nt] = (f32x4)0.f; accB[mt][nt] = (f32x4)0.f; }

    auto stage = [&](int kc, int bufi) {
        const bf16_t* rp = xp + (size_t)(row0 + lane) * RS + kc * 64 + wv * 8;
        bf16_t* base = (bf16_t*)(smem + bufi * 16384);
        gload_lds16(rp,       base + wv * 512);
        gload_lds16(rp + 32,  base + (wv + 4) * 512);
        gload_lds16(rp + 128, base + 4096 + wv * 512);
        gload_lds16(rp + 160, base + 4096 + (wv + 4) * 512);
    };

    stage(0, 0);
    stage(1, 1);
    __syncthreads();

#pragma unroll
    for (int kc = 0; kc < 2; ++kc) {
        const bf16_t* aH = (const bf16_t*)(smem + (size_t)kc * 16384);
        const bf16_t* aL = aH + 4096;
#pragma unroll
        for (int ks = 0; ks < 2; ++ks) {
            const int slab = kc * 2 + ks;
            bf16x8 BhA[2], BlA[2], BhB[2], BlB[2];
            loadB(Wh, Wl, slab,     wn, lane, BhA, BlA);
            loadB(Wh, Wl, slab + 4, wn, lane, BhB, BlB);
#pragma unroll
            for (int mt = 0; mt < 4; ++mt) {
                const int ro = mt * 16 + l15;
                const bf16x8 Ah = *reinterpret_cast<const bf16x8*>(aH + ((ks * 4 + l4) * 64 + ro) * 8);
                const bf16x8 Al = *reinterpret_cast<const bf16x8*>(aL + ((ks * 4 + l4) * 64 + ro) * 8);
#pragma unroll
                for (int nt = 0; nt < 2; ++nt) {
                    accA[mt][nt] = mfma16(Al, BhA[nt], accA[mt][nt]);
                    accA[mt][nt] = mfma16(Ah, BlA[nt], accA[mt][nt]);
                    accA[mt][nt] = mfma16(Ah, BhA[nt], accA[mt][nt]);
                    accB[mt][nt] = mfma16(Al, BhB[nt], accB[mt][nt]);
                    accB[mt][nt] = mfma16(Ah, BlB[nt], accB[mt][nt]);
                    accB[mt][nt] = mfma16(Ah, BhB[nt], accB[mt][nt]);
                }
            }
        }
    }

#pragma unroll
    for (int mt = 0; mt < 4; ++mt)
#pragma unroll
        for (int r2 = 0; r2 < 4; ++r2) {
            const int row = mt * 16 + l4 * 4 + r2;
#pragma unroll
            for (int nt = 0; nt < 2; ++nt) {
                const int col = wn * 32 + nt * 16 + l15;
                Pa[(size_t)(row0 + row) * H + col] = accA[mt][nt][r2];
                Pb[(size_t)(row0 + row) * H + col] = accB[mt][nt][r2];
            }
        }
}

// ---------------------------------------------------------------------------
// proj32_mfma_k: he[slot] = relu(ea[perm[slot]] @ We + be), K=32
// ---------------------------------------------------------------------------
__global__ __launch_bounds__(256, 4)
void proj32_mfma_k(const float* __restrict__ in, const int* __restrict__ ridx,
                   const bf16_t* __restrict__ Wh, const bf16_t* __restrict__ Wl,
                   const float* __restrict__ b, bf16_t* __restrict__ outP)
{
    __shared__ __align__(16) bf16_t sA[2][2048];
    const int t = threadIdx.x, lane = t & 63, wv = t >> 6;
    const int wn = wv;
    const int l15 = lane & 15, l4 = lane >> 4;
    const int row0 = blockIdx.x * 64;

    const int srow = ridx ? ridx[row0 + lane] : row0 + lane;
    const float* sp = in + (size_t)srow * 32 + wv * 8;
    bf16x8 h8, l8;
    split8(ld4(sp), ld4(sp + 4), h8, l8);
    *reinterpret_cast<bf16x8*>(&sA[0][(wv * 64 + lane) * 8]) = h8;
    *reinterpret_cast<bf16x8*>(&sA[1][(wv * 64 + lane) * 8]) = l8;
    __syncthreads();

    f32x4 acc[4][2];
#pragma unroll
    for (int mt = 0; mt < 4; ++mt)
#pragma unroll
        for (int nt = 0; nt < 2; ++nt) acc[mt][nt] = (f32x4)0.f;

    bf16x8 Bh[2], Bl[2];
    loadB(Wh, Wl, 0, wn, lane, Bh, Bl);
#pragma unroll
    for (int mt = 0; mt < 4; ++mt) {
        const int ro = mt * 16 + l15;
        const bf16x8 Ah = *reinterpret_cast<const bf16x8*>(&sA[0][(l4 * 64 + ro) * 8]);
        const bf16x8 Al = *reinterpret_cast<const bf16x8*>(&sA[1][(l4 * 64 + ro) * 8]);
#pragma unroll
        for (int nt = 0; nt < 2; ++nt) {
            acc[mt][nt] = mfma16(Al, Bh[nt], acc[mt][nt]);
            acc[mt][nt] = mfma16(Ah, Bl[nt], acc[mt][nt]);
            acc[mt][nt] = mfma16(Ah, Bh[nt], acc[mt][nt]);
        }
    }

    float bb[2];
#pragma unroll
    for (int nt = 0; nt < 2; ++nt) bb[nt] = b[wn * 32 + nt * 16 + l15];
#pragma unroll
    for (int mt = 0; mt < 4; ++mt)
#pragma unroll
        for (int r2 = 0; r2 < 4; ++r2) {
            const int row = mt * 16 + l4 * 4 + r2;
            bf16_t* opP = outP + (size_t)(row0 + row) * RS;
#pragma unroll
            for (int nt = 0; nt < 2; ++nt) {
                const int col = wn * 32 + nt * 16 + l15;
                float v = acc[mt][nt][r2] + bb[nt];
                v = v > 0.f ? v : 0.f;
                const bf16_t oh = (bf16_t)v;
                opP[col]       = oh;
                opP[col + 128] = (bf16_t)(v - (float)oh);
            }
        }
}

// ---------------------------------------------------------------------------
// proj64_mfma_k: hx[row] = relu(x[row] @ Wn + bn), K=64
// ---------------------------------------------------------------------------
__global__ __launch_bounds__(256, 4)
void proj64_mfma_k(const float* __restrict__ in,
                   const bf16_t* __restrict__ Wh, const bf16_t* __restrict__ Wl,
                   const float* __restrict__ b, bf16_t* __restrict__ outP)
{
    __shared__ __align__(16) bf16_t sA[2][4096];
    const int t = threadIdx.x, lane = t & 63, wv = t >> 6;
    const int wn = wv;
    const int l15 = lane & 15, l4 = lane >> 4;
    const int row0 = blockIdx.x * 64;

    const float* sp = in + (size_t)(row0 + lane) * 64 + wv * 16;
    bf16x8 h8, l8;
    split8(ld4(sp), ld4(sp + 4), h8, l8);
    *reinterpret_cast<bf16x8*>(&sA[0][((wv * 2)     * 64 + lane) * 8]) = h8;
    *reinterpret_cast<bf16x8*>(&sA[1][((wv * 2)     * 64 + lane) * 8]) = l8;
    split8(ld4(sp + 8), ld4(sp + 12), h8, l8);
    *reinterpret_cast<bf16x8*>(&sA[0][((wv * 2 + 1) * 64 + lane) * 8]) = h8;
    *reinterpret_cast<bf16x8*>(&sA[1][((wv * 2 + 1) * 64 + lane) * 8]) = l8;
    __syncthreads();

    f32x4 acc[4][2];
#pragma unroll
    for (int mt = 0; mt < 4; ++mt)
#pragma unroll
        for (int nt = 0; nt < 2; ++nt) acc[mt][nt] = (f32x4)0.f;

#pragma unroll
    for (int ks = 0; ks < 2; ++ks) {
        bf16x8 Bh[2], Bl[2];
        loadB(Wh, Wl, ks, wn, lane, Bh, Bl);
#pragma unroll
        for (int mt = 0; mt < 4; ++mt) {
            const int ro = mt * 16 + l15;
            const bf16x8 Ah = *reinterpret_cast<const bf16x8*>(&sA[0][((ks * 4 + l4) * 64 + ro) * 8]);
            const bf16x8 Al = *reinterpret_cast<const bf16x8*>(&sA[1][((ks * 4 + l4) * 64 + ro) * 8]);
#pragma unroll
            for (int nt = 0; nt < 2; ++nt) {
                acc[mt][nt] = mfma16(Al, Bh[nt], acc[mt][nt]);
                acc[mt][nt] = mfma16(Ah, Bl[nt], acc[mt][nt]);
                acc[mt][nt] = mfma16(Ah, Bh[nt], acc[mt][nt]);
            }
        }
    }

    float bb[2];
#pragma unroll
    for (int nt = 0; nt < 2; ++nt) bb[nt] = b[wn * 32 + nt * 16 + l15];
#pragma unroll
    for (int mt = 0; mt < 4; ++mt)
#pragma unroll
        for (int r2 = 0; r2 < 4; ++r2) {
            const int row = mt * 16 + l4 * 4 + r2;
            bf16_t* opP = outP + (size_t)(row0 + row) * RS;
#pragma unroll
            for (int nt = 0; nt < 2; ++nt) {
                const int col = wn * 32 + nt * 16 + l15;
                float v = acc[mt][nt][r2] + bb[nt];
                v = v > 0.f ? v : 0.f;
                const bf16_t oh = (bf16_t)v;
                opP[col]       = oh;
                opP[col + 128] = (bf16_t)(v - (float)oh);
            }
        }
}

// ---------------------------------------------------------------------------
// head_mfma_k: logits[row] = relu(x[row] @ aW1 + ab1) . aW2 + ab2
// ---------------------------------------------------------------------------
__global__ __launch_bounds__(256, 4)
void head_mfma_k(const bf16_t* __restrict__ xp,
                 const bf16_t* __restrict__ W1h, const bf16_t* __restrict__ W1l,
                 const float* __restrict__ b1, const float* __restrict__ w2,
                 const float* __restrict__ b2, float* __restrict__ logits)
{
    __shared__ __align__(16) char smem[32 * 1024];
    __shared__ float redS[4][64];
    const int t = threadIdx.x, lane = t & 63, wv = t >> 6;
    const int wn = wv;
    const int l15 = lane & 15, l4 = lane >> 4;
    const int row0 = blockIdx.x * 64;

    f32x4 acc[4][2];
#pragma unroll
    for (int mt = 0; mt < 4; ++mt)
#pragma unroll
        for (int nt = 0; nt < 2; ++nt) acc[mt][nt] = (f32x4)0.f;

    auto stage = [&](int kh, int bufi) {
        const bf16_t* rp = xp + (size_t)(row0 + lane) * RS + kh * 64 + wv * 8;
        bf16_t* base = (bf16_t*)(smem + bufi * 16384);
        gload_lds16(rp,       base + wv * 512);
        gload_lds16(rp + 32,  base + (wv + 4) * 512);
        gload_lds16(rp + 128, base + 4096 + wv * 512);
        gload_lds16(rp + 160, base + 4096 + (wv + 4) * 512);
    };
    stage(0, 0);
    stage(1, 1);
    __syncthreads();

#pragma unroll
    for (int kc = 0; kc < 2; ++kc) {
        const bf16_t* aH = (const bf16_t*)(smem + (size_t)kc * 16384);
        const bf16_t* aL = aH + 4096;
#pragma unroll
        for (int ks = 0; ks < 2; ++ks) {
            bf16x8 Bh[2], Bl[2];
            loadB(W1h, W1l, kc * 2 + ks, wn, lane, Bh, Bl);
#pragma unroll
            for (int mt = 0; mt < 4; ++mt) {
                const int ro = mt * 16 + l15;
                const bf16x8 Ah = *reinterpret_cast<const bf16x8*>(aH + ((ks * 4 + l4) * 64 + ro) * 8);
                const bf16x8 Al = *reinterpret_cast<const bf16x8*>(aL + ((ks * 4 + l4) * 64 + ro) * 8);
#pragma unroll
                for (int nt = 0; nt < 2; ++nt) {
                    acc[mt][nt] = mfma16(Al, Bh[nt], acc[mt][nt]);
                    acc[mt][nt] = mfma16(Ah, Bl[nt], acc[mt][nt]);
                    acc[mt][nt] = mfma16(Ah, Bh[nt], acc[mt][nt]);
                }
            }
        }
    }

    float bb[2], vv[2];
#pragma unroll
    for (int nt = 0; nt < 2; ++nt) {
        const int col = wn * 32 + nt * 16 + l15;
        bb[nt] = b1[col]; vv[nt] = w2[col];
    }
#pragma unroll
    for (int mt = 0; mt < 4; ++mt)
#pragma unroll
        for (int r2 = 0; r2 < 4; ++r2) {
            float pp = 0.f;
#pragma unroll
            for (int nt = 0; nt < 2; ++nt) {
                float h = acc[mt][nt][r2] + bb[nt];
                h = h > 0.f ? h : 0.f;
                pp = fmaf(h, vv[nt], pp);
            }
            pp += __shfl_xor(pp, 1, 16); pp += __shfl_xor(pp, 2, 16);
            pp += __shfl_xor(pp, 4, 16); pp += __shfl_xor(pp, 8, 16);
            if (l15 == 0) redS[wn][mt * 16 + l4 * 4 + r2] = pp;
        }
    __syncthreads();
    if (t < 64)
        logits[row0 + t] = redS[0][t] + redS[1][t] + redS[2][t] + redS[3][t] + b2[0];
}

// ---------------------------------------------------------------------------
// MFMA fused 2-layer MLP + LN, bf16x3 precision. (R13-proven)
// ---------------------------------------------------------------------------
template<int NSEG, bool PLANES, bool PRE>
__global__ __launch_bounds__(256, 4)
void mfma_mlp_ln(const void* __restrict__ p0v, const int* __restrict__ i0,
                 const void* __restrict__ p1v, const int* __restrict__ i1,
                 const void* __restrict__ p2v, const int* __restrict__ i2,
                 const int* __restrict__ iA, const int* __restrict__ iB,
                 const float* __restrict__ Pa, const float* __restrict__ Pb,
                 const bf16_t* __restrict__ W1h, const bf16_t* __restrict__ W1l,
                 const bf16_t* __restrict__ W2h, const bf16_t* __restrict__ W2l,
                 const float* __restrict__ b1, const float* __restrict__ b2,
                 const float* __restrict__ gam, const float* __restrict__ bet,
                 const float* __restrict__ useg,
                 bf16_t* __restrict__ outP, float* __restrict__ out32,
                 float* __restrict__ pool, int gshift, float pscale, int cpx)
{
    __shared__ __align__(16) char smem[32 * 1024];
    __shared__ float redS[4][64], redQ[4][64];

    const int t = threadIdx.x;
    const int lane = t & 63;
    const int wv = t >> 6;
    const int wn = wv;
    const int l15 = lane & 15, l4 = lane >> 4;
    const int bid = (cpx > 0) ? xcd_swz(blockIdx.x, cpx) : blockIdx.x;
    const int row0 = bid * 64;

    const int s0 = (PRE || !i0) ? row0 + lane : i0[row0 + lane];
    const int s1 = (NSEG > 1) ? (i1 ? i1[row0 + lane] : row0 + lane) : 0;
    const int s2 = (NSEG > 2) ? (i2 ? i2[row0 + lane] : row0 + lane) : 0;

    f32x4 acc[4][2];
#pragma unroll
    for (int mt = 0; mt < 4; ++mt)
#pragma unroll
        for (int nt = 0; nt < 2; ++nt) acc[mt][nt] = (f32x4)0.f;

    constexpr int NC = NSEG * 2;
    constexpr int NS1 = NC * 2;

    auto stage_async = [&](int kc, int bufi) {
        const int seg = kc >> 1, kh = kc & 1;
        const bf16_t* p; int srow;
        if (seg == 0)      { p = (const bf16_t*)p0v; srow = s0; }
        else if (seg == 1) { p = (const bf16_t*)p1v; srow = s1; }
        else               { p = (const bf16_t*)p2v; srow = s2; }
        const bf16_t* rp = p + (size_t)srow * RS + kh * 64 + wv * 8;
        bf16_t* base = (bf16_t*)(smem + bufi * 16384);
        gload_lds16(rp,        base + wv * 512);
        gload_lds16(rp + 32,   base + (wv + 4) * 512);
        gload_lds16(rp + 128,  base + 4096 + wv * 512);
        gload_lds16(rp + 160,  base + 4096 + (wv + 4) * 512);
    };

    auto stage_f32 = [&](int kc, int bufi) {
        const int seg = kc >> 1, kh = kc & 1;
        const float* p; int srow;
        if (seg == 0)      { p = (const float*)p0v; srow = s0; }
        else if (seg == 1) { p = (const float*)p1v; srow = s1; }
        else               { p = (const float*)p2v; srow = s2; }
        const float* sp = p + (size_t)srow * H + kh * 64 + wv * 8;
        bf16_t* base = (bf16_t*)(smem + bufi * 16384);
        bf16x8 h, l;
        split8(ld4(sp), ld4(sp + 4), h, l);
        *reinterpret_cast<bf16x8*>(base + ((wv)     * 64 + lane) * 8) = h;
        *reinterpret_cast<bf16x8*>(base + 4096 + ((wv)     * 64 + lane) * 8) = l;
        split8(ld4(sp + 32), ld4(sp + 36), h, l);
        *reinterpret_cast<bf16x8*>(base + ((wv + 4) * 64 + lane) * 8) = h;
        *reinterpret_cast<bf16x8*>(base + 4096 + ((wv + 4) * 64 + lane) * 8) = l;
    };

    bf16x8 BhA[2], BlA[2], BhB[2], BlB[2];
    loadB(W1h, W1l, 0, wn, lane, BhA, BlA);
    if constexpr (PLANES) stage_async(0, 0); else stage_f32(0, 0);

    if constexpr (PRE) {
        const int ia = iA[row0 + lane];
        const int ib = iB[row0 + lane];
#pragma unroll
        for (int mt = 0; mt < 4; ++mt)
#pragma unroll
            for (int r2 = 0; r2 < 4; ++r2) {
                const int r = mt * 16 + l4 * 4 + r2;
                const int sa = __shfl(ia, r);
                const int sb = __shfl(ib, r);
#pragma unroll
                for (int nt = 0; nt < 2; ++nt) {
                    const int col = wn * 32 + nt * 16 + l15;
                    acc[mt][nt][r2] = Pa[(size_t)sa * H + col] + Pb[(size_t)sb * H + col];
                }
            }
    }
    __syncthreads();

#pragma unroll 1
    for (int kc = 0; kc < NC; ++kc) {
        if (kc + 1 < NC) {
            if constexpr (PLANES) stage_async(kc + 1, (kc & 1) ^ 1);
            else                  stage_f32(kc + 1, (kc & 1) ^ 1);
        }
        const bf16_t* aH = (const bf16_t*)(smem + (size_t)(kc & 1) * 16384);
        const bf16_t* aL = aH + 4096;

        {
            const int slab = kc * 2;
            if (slab + 1 < NS1)
                loadB(W1h, W1l, slab + 1, wn, lane, BhB, BlB);
#pragma unroll
            for (int mt = 0; mt < 4; ++mt) {
                const int ro = mt * 16 + l15;
                const bf16x8 Ah = *reinterpret_cast<const bf16x8*>(aH + ((l4) * 64 + ro) * 8);
                const bf16x8 Al = *reinterpret_cast<const bf16x8*>(aL + ((l4) * 64 + ro) * 8);
#pragma unroll
                for (int nt = 0; nt < 2; ++nt) {
                    acc[mt][nt] = mfma16(Al, BhA[nt], acc[mt][nt]);
                    acc[mt][nt] = mfma16(Ah, BlA[nt], acc[mt][nt]);
                    acc[mt][nt] = mfma16(Ah, BhA[nt], acc[mt][nt]);
                }
            }
        }
        {
            const int slab = kc * 2 + 1;
            if (slab + 1 < NS1)
                loadB(W1h, W1l, slab + 1, wn, lane, BhA, BlA);
#pragma unroll
            for (int mt = 0; mt < 4; ++mt) {
                const int ro = mt * 16 + l15;
                const bf16x8 Ah = *reinterpret_cast<const bf16x8*>(aH + ((4 + l4) * 64 + ro) * 8);
                const bf16x8 Al = *reinterpret_cast<const bf16x8*>(aL + ((4 + l4) * 64 + ro) * 8);
#pragma unroll
                for (int nt = 0; nt < 2; ++nt) {
                    acc[mt][nt] = mfma16(Al, BhB[nt], acc[mt][nt]);
                    acc[mt][nt] = mfma16(Ah, BlB[nt], acc[mt][nt]);
                    acc[mt][nt] = mfma16(Ah, BhB[nt], acc[mt][nt]);
                }
            }
        }
        __syncthreads();
    }

    {
        const int g = row0 >> gshift;
        bf16_t* sHh = (bf16_t*)smem;
        bf16_t* sHl = sHh + 8192;
#pragma unroll
        for (int mt = 0; mt < 4; ++mt)
#pragma unroll
            for (int nt = 0; nt < 2; ++nt) {
                const int col = wn * 32 + nt * 16 + l15;
                float bb = b1[col];
                if (useg) bb += useg[(size_t)g * H + col];
#pragma unroll
                for (int r2 = 0; r2 < 4; ++r2) {
                    const int rloc = mt * 16 + l4 * 4 + r2;
                    float v = acc[mt][nt][r2] + bb;
                    v = v > 0.f ? v : 0.f;
                    const bf16_t h = (bf16_t)v;
                    const int sidx = (col >> 3) * 512 + rloc * 8 + (col & 7);
                    sHh[sidx] = h;
                    sHl[sidx] = (bf16_t)(v - (float)h);
                    acc[mt][nt][r2] = 0.f;
                }
            }
    }
    __syncthreads();

    {
        const bf16_t* sHh = (const bf16_t*)smem;
        const bf16_t* sHl = sHh + 8192;
        loadB(W2h, W2l, 0, wn, lane, BhA, BlA);
#pragma unroll
        for (int kc2 = 0; kc2 < 4; ++kc2) {
            if (kc2 + 1 < 4) {
                if ((kc2 & 1) == 0) loadB(W2h, W2l, kc2 + 1, wn, lane, BhB, BlB);
                else                loadB(W2h, W2l, kc2 + 1, wn, lane, BhA, BlA);
            }
#pragma unroll
            for (int mt = 0; mt < 4; ++mt) {
                const int ro = mt * 16 + l15;
                const bf16x8 Ah = *reinterpret_cast<const bf16x8*>(sHh + ((kc2 * 4 + l4) * 64 + ro) * 8);
                const bf16x8 Al = *reinterpret_cast<const bf16x8*>(sHl + ((kc2 * 4 + l4) * 64 + ro) * 8);
#pragma unroll
                for (int nt = 0; nt < 2; ++nt) {
                    if ((kc2 & 1) == 0) {
                        acc[mt][nt] = mfma16(Al, BhA[nt], acc[mt][nt]);
                        acc[mt][nt] = mfma16(Ah, BlA[nt], acc[mt][nt]);
                        acc[mt][nt] = mfma16(Ah, BhA[nt], acc[mt][nt]);
                    } else {
                        acc[mt][nt] = mfma16(Al, BhB[nt], acc[mt][nt]);
                        acc[mt][nt] = mfma16(Ah, BlB[nt], acc[mt][nt]);
                        acc[mt][nt] = mfma16(Ah, BhB[nt], acc[mt][nt]);
                    }
                }
            }
        }
    }

    float bb2[2], ggv[2], btv[2];
#pragma unroll
    for (int nt = 0; nt < 2; ++nt) {
        const int col = wn * 32 + nt * 16 + l15;
        bb2[nt] = b2[col]; ggv[nt] = gam[col]; btv[nt] = bet[col];
    }
#pragma unroll
    for (int mt = 0; mt < 4; ++mt)
#pragma unroll
        for (int r2 = 0; r2 < 4; ++r2) {
            float s = 0.f, q = 0.f;
#pragma unroll
            for (int nt = 0; nt < 2; ++nt) {
                const float v = acc[mt][nt][r2] + bb2[nt];
                s += v; q += v * v;
            }
            s += __shfl_xor(s, 1, 16); s += __shfl_xor(s, 2, 16);
            s += __shfl_xor(s, 4, 16); s += __shfl_xor(s, 8, 16);
            q += __shfl_xor(q, 1, 16); q += __shfl_xor(q, 2, 16);
            q += __shfl_xor(q, 4, 16); q += __shfl_xor(q, 8, 16);
            if (l15 == 0) {
                const int row = mt * 16 + l4 * 4 + r2;
                redS[wn][row] = s; redQ[wn][row] = q;
            }
        }
    __syncthreads();

    float cs[2] = {0.f, 0.f};
#pragma unroll
    for (int mt = 0; mt < 4; ++mt)
#pragma unroll
        for (int r2 = 0; r2 < 4; ++r2) {
            const int row = mt * 16 + l4 * 4 + r2;
            const float S = redS[0][row] + redS[1][row] + redS[2][row] + redS[3][row];
            const float Q = redQ[0][row] + redQ[1][row] + redQ[2][row] + redQ[3][row];
            const float mean = S * (1.f / 128.f);
            const float var  = Q * (1.f / 128.f) - mean * mean;
            const float rstd = rsqrtf(var + 1e-5f);
            bf16_t* opP = outP + (size_t)(row0 + row) * RS;
#pragma unroll
            for (int nt = 0; nt < 2; ++nt) {
                const int col = wn * 32 + nt * 16 + l15;
                const float v = acc[mt][nt][r2] + bb2[nt];
                const float o = (v - mean) * rstd * ggv[nt] + btv[nt];
                const bf16_t oh = (bf16_t)o;
                opP[col]       = oh;
                opP[col + 128] = (bf16_t)(o - (float)oh);
                if (out32) out32[(size_t)(row0 + row) * H + col] = o;
                cs[nt] += o;
            }
        }

    if (pool != nullptr) {
        const int g = row0 >> gshift;
#pragma unroll
        for (int nt = 0; nt < 2; ++nt) {
            float s = cs[nt];
            s += __shfl_xor(s, 16);
            s += __shfl_xor(s, 32);
            if (l4 == 0)
                atomicAdd(&pool[(size_t)g * H + wn * 32 + nt * 16 + l15], s * pscale);
        }
    }
}

// ---------------------------------------------------------------------------
// Head (fp32, bf16-plane input) — value head only (1 block)
// ---------------------------------------------------------------------------
__global__ __launch_bounds__(256, 2)
void head_mlp(const bf16_t* __restrict__ inP, const float* __restrict__ W1,
              const float* __restrict__ b1, const float* __restrict__ w2,
              const float* __restrict__ b2, float* __restrict__ outp)
{
    __shared__ float sA[BM * LDA];
    __shared__ float sW[BK * BN];

    const int tid = threadIdx.x;
    const int rg = tid >> 4, cg = tid & 15;
    const int m0 = rg * 4, n0 = cg * 8;
    const int row0 = blockIdx.x * BM;
    const int lr = tid >> 2, lc = (tid & 3) * 8;
    const int wr = tid >> 3, wc = (tid & 7) * 16;

    float acc[4][8];
#pragma unroll
    for (int i = 0; i < 4; ++i)
#pragma unroll
        for (int j = 0; j < 8; ++j) acc[i][j] = 0.f;

#pragma unroll 1
    for (int kc = 0; kc < 4; ++kc) {
        const int koff = kc * 32;
        const bf16_t* rp = inP + (size_t)(row0 + lr) * RS + koff + lc;
        const bf16x8 h = *reinterpret_cast<const bf16x8*>(rp);
        const bf16x8 l = *reinterpret_cast<const bf16x8*>(rp + 128);
        float a[8];
#pragma unroll
        for (int j = 0; j < 8; ++j) a[j] = (float)h[j] + (float)l[j];
        st4(&sA[lr * LDA + lc],     make_float4(a[0], a[1], a[2], a[3]));
        st4(&sA[lr * LDA + lc + 4], make_float4(a[4], a[5], a[6], a[7]));
        const float* wsrc = W1 + (size_t)koff * BN + wr * BN + wc;
        st4(&sW[wr * BN + wc],      ld4(wsrc));
        st4(&sW[wr * BN + wc + 4],  ld4(wsrc + 4));
        st4(&sW[wr * BN + wc + 8],  ld4(wsrc + 8));
        st4(&sW[wr * BN + wc + 12], ld4(wsrc + 12));
        __syncthreads();
#pragma unroll
        for (int kk = 0; kk < BK; ++kk) {
            float a2[4];
#pragma unroll
            for (int i = 0; i < 4; ++i) a2[i] = sA[(m0 + i) * LDA + kk];
            const float4 wA = ld4(&sW[kk * BN + n0]);
            const float4 wB = ld4(&sW[kk * BN + n0 + 4]);
            const float w[8] = {wA.x, wA.y, wA.z, wA.w, wB.x, wB.y, wB.z, wB.w};
#pragma unroll
            for (int i = 0; i < 4; ++i)
#pragma unroll
                for (int j = 0; j < 8; ++j)
                    acc[i][j] = fmaf(a2[i], w[j], acc[i][j]);
        }
        __syncthreads();
    }

    const float4 bA = ld4(&b1[n0]),  bB = ld4(&b1[n0 + 4]);
    const float4 vA = ld4(&w2[n0]),  vB = ld4(&w2[n0 + 4]);
    const float bb[8] = {bA.x, bA.y, bA.z, bA.w, bB.x, bB.y, bB.z, bB.w};
    const float vv[8] = {vA.x, vA.y, vA.z, vA.w, vB.x, vB.y, vB.z, vB.w};
#pragma unroll
    for (int i = 0; i < 4; ++i) {
        float p = 0.f;
#pragma unroll
        for (int j = 0; j < 8; ++j) {
            float h = acc[i][j] + bb[j];
            h = h > 0.f ? h : 0.f;
            p = fmaf(h, vv[j], p);
        }
        p += __shfl_xor(p, 1, 16); p += __shfl_xor(p, 2, 16);
        p += __shfl_xor(p, 4, 16); p += __shfl_xor(p, 8, 16);
        if (cg == 0) outp[row0 + m0 + i] = p + b2[0];
    }
}

// ---------------------------------------------------------------------------
// CSR build
// ---------------------------------------------------------------------------
__global__ void count_int_k(const int* __restrict__ dst, int* __restrict__ cnt)
{
    const int i = blockIdx.x * 256 + threadIdx.x;
    atomicAdd(&cnt[dst[i]], 1);
}

__global__ void scan_graph_k(const int* __restrict__ cnt, int* __restrict__ off)
{
    __shared__ int s[256];
    const int g = blockIdx.x;
    const int t = threadIdx.x;
    const int a = cnt[g * Pn + 2 * t];
    const int b = cnt[g * Pn + 2 * t + 1];
    s[t] = a + b;
    __syncthreads();
    for (int d = 1; d < 256; d <<= 1) {
        const int v = (t >= d) ? s[t - d] : 0;
        __syncthreads();
        s[t] += v;
        __syncthreads();
    }
    const int excl = s[t] - (a + b);
    off[g * Pn + 2 * t]     = g * EPGn + excl;
    off[g * Pn + 2 * t + 1] = g * EPGn + excl + a;
}

__global__ void place_k(const int* __restrict__ dst, const int* __restrict__ off,
                        int* __restrict__ cur, int* __restrict__ perm)
{
    const int i = blockIdx.x * 256 + threadIdx.x;
    const int d = dst[i];
    const int p = off[d] + atomicAdd(&cur[d], 1);
    perm[p] = i;
}

__global__ void sort_bucket_k(int* __restrict__ perm, const int* __restrict__ off,
                              const int* __restrict__ cnt)
{
    const int n = blockIdx.x * 256 + threadIdx.x;
    if (n >= Nn) return;
    const int o = off[n], c = cnt[n];
    for (int i = 1; i < c; ++i) {
        const int key = perm[o + i];
        int j = i - 1;
        while (j >= 0 && perm[o + j] > key) { perm[o + j + 1] = perm[o + j]; --j; }
        perm[o + j + 1] = key;
    }
}

__global__ void make_pidx_k(const int* __restrict__ perm, const int* __restrict__ src,
                            const int* __restrict__ dst, int* __restrict__ psrc,
                            int* __restrict__ pdst)
{
    const int s = blockIdx.x * 256 + threadIdx.x;
    const int e = perm[s];
    psrc[s] = src[e];
    pdst[s] = dst[e];
}

// agg[n] = mean of incoming edge rows (contiguous CSR-slot order)
__global__ __launch_bounds__(256)
void gather_agg_k(const bf16_t* __restrict__ hep, const int* __restrict__ off,
                  const int* __restrict__ cnt, bf16_t* __restrict__ aggp, int cpx)
{
    const int tid = threadIdx.x;
    const int bid = xcd_swz(blockIdx.x, cpx);
    const int n = bid * 16 + (tid >> 4);
    const int q = tid & 15;
    const int o = off[n], c = cnt[n];
    float a[8] = {0.f, 0.f, 0.f, 0.f, 0.f, 0.f, 0.f, 0.f};
    const bf16_t* rp = hep + (size_t)o * RS + q * 8;
    for (int k = 0; k < c; ++k, rp += RS) {
        const bf16x8 h = *reinterpret_cast<const bf16x8*>(rp);
        const bf16x8 l = *reinterpret_cast<const bf16x8*>(rp + 128);
#pragma unroll
        for (int j = 0; j < 8; ++j) a[j] += (float)h[j] + (float)l[j];
    }
    const float inv = 1.f / fmaxf((float)c, 1.f);
    bf16x8 hv, lv;
#pragma unroll
    for (int j = 0; j < 8; ++j) {
        const float v = a[j] * inv;
        const bf16_t h = (bf16_t)v;
        hv[j] = h;
        lv[j] = (bf16_t)(v - (float)h);
    }
    bf16_t* op = aggp + (size_t)n * RS + q * 8;
    *reinterpret_cast<bf16x8*>(op)       = hv;
    *reinterpret_cast<bf16x8*>(op + 128) = lv;
}

__global__ void init_u_k(float* __restrict__ u, bf16_t* __restrict__ up,
                         const float* __restrict__ u0)
{
    const int idx = blockIdx.x * 256 + threadIdx.x;
    const int g = idx >> 7, col = idx & 127;
    const float v = u0[col];
    u[idx] = v;
    const bf16_t h = (bf16_t)v;
    up[(size_t)g * RS + col]       = h;
    up[(size_t)g * RS + 128 + col] = (bf16_t)(v - (float)h);
}

__global__ void softmax_head_k(const float* __restrict__ logits, float* __restrict__ outp)
{
    const int g = blockIdx.x;
    const int tid = threadIdx.x;
    const float* lg = logits + (size_t)g * Pn;
    const float v0 = lg[tid], v1 = lg[tid + 256];
    float bv; int bi;
    if (v1 > v0) { bv = v1; bi = tid + 256; } else { bv = v0; bi = tid; }

    __shared__ float sv[256];
    __shared__ int   si[256];
    sv[tid] = bv; si[tid] = bi;
    __syncthreads();
    for (int s = 128; s > 0; s >>= 1) {
        if (tid < s) {
            const float ov = sv[tid + s]; const int oi = si[tid + s];
            if (ov > sv[tid] || (ov == sv[tid] && oi < si[tid])) { sv[tid] = ov; si[tid] = oi; }
        }
        __syncthreads();
    }
    const float mx = sv[0];
    const int ai = si[0];
    __syncthreads();

    const float d0 = v0 - mx, d1 = v1 - mx;
    const float e0 = __expf(d0), e1 = __expf(d1);
    __shared__ float ss[256];
    __shared__ float st[256];
    ss[tid] = e0 + e1;
    st[tid] = e0 * d0 + e1 * d1;
    __syncthreads();
    for (int s = 128; s > 0; s >>= 1) {
        if (tid < s) { ss[tid] += ss[tid + s]; st[tid] += st[tid + s]; }
        __syncthreads();
    }
    if (tid == 0) {
        const float S = ss[0];
        const float logS = logf(S);
        outp[g]            = (float)ai;
        outp[Gn + g]       = -logS;
        outp[2 * Gn + g]   = logS - st[0] / S;
    }
}

} // namespace

extern "C" void kernel_launch(void* const* d_in, const int* in_sizes, int n_in,
                              void* d_out, int out_size, void* d_ws, size_t ws_size,
                              hipStream_t stream)
{
    (void)in_sizes; (void)n_in; (void)out_size; (void)ws_size;

    const float* x     = (const float*)d_in[0];
    const float* ea    = (const float*)d_in[1];
    const int*   ei    = (const int*)d_in[2];
    const float* Wn  = (const float*)d_in[6];
    const float* bn_ = (const float*)d_in[7];
    const float* We  = (const float*)d_in[8];
    const float* be_ = (const float*)d_in[9];
    const float* u0  = (const float*)d_in[10];
    const float* eW1 = (const float*)d_in[11];
    const float* eb1 = (const float*)d_in[12];
    const float* eW2 = (const float*)d_in[13];
    const float* eb2 = (const float*)d_in[14];
    const float* eg  = (const float*)d_in[15];
    const float* ebn = (const float*)d_in[16];
    const float* nW1 = (const float*)d_in[17];
    const float* nb1 = (const float*)d_in[18];
    const float* nW2 = (const float*)d_in[19];
    const float* nb2 = (const float*)d_in[20];
    const float* ng  = (const float*)d_in[21];
    const float* nbn = (const float*)d_in[22];
    const float* gW1 = (const float*)d_in[23];
    const float* gb1 = (const float*)d_in[24];
    const float* gW2 = (const float*)d_in[25];
    const float* gb2 = (const float*)d_in[26];
    const float* gg  = (const float*)d_in[27];
    const float* gbn = (const float*)d_in[28];
    const float* aW1 = (const float*)d_in[29];
    const float* ab1 = (const float*)d_in[30];
    const float* aW2 = (const float*)d_in[31];
    const float* ab2 = (const float*)d_in[32];
    const float* cW1 = (const float*)d_in[33];
    const float* cb1 = (const float*)d_in[34];
    const float* cW2 = (const float*)d_in[35];
    const float* cb2 = (const float*)d_in[36];

    const int* srcI = ei;
    const int* dstI = ei + En;

    // workspace layout
    float* ws     = (float*)d_ws;
    float* u      = ws;                              // 64*128 fp32
    float* nmean  = u + Gn * H;                      // 64*128
    float* emean  = nmean + Gn * H;                  // 64*128 (adjacent)
    float* usegE  = emean + Gn * H;                  // 64*128
    float* usegN  = usegE + Gn * H;                  // 64*128
    float* Pa     = usegN + Gn * H;                  // N*128 fp32
    float* Pb     = Pa + (size_t)Nn * H;             // N*128 fp32
    float* logits = Pb + (size_t)Nn * H;             // N
    int*   cnt    = (int*)(logits + Nn);             // N
    int*   off    = cnt + Nn;                        // N
    int*   cur    = off + Nn;                        // N
    int*   perm   = cur + Nn;                        // E
    int*   psrc   = perm + En;                       // E
    int*   pdst   = psrc + En;                       // E
    bf16_t* bfb  = (bf16_t*)(pdst + En);
    bf16_t* hxp  = bfb;                              // N*256
    bf16_t* hep  = hxp + (size_t)Nn * RS;            // E*256 (CSR-slot order)
    bf16_t* aggp = hep + (size_t)En * RS;            // N*256
    bf16_t* up   = aggp + (size_t)Nn * RS;           // 64*256
    bf16_t* frag = up + Gn * RS;
    // frag offsets must match prep_all_k's table:
    bf16_t* eW1h = frag;              bf16_t* eW1l = eW1h + 49152;
    bf16_t* eW2h = frag + 98304;      bf16_t* eW2l = eW2h + 16384;
    bf16_t* nW1h = frag + 131072;     bf16_t* nW1l = nW1h + 32768;
    bf16_t* nW2h = frag + 196608;     bf16_t* nW2l = nW2h + 16384;
    bf16_t* gW1h = frag + 229376;     bf16_t* gW1l = gW1h + 49152;
    bf16_t* gW2h = frag + 327680;     bf16_t* gW2l = gW2h + 16384;
    bf16_t* Weh  = frag + 360448;     bf16_t* Wel  = Weh + 4096;
    bf16_t* aW1h = frag + 368640;     bf16_t* aW1l = aW1h + 16384;
    bf16_t* Wnh  = frag + 401408;     bf16_t* Wnl  = Wnh + 8192;

    float* outp = (float*)d_out;

    // weight prep: one big launch + one small for Wn
    prep_all_k<<<200704 / 256, 256, 0, stream>>>(eW1, eW2, nW1, nW2, gW1, gW2, We, aW1, frag);
    prep_wn_k<<<(64 * 128) / 256, 256, 0, stream>>>(Wn, Wnh, Wnl);

    // CSR build; cnt+cur zeroed in one pass (off overwritten by scan)
    hipMemsetAsync(cnt, 0, 3 * Nn * sizeof(int), stream);
    count_int_k<<<En / 256, 256, 0, stream>>>(dstI, cnt);
    scan_graph_k<<<Gn, 256, 0, stream>>>(cnt, off);
    place_k<<<En / 256, 256, 0, stream>>>(dstI, off, cur, perm);
    sort_bucket_k<<<(Nn + 255) / 256, 256, 0, stream>>>(perm, off, cnt);
    make_pidx_k<<<En / 256, 256, 0, stream>>>(perm, srcI, dstI, psrc, pdst);

    // input projections + constants
    proj64_mfma_k<<<Nn / 64, 256, 0, stream>>>(x, Wnh, Wnl, bn_, hxp);
    proj32_mfma_k<<<En / 64, 256, 0, stream>>>(ea, perm, Weh, Wel, be_, hep);
    init_u_k<<<(Gn * H) / 256, 256, 0, stream>>>(u, up, u0);

    for (int l = 0; l < 2; ++l) {
        useg2_k<<<2 * Gn, H, 0, stream>>>(u, eW1 + 384 * H, nW1 + 256 * H, usegE, usegN);
        xpart_k<<<Nn / 64, 256, 0, stream>>>(hxp, eW1h, eW1l, Pa, Pb);
        hipMemsetAsync(nmean, 0, 2 * Gn * H * sizeof(float), stream);   // nmean+emean
        mfma_mlp_ln<1, true, true><<<En / 64, 256, 0, stream>>>(
            hep, nullptr, nullptr, nullptr, nullptr, nullptr,
            psrc, pdst, Pa, Pb,
            eW1h + 8 * SLAB, eW1l + 8 * SLAB, eW2h, eW2l, eb1, eb2, eg, ebn, usegE,
            hep, nullptr, emean, 12, 1.f / EPGn, (En / 64) / 8);
        gather_agg_k<<<Nn / 16, 256, 0, stream>>>(hep, off, cnt, aggp, (Nn / 16) / 8);
        mfma_mlp_ln<2, true, false><<<Nn / 64, 256, 0, stream>>>(
            hxp, nullptr, aggp, nullptr, nullptr, nullptr,
            nullptr, nullptr, nullptr, nullptr,
            nW1h, nW1l, nW2h, nW2l, nb1, nb2, ng, nbn, usegN,
            hxp, nullptr, nmean, 9, 1.f / Pn, (Nn / 64) / 8);
        mfma_mlp_ln<3, false, false><<<1, 256, 0, stream>>>(
            u, nullptr, nmean, nullptr, emean, nullptr,
            nullptr, nullptr, nullptr, nullptr,
            gW1h, gW1l, gW2h, gW2l, gb1, gb2, gg, gbn, nullptr,
            up, u, nullptr, 0, 0.f, 0);
    }

    head_mfma_k<<<Nn / 64, 256, 0, stream>>>(hxp, aW1h, aW1l, ab1, aW2, ab2, logits);
    softmax_head_k<<<Gn, 256, 0, stream>>>(logits, outp);
    head_mlp<<<1, 256, 0, stream>>>(up, cW1, cb1, cW2, cb2, outp + 3 * Gn);
}